// Round 3
// baseline (964.289 us; speedup 1.0000x reference)
//
#include <hip/hip_runtime.h>
#include <hip/hip_bf16.h>
#include <stdint.h>
#include <stddef.h>

#define SEQL 2048
#define DIMSZ 2048
#define HN 16
#define DKD 128
#define DVD 128
#define QSCALE 0.08838834764831843f   // 128^-0.5

typedef __attribute__((ext_vector_type(4))) float f32x4;
typedef __attribute__((ext_vector_type(2))) float f32x2;
typedef __attribute__((ext_vector_type(8))) short bf16x8;

__device__ __forceinline__ float sigmoid_f(float x) { return 1.f / (1.f + __expf(-x)); }

// ---------------- bf16 GEMM: C[M,N] (f32) = A[M,K]bf16 @ Bt[N,K]bf16 ----------------
#define BM 128
#define BN 128
#define BKK 64

__global__ __launch_bounds__(256) void gemm_bt(
    const __hip_bfloat16* __restrict__ A, const __hip_bfloat16* __restrict__ B,
    float* __restrict__ C, int M, int N, int lda, int klen, int accum)
{
  __shared__ __hip_bfloat16 As[BM * BKK];
  __shared__ __hip_bfloat16 Bs[BN * BKK];
  const int tid = threadIdx.x;
  const int lane = tid & 63;
  const int w = tid >> 6;
  const int wm = w >> 1, wn = w & 1;            // 2x2 wave grid, 64x64 each
  const int m0 = blockIdx.y * BM, n0 = blockIdx.x * BN;
  const int l15 = lane & 15, l4 = lane >> 4;
  const int kbase = blockIdx.z * klen;

  f32x4 acc[4][4] = {};

  for (int k0 = kbase; k0 < kbase + klen; k0 += BKK) {
#pragma unroll
    for (int i = 0; i < 4; ++i) {
      const int c = (w * 4 + i) * 64 + lane;     // chunk id, 16B each; 8 chunks/row
      const int row = c >> 3;
      const int colb = (c & 7) * 8;
      __builtin_amdgcn_global_load_lds(
          (const __attribute__((address_space(1))) void*)(A + (size_t)(m0 + row) * lda + k0 + colb),
          (__attribute__((address_space(3))) void*)(As + (size_t)c * 8), 16, 0, 0);
      __builtin_amdgcn_global_load_lds(
          (const __attribute__((address_space(1))) void*)(B + (size_t)(n0 + row) * lda + k0 + colb),
          (__attribute__((address_space(3))) void*)(Bs + (size_t)c * 8), 16, 0, 0);
    }
    __syncthreads();
#pragma unroll
    for (int kk = 0; kk < BKK; kk += 32) {
      bf16x8 af[4], bfv[4];
#pragma unroll
      for (int mi = 0; mi < 4; ++mi)
        af[mi] = *(const bf16x8*)(As + (wm * 64 + mi * 16 + l15) * BKK + kk + l4 * 8);
#pragma unroll
      for (int ni = 0; ni < 4; ++ni)
        bfv[ni] = *(const bf16x8*)(Bs + (wn * 64 + ni * 16 + l15) * BKK + kk + l4 * 8);
#pragma unroll
      for (int mi = 0; mi < 4; ++mi)
#pragma unroll
        for (int ni = 0; ni < 4; ++ni)
          acc[mi][ni] = __builtin_amdgcn_mfma_f32_16x16x32_bf16(af[mi], bfv[ni], acc[mi][ni], 0, 0, 0);
    }
    __syncthreads();
  }

  float* Cz = C + (size_t)blockIdx.z * M * N;
#pragma unroll
  for (int mi = 0; mi < 4; ++mi) {
#pragma unroll
    for (int ni = 0; ni < 4; ++ni) {
      const int row = m0 + wm * 64 + mi * 16 + l4 * 4;
      const int col = n0 + wn * 64 + ni * 16 + l15;
#pragma unroll
      for (int r = 0; r < 4; ++r) {
        size_t idx = (size_t)(row + r) * N + col;
        if (accum) Cz[idx] += acc[mi][ni][r];
        else Cz[idx] = acc[mi][ni][r];
      }
    }
  }
}

// ---------------- transpose + cast (optional hi/lo split): out[C,R] = bf16(in[R,C]^T) ----------------
__global__ __launch_bounds__(256) void transpose_cast_kernel(
    const float* __restrict__ in, __hip_bfloat16* __restrict__ outT,
    __hip_bfloat16* __restrict__ outLo, int R, int C)
{
  __shared__ float tile[32][33];
  const int c0 = blockIdx.x * 32, r0 = blockIdx.y * 32;
  const int tc = threadIdx.x & 31, tr = threadIdx.x >> 5;   // tr in 0..7
#pragma unroll
  for (int i = 0; i < 4; ++i)
    tile[tr + i * 8][tc] = in[(size_t)(r0 + tr + i * 8) * C + c0 + tc];
  __syncthreads();
#pragma unroll
  for (int i = 0; i < 4; ++i) {
    float val = tile[tc][tr + i * 8];
    __hip_bfloat16 h = __float2bfloat16(val);
    size_t oi = (size_t)(c0 + tr + i * 8) * R + r0 + tc;
    outT[oi] = h;
    if (outLo) outLo[oi] = __float2bfloat16(val - __bfloat162float(h));
  }
}

// ---------------- elementwise cast with optional lo residual ----------------
__global__ __launch_bounds__(256) void cast_split_kernel(
    const float* __restrict__ in, __hip_bfloat16* __restrict__ hi,
    __hip_bfloat16* __restrict__ lo, int n4)
{
  int idx = blockIdx.x * 256 + threadIdx.x;
  if (idx >= n4) return;
  f32x4 v = *(const f32x4*)(in + (size_t)idx * 4);
  union { __hip_bfloat16 b[4]; unsigned long long u; } ph, pl;
#pragma unroll
  for (int j = 0; j < 4; ++j) {
    float f = v[j];
    __hip_bfloat16 hh = __float2bfloat16(f);
    ph.b[j] = hh;
    pl.b[j] = __float2bfloat16(f - __bfloat162float(hh));
  }
  *(unsigned long long*)((char*)hi + (size_t)idx * 8) = ph.u;
  if (lo) *(unsigned long long*)((char*)lo + (size_t)idx * 8) = pl.u;
}

// ---------------- split-K reduce (8 partials) -> bf16 hi (+ optional lo) ----------------
__global__ __launch_bounds__(256) void reduce8_kernel(
    const float* __restrict__ part, __hip_bfloat16* __restrict__ hi,
    __hip_bfloat16* __restrict__ lo, int n4)
{
  int idx = blockIdx.x * 256 + threadIdx.x;
  if (idx >= n4) return;
  const size_t chunk = (size_t)SEQL * DVD;   // 2048*128
  f32x4 a = *(const f32x4*)(part + (size_t)idx * 4);
#pragma unroll
  for (int z = 1; z < 8; ++z) {
    f32x4 b = *(const f32x4*)(part + z * chunk + (size_t)idx * 4);
    a.x += b.x; a.y += b.y; a.z += b.z; a.w += b.w;
  }
  union { __hip_bfloat16 b[4]; unsigned long long u; } ph, pl;
#pragma unroll
  for (int j = 0; j < 4; ++j) {
    float f = a[j];
    __hip_bfloat16 hh = __float2bfloat16(f);
    ph.b[j] = hh;
    pl.b[j] = __float2bfloat16(f - __bfloat162float(hh));
  }
  *(unsigned long long*)((char*)hi + (size_t)idx * 8) = ph.u;
  if (lo) *(unsigned long long*)((char*)lo + (size_t)idx * 8) = pl.u;
}

// ---------------- beta = sigmoid(x @ Wb), thread per (s,h); writes [h][s] ----------------
__global__ __launch_bounds__(256) void beta_kernel(
    const float* __restrict__ x, const float* __restrict__ Wb, float* __restrict__ betaT)
{
  int idx = blockIdx.x * 256 + threadIdx.x;      // 0..32767
  int s = idx >> 4, h = idx & 15;
  const float* xr = x + (size_t)s * DIMSZ;
  float acc = 0.f;
  for (int d = 0; d < DIMSZ; d += 4) {
    f32x4 xv = *(const f32x4*)(xr + d);
    acc = fmaf(xv.x, Wb[(size_t)(d + 0) * HN + h], acc);
    acc = fmaf(xv.y, Wb[(size_t)(d + 1) * HN + h], acc);
    acc = fmaf(xv.z, Wb[(size_t)(d + 2) * HN + h], acc);
    acc = fmaf(xv.w, Wb[(size_t)(d + 3) * HN + h], acc);
  }
  betaT[(size_t)h * SEQL + s] = 1.f / (1.f + expf(-acc));
}

// ---------------- fused conv+silu+mix+l2norm+gate-exp -> packed slots ----------------
// One 64-thread block per (h,t). Slot (2304B): [k 512 | q 512 | e 512 | v 512 | beta 4 | pad]
// k/q/e stored granule-permuted: channel d = s*8+r -> dword p:
//   r<4 : p = s*4+r            (granule s        -> bank-quad s&7)
//   r>=4: p = 64+((s+4)&15)*4+(r-4)  (granule 16+((s+4)&15) -> bank-quad (s+4)&7)
// so the recurrence's two ds_read_b128 per array are 2-way (free) bank patterns.
#define SLOTB 2304

__global__ __launch_bounds__(64) void prep_slots(
    const float* __restrict__ xq, const float* __restrict__ xk, const float* __restrict__ xv,
    const float* __restrict__ g, const float* __restrict__ ve,
    const float* __restrict__ lam,
    const float* __restrict__ cwq, const float* __restrict__ cwk, const float* __restrict__ cwv,
    const float* __restrict__ dtb, const float* __restrict__ A_log,
    const float* __restrict__ betaT, char* __restrict__ packed)
{
  const int bid = blockIdx.x;          // h*2048 + t
  const int h = bid >> 11, t = bid & 2047;
  const int d2 = threadIdx.x * 2;      // channels d2, d2+1 of this head
  const int c = h * 128 + d2;

  f32x4 wq0 = *(const f32x4*)(cwq + (size_t)c * 4), wq1 = *(const f32x4*)(cwq + (size_t)(c + 1) * 4);
  f32x4 wk0 = *(const f32x4*)(cwk + (size_t)c * 4), wk1 = *(const f32x4*)(cwk + (size_t)(c + 1) * 4);
  f32x4 wv0 = *(const f32x4*)(cwv + (size_t)c * 4), wv1 = *(const f32x4*)(cwv + (size_t)(c + 1) * 4);

  float aq0 = 0, aq1 = 0, ak0 = 0, ak1 = 0, av0 = 0, av1 = 0;
#pragma unroll
  for (int i = 0; i < 4; ++i) {
    int sr = t - 3 + i;
    if (sr >= 0) {
      f32x2 a = *(const f32x2*)(xq + (size_t)sr * 2048 + c);
      f32x2 b = *(const f32x2*)(xk + (size_t)sr * 2048 + c);
      f32x2 d = *(const f32x2*)(xv + (size_t)sr * 2048 + c);
      aq0 = fmaf(a.x, wq0[i], aq0); aq1 = fmaf(a.y, wq1[i], aq1);
      ak0 = fmaf(b.x, wk0[i], ak0); ak1 = fmaf(b.y, wk1[i], ak1);
      av0 = fmaf(d.x, wv0[i], av0); av1 = fmaf(d.y, wv1[i], av1);
    }
  }
  float yq0 = aq0 * sigmoid_f(aq0), yq1 = aq1 * sigmoid_f(aq1);
  float yk0 = ak0 * sigmoid_f(ak0), yk1 = ak1 * sigmoid_f(ak1);
  float yv0 = av0 * sigmoid_f(av0), yv1 = av1 * sigmoid_f(av1);

  float l0 = lam[0], l1 = lam[1];
  f32x2 vev = *(const f32x2*)(ve + ((size_t)t * HN + h) * 128 + d2);
  float v0 = l0 * yv0 + l1 * vev.x;
  float v1 = l0 * yv1 + l1 * vev.y;

  float ssq = yq0 * yq0 + yq1 * yq1;
  float ssk = yk0 * yk0 + yk1 * yk1;
#pragma unroll
  for (int off = 32; off > 0; off >>= 1) {
    ssq += __shfl_xor(ssq, off);
    ssk += __shfl_xor(ssk, off);
  }
  float rq = rsqrtf(ssq + 1e-6f) * QSCALE;
  float rk = rsqrtf(ssk + 1e-6f);

  float A = expf(A_log[h]);
  f32x2 gv = *(const f32x2*)(g + (size_t)t * 2048 + c);
  float g0 = gv.x + dtb[c], g1 = gv.y + dtb[c + 1];
  float sp0 = (g0 > 20.f) ? g0 : log1pf(expf(fminf(g0, 20.f)));
  float sp1 = (g1 > 20.f) ? g1 : log1pf(expf(fminf(g1, 20.f)));
  float e0 = expf(-A * sp0), e1 = expf(-A * sp1);

  char* slot = packed + (size_t)bid * SLOTB;
  const int s = d2 >> 3, r = d2 & 7;
  const int p0 = (r < 4) ? (s * 4 + r) : (64 + ((s + 4) & 15) * 4 + (r - 4));
  f32x2 kk; kk.x = yk0 * rk; kk.y = yk1 * rk;
  f32x2 qq; qq.x = yq0 * rq; qq.y = yq1 * rq;
  f32x2 ee; ee.x = e0; ee.y = e1;
  f32x2 vv2; vv2.x = v0; vv2.y = v1;
  *(f32x2*)(slot + (size_t)p0 * 4) = kk;
  *(f32x2*)(slot + 512 + (size_t)p0 * 4) = qq;
  *(f32x2*)(slot + 1024 + (size_t)p0 * 4) = ee;
  *(f32x2*)(slot + 1536 + (size_t)d2 * 4) = vv2;
  if (threadIdx.x == 0) *(float*)(slot + 2048) = betaT[(size_t)h * SEQL + t];
}

// ---------------- DPP 16-lane row reduction (all lanes get the sum) ----------------
__device__ __forceinline__ float rowsum16(float x)
{
  union fi { float f; int i; };
  fi a, t; a.f = x;
  t.i = __builtin_amdgcn_update_dpp(0, a.i, 0x128, 0xf, 0xf, true); a.f += t.f; // row_ror:8
  t.i = __builtin_amdgcn_update_dpp(0, a.i, 0x124, 0xf, 0xf, true); a.f += t.f; // row_ror:4
  t.i = __builtin_amdgcn_update_dpp(0, a.i, 0x122, 0xf, 0xf, true); a.f += t.f; // row_ror:2
  t.i = __builtin_amdgcn_update_dpp(0, a.i, 0x121, 0xf, 0xf, true); a.f += t.f; // row_ror:1
  return a.f;
}

// ---------------- gated delta-rule recurrence, LDS-ring pipelined ----------------
// 512 one-wave blocks (2/CU): head h = bid>>5, columns (bid&31)*4 .. +3 (16 lanes each).
// 16-slot LDS ring (36KB), 3 global_load_lds per step, counted vmcnt (T3/T4 pattern).
#define NSLOT 16
#define WAITV(N) asm volatile("s_waitcnt vmcnt(" #N ")" ::: "memory")
#define WAITL0() asm volatile("s_waitcnt lgkmcnt(0)" ::: "memory")

__global__ __launch_bounds__(64, 1) void kda_rec2(
    const char* __restrict__ packed, float* __restrict__ o)
{
  __shared__ float ldsf[NSLOT * SLOTB / 4];
  char* ldsb = (char*)ldsf;
  const int bid = blockIdx.x;
  const int h = bid >> 5;
  const int lane = threadIdx.x;
  const int grp = lane >> 4, sub = lane & 15;
  const int col = (bid & 31) * 4 + grp;
  const char* gbase = packed + (size_t)h * SEQL * SLOTB;
  float* po = o + (size_t)h * 128 + col;

  auto issue = [&](int t) {
    const char* src = gbase + (size_t)t * SLOTB;
    char* dst = ldsb + (size_t)(t & (NSLOT - 1)) * SLOTB;
    __builtin_amdgcn_global_load_lds(
        (const __attribute__((address_space(1))) void*)(src + lane * 16),
        (__attribute__((address_space(3))) void*)(dst + lane * 16), 16, 0, 0);
    __builtin_amdgcn_global_load_lds(
        (const __attribute__((address_space(1))) void*)(src + 1024 + lane * 16),
        (__attribute__((address_space(3))) void*)(dst + 1024 + lane * 16), 16, 0, 0);
    __builtin_amdgcn_global_load_lds(
        (const __attribute__((address_space(1))) void*)(src + 2048 + lane * 4),
        (__attribute__((address_space(3))) void*)(dst + 2048 + lane * 4), 4, 0, 0);
  };

  const int ro1 = sub * 16;
  const int ro2 = 256 + ((sub + 4) & 15) * 16;

  f32x4 ck0, ck1, cq0, cq1, ce0, ce1; float cv_, cb_;
  auto readslot = [&](int t, f32x4& k0, f32x4& k1, f32x4& q0, f32x4& q1,
                      f32x4& e0, f32x4& e1, float& vt, float& bt) {
    const char* sb = ldsb + (size_t)(t & (NSLOT - 1)) * SLOTB;
    k0 = *(const f32x4*)(sb + ro1);        k1 = *(const f32x4*)(sb + ro2);
    q0 = *(const f32x4*)(sb + 512 + ro1);  q1 = *(const f32x4*)(sb + 512 + ro2);
    e0 = *(const f32x4*)(sb + 1024 + ro1); e1 = *(const f32x4*)(sb + 1024 + ro2);
    vt = *(const float*)(sb + 1536 + col * 4);
    bt = *(const float*)(sb + 2048);
  };

  float S0 = 0, S1 = 0, S2 = 0, S3 = 0, S4 = 0, S5 = 0, S6 = 0, S7 = 0;

  auto stepf = [&](int t, f32x4 k0, f32x4 k1, f32x4 e0, f32x4 e1,
                   f32x4 q0, f32x4 q1, float vt, float bt) {
    S0 *= e0.x; S1 *= e0.y; S2 *= e0.z; S3 *= e0.w;
    S4 *= e1.x; S5 *= e1.y; S6 *= e1.z; S7 *= e1.w;
    float pa = k0.x * S0; pa = fmaf(k0.y, S1, pa);
    float pb2 = k0.z * S2; pb2 = fmaf(k0.w, S3, pb2);
    float pc = k1.x * S4; pc = fmaf(k1.y, S5, pc);
    float pd = k1.z * S6; pd = fmaf(k1.w, S7, pd);
    float pred = rowsum16((pa + pb2) + (pc + pd));
    float vnew = bt * (vt - pred);
    S0 = fmaf(k0.x, vnew, S0); S1 = fmaf(k0.y, vnew, S1);
    S2 = fmaf(k0.z, vnew, S2); S3 = fmaf(k0.w, vnew, S3);
    S4 = fmaf(k1.x, vnew, S4); S5 = fmaf(k1.y, vnew, S5);
    S6 = fmaf(k1.z, vnew, S6); S7 = fmaf(k1.w, vnew, S7);
    float oa = q0.x * S0; oa = fmaf(q0.y, S1, oa);
    float ob = q0.z * S2; ob = fmaf(q0.w, S3, ob);
    float oc = q1.x * S4; oc = fmaf(q1.y, S5, oc);
    float od = q1.z * S6; od = fmaf(q1.w, S7, od);
    float outv = rowsum16((oa + ob) + (oc + od));
    if (sub == 0) po[(size_t)t * 2048] = outv;
  };

#pragma unroll
  for (int t = 0; t < NSLOT; ++t) issue(t);
  WAITV(40);
  readslot(0, ck0, ck1, cq0, cq1, ce0, ce1, cv_, cb_);

  int t = 0;
  for (; t < SEQL - NSLOT; ++t) {
    WAITL0();                       // prior ds_reads done -> safe to overwrite slot (t&15)
    issue(t + NSLOT);
    WAITV(40);                      // guarantees slot t+1 resident (oldest in queue)
    f32x4 nk0, nk1, nq0, nq1, ne0, ne1; float nv, nb;
    readslot(t + 1, nk0, nk1, nq0, nq1, ne0, ne1, nv, nb);
    stepf(t, ck0, ck1, ce0, ce1, cq0, cq1, cv_, cb_);
    ck0 = nk0; ck1 = nk1; cq0 = nq0; cq1 = nq1; ce0 = ne0; ce1 = ne1; cv_ = nv; cb_ = nb;
  }
  WAITV(0);
  for (; t < SEQL - 1; ++t) {
    f32x4 nk0, nk1, nq0, nq1, ne0, ne1; float nv, nb;
    readslot(t + 1, nk0, nk1, nq0, nq1, ne0, ne1, nv, nb);
    stepf(t, ck0, ck1, ce0, ce1, cq0, cq1, cv_, cb_);
    ck0 = nk0; ck1 = nk1; cq0 = nq0; cq1 = nq1; ce0 = ne0; ce1 = ne1; cv_ = nv; cb_ = nb;
  }
  stepf(SEQL - 1, ck0, ck1, ce0, ce1, cq0, cq1, cv_, cb_);
}

// ---------------- sigmoid-gated RMSNorm -> bf16 ----------------
__global__ __launch_bounds__(256) void rmsgate_kernel(
    const float* __restrict__ o, const float* __restrict__ gate,
    const float* __restrict__ bg2, const float* __restrict__ norm_w,
    __hip_bfloat16* __restrict__ og)
{
  int row = blockIdx.x * 4 + (threadIdx.x >> 6);   // s*16 + h
  int lane = threadIdx.x & 63;
  int s = row >> 4, h = row & 15;
  int j = lane * 2;
  const float* p = o + (size_t)row * 128 + j;
  f32x2 v = *(const f32x2*)p;
  float ss = v.x * v.x + v.y * v.y;
#pragma unroll
  for (int off = 32; off > 0; off >>= 1) ss += __shfl_xor(ss, off);
  float rs = rsqrtf(ss * (1.f / 128.f) + 1e-6f);
  int c = h * 128 + j;
  float g0 = gate[(size_t)s * 2048 + c] + bg2[c];
  float g1 = gate[(size_t)s * 2048 + c + 1] + bg2[c + 1];
  float o0 = v.x * rs * norm_w[j] * (1.f / (1.f + expf(-g0)));
  float o1 = v.y * rs * norm_w[j + 1] * (1.f / (1.f + expf(-g1)));
  union { __hip_bfloat16 b[2]; unsigned int u; } pk2;
  pk2.b[0] = __float2bfloat16(o0);
  pk2.b[1] = __float2bfloat16(o1);
  *(unsigned int*)((char*)og + ((size_t)s * 2048 + c) * 2) = pk2.u;
}

// =====================================================================
extern "C" void kernel_launch(void* const* d_in, const int* in_sizes, int n_in,
                              void* d_out, int out_size, void* d_ws, size_t ws_size,
                              hipStream_t stream)
{
  const float* x      = (const float*)d_in[0];
  const float* ve     = (const float*)d_in[1];
  const float* lam    = (const float*)d_in[2];
  const float* Wq     = (const float*)d_in[3];
  const float* Wk     = (const float*)d_in[4];
  const float* Wv     = (const float*)d_in[5];
  const float* cwq    = (const float*)d_in[6];
  const float* cwk    = (const float*)d_in[7];
  const float* cwv    = (const float*)d_in[8];
  const float* Wf1    = (const float*)d_in[9];
  const float* Wf2    = (const float*)d_in[10];
  const float* Wb     = (const float*)d_in[11];
  const float* A_log  = (const float*)d_in[12];
  const float* dtb    = (const float*)d_in[13];
  const float* Wg1    = (const float*)d_in[14];
  const float* Wg2    = (const float*)d_in[15];
  const float* bg2    = (const float*)d_in[16];
  const float* norm_w = (const float*)d_in[17];
  const float* Wo     = (const float*)d_in[18];
  float* out = (float*)d_out;

  const size_t S2 = (size_t)2048 * 2048;

  char* p = (char*)d_ws;
  auto alloc = [&](size_t bytes) { char* r = p; p += (bytes + 255) & ~(size_t)255; return r; };

  __hip_bfloat16* xb    = (__hip_bfloat16*)alloc(S2 * 2);
  __hip_bfloat16* WoT   = (__hip_bfloat16*)alloc(S2 * 2);
  __hip_bfloat16* Wf1hT = (__hip_bfloat16*)alloc(2048 * 128 * 2);
  __hip_bfloat16* Wf1lT = (__hip_bfloat16*)alloc(2048 * 128 * 2);
  __hip_bfloat16* Wf2hT = (__hip_bfloat16*)alloc(2048 * 128 * 2);
  __hip_bfloat16* Wf2lT = (__hip_bfloat16*)alloc(2048 * 128 * 2);
  __hip_bfloat16* Wg1T  = (__hip_bfloat16*)alloc(2048 * 128 * 2);
  __hip_bfloat16* Wg2T  = (__hip_bfloat16*)alloc(2048 * 128 * 2);
  float* xq   = (float*)alloc(S2 * 4);
  float* xk   = (float*)alloc(S2 * 4);   // later aliased: gate output
  float* xv   = (float*)alloc(S2 * 4);   // later aliased: o
  float* gbuf = (float*)alloc(S2 * 4);   // raw g = f1 @ Wf2
  __hip_bfloat16* f1h = (__hip_bfloat16*)alloc(2048 * 128 * 2);
  __hip_bfloat16* f1l = (__hip_bfloat16*)alloc(2048 * 128 * 2);
  __hip_bfloat16* g1b = (__hip_bfloat16*)alloc(2048 * 128 * 2);
  float* fpart = (float*)alloc((size_t)8 * 2048 * 128 * 4);
  float* betaT = (float*)alloc((size_t)2048 * 16 * 4);
  char* packed = alloc((size_t)HN * SEQL * SLOTB);   // 72MB

  // overlays inside packed (dead before prep_slots writes it):
  __hip_bfloat16* WqT = (__hip_bfloat16*)(packed);
  __hip_bfloat16* WkT = (__hip_bfloat16*)(packed + S2 * 2);
  __hip_bfloat16* WvT = (__hip_bfloat16*)(packed + 2 * S2 * 2);
  __hip_bfloat16* xlo = (__hip_bfloat16*)(packed + 3 * S2 * 2);
  __hip_bfloat16* og  = (__hip_bfloat16*)(packed);   // reused after recurrence

  float* gatebuf = xk;
  float* obuf    = xv;

  // 1. split-cast x
  cast_split_kernel<<<4096, 256, 0, stream>>>(x, xb, xlo, (int)(S2 / 4));

  // 2. weight transposes
  transpose_cast_kernel<<<dim3(64, 64), 256, 0, stream>>>(Wq, WqT, nullptr, 2048, 2048);
  transpose_cast_kernel<<<dim3(64, 64), 256, 0, stream>>>(Wk, WkT, nullptr, 2048, 2048);
  transpose_cast_kernel<<<dim3(64, 64), 256, 0, stream>>>(Wv, WvT, nullptr, 2048, 2048);
  transpose_cast_kernel<<<dim3(64, 64), 256, 0, stream>>>(Wo, WoT, nullptr, 2048, 2048);
  transpose_cast_kernel<<<dim3(4, 64), 256, 0, stream>>>(Wf1, Wf1hT, Wf1lT, 2048, 128);
  transpose_cast_kernel<<<dim3(64, 4), 256, 0, stream>>>(Wf2, Wf2hT, Wf2lT, 128, 2048);
  transpose_cast_kernel<<<dim3(4, 64), 256, 0, stream>>>(Wg1, Wg1T, nullptr, 2048, 128);
  transpose_cast_kernel<<<dim3(64, 4), 256, 0, stream>>>(Wg2, Wg2T, nullptr, 128, 2048);

  // 3. projection GEMMs
  gemm_bt<<<dim3(16, 16), 256, 0, stream>>>(xb, WqT, xq, 2048, 2048, 2048, 2048, 0);
  gemm_bt<<<dim3(16, 16), 256, 0, stream>>>(xb, WkT, xk, 2048, 2048, 2048, 2048, 0);
  gemm_bt<<<dim3(16, 16), 256, 0, stream>>>(xb, WvT, xv, 2048, 2048, 2048, 2048, 0);

  // 4. f-path: f1 = x @ Wf1 (split precision, split-K z=8); g = f1 @ Wf2 (split)
  gemm_bt<<<dim3(1, 16, 8), 256, 0, stream>>>(xb,  Wf1hT, fpart, 2048, 128, 2048, 256, 0);
  gemm_bt<<<dim3(1, 16, 8), 256, 0, stream>>>(xlo, Wf1hT, fpart, 2048, 128, 2048, 256, 1);
  gemm_bt<<<dim3(1, 16, 8), 256, 0, stream>>>(xb,  Wf1lT, fpart, 2048, 128, 2048, 256, 1);
  reduce8_kernel<<<256, 256, 0, stream>>>(fpart, f1h, f1l, 65536);
  gemm_bt<<<dim3(16, 16), 256, 0, stream>>>(f1h, Wf2hT, gbuf, 2048, 2048, 128, 128, 0);
  gemm_bt<<<dim3(16, 16), 256, 0, stream>>>(f1l, Wf2hT, gbuf, 2048, 2048, 128, 128, 1);
  gemm_bt<<<dim3(16, 16), 256, 0, stream>>>(f1h, Wf2lT, gbuf, 2048, 2048, 128, 128, 1);

  // 5. beta
  beta_kernel<<<128, 256, 0, stream>>>(x, Wb, betaT);

  // 6. fused prep -> packed slots (overwrites WqT/WkT/WvT/xlo overlays)
  prep_slots<<<HN * SEQL, 64, 0, stream>>>(xq, xk, xv, gbuf, ve, lam,
                                           cwq, cwk, cwv, dtb, A_log, betaT, packed);

  // 7. recurrence
  kda_rec2<<<512, 64, 0, stream>>>(packed, obuf);

  // 8. gate path (after rec so gatebuf can alias xk)
  gemm_bt<<<dim3(1, 16, 8), 256, 0, stream>>>(xb, Wg1T, fpart, 2048, 128, 2048, 256, 0);
  reduce8_kernel<<<256, 256, 0, stream>>>(fpart, g1b, nullptr, 65536);
  gemm_bt<<<dim3(16, 16), 256, 0, stream>>>(g1b, Wg2T, gatebuf, 2048, 2048, 128, 128, 0);

  // 9. gated rmsnorm -> bf16 (og aliases packed, dead after rec)
  rmsgate_kernel<<<8192, 256, 0, stream>>>(obuf, gatebuf, bg2, norm_w, og);

  // 10. output projection
  gemm_bt<<<dim3(16, 16), 256, 0, stream>>>(og, WoT, out, 2048, 2048, 2048, 2048, 0);
}

// Round 4
// 673.864 us; speedup vs baseline: 1.4310x; 1.4310x over previous
//
#include <hip/hip_runtime.h>
#include <hip/hip_bf16.h>
#include <stdint.h>
#include <stddef.h>

#define SEQL 2048
#define DIMSZ 2048
#define HN 16
#define DKD 128
#define DVD 128
#define QSCALE 0.08838834764831843f   // 128^-0.5

typedef __attribute__((ext_vector_type(4))) float f32x4;
typedef __attribute__((ext_vector_type(2))) float f32x2;
typedef __attribute__((ext_vector_type(8))) short bf16x8;

__device__ __forceinline__ float sigmoid_f(float x) { return 1.f / (1.f + __expf(-x)); }

// ---------------- bf16 GEMM: C[M,N] (f32) = A[M,K]bf16 @ Bt[N,K]bf16 ----------------
#define BM 128
#define BN 128
#define BKK 64

__global__ __launch_bounds__(256) void gemm_bt(
    const __hip_bfloat16* __restrict__ A, const __hip_bfloat16* __restrict__ B,
    float* __restrict__ C, int M, int N, int lda, int klen, int accum)
{
  __shared__ __hip_bfloat16 As[BM * BKK];
  __shared__ __hip_bfloat16 Bs[BN * BKK];
  const int tid = threadIdx.x;
  const int lane = tid & 63;
  const int w = tid >> 6;
  const int wm = w >> 1, wn = w & 1;            // 2x2 wave grid, 64x64 each
  const int m0 = blockIdx.y * BM, n0 = blockIdx.x * BN;
  const int l15 = lane & 15, l4 = lane >> 4;
  const int kbase = blockIdx.z * klen;

  f32x4 acc[4][4] = {};

  for (int k0 = kbase; k0 < kbase + klen; k0 += BKK) {
#pragma unroll
    for (int i = 0; i < 4; ++i) {
      const int c = (w * 4 + i) * 64 + lane;     // chunk id, 16B each; 8 chunks/row
      const int row = c >> 3;
      const int colb = (c & 7) * 8;
      __builtin_amdgcn_global_load_lds(
          (const __attribute__((address_space(1))) void*)(A + (size_t)(m0 + row) * lda + k0 + colb),
          (__attribute__((address_space(3))) void*)(As + (size_t)c * 8), 16, 0, 0);
      __builtin_amdgcn_global_load_lds(
          (const __attribute__((address_space(1))) void*)(B + (size_t)(n0 + row) * lda + k0 + colb),
          (__attribute__((address_space(3))) void*)(Bs + (size_t)c * 8), 16, 0, 0);
    }
    __syncthreads();
#pragma unroll
    for (int kk = 0; kk < BKK; kk += 32) {
      bf16x8 af[4], bfv[4];
#pragma unroll
      for (int mi = 0; mi < 4; ++mi)
        af[mi] = *(const bf16x8*)(As + (wm * 64 + mi * 16 + l15) * BKK + kk + l4 * 8);
#pragma unroll
      for (int ni = 0; ni < 4; ++ni)
        bfv[ni] = *(const bf16x8*)(Bs + (wn * 64 + ni * 16 + l15) * BKK + kk + l4 * 8);
#pragma unroll
      for (int mi = 0; mi < 4; ++mi)
#pragma unroll
        for (int ni = 0; ni < 4; ++ni)
          acc[mi][ni] = __builtin_amdgcn_mfma_f32_16x16x32_bf16(af[mi], bfv[ni], acc[mi][ni], 0, 0, 0);
    }
    __syncthreads();
  }

  float* Cz = C + (size_t)blockIdx.z * M * N;
#pragma unroll
  for (int mi = 0; mi < 4; ++mi) {
#pragma unroll
    for (int ni = 0; ni < 4; ++ni) {
      const int row = m0 + wm * 64 + mi * 16 + l4 * 4;
      const int col = n0 + wn * 64 + ni * 16 + l15;
#pragma unroll
      for (int r = 0; r < 4; ++r) {
        size_t idx = (size_t)(row + r) * N + col;
        if (accum) Cz[idx] += acc[mi][ni][r];
        else Cz[idx] = acc[mi][ni][r];
      }
    }
  }
}

// ---------------- transpose + cast (optional hi/lo split): out[C,R] = bf16(in[R,C]^T) ----------------
__global__ __launch_bounds__(256) void transpose_cast_kernel(
    const float* __restrict__ in, __hip_bfloat16* __restrict__ outT,
    __hip_bfloat16* __restrict__ outLo, int R, int C)
{
  __shared__ float tile[32][33];
  const int c0 = blockIdx.x * 32, r0 = blockIdx.y * 32;
  const int tc = threadIdx.x & 31, tr = threadIdx.x >> 5;   // tr in 0..7
#pragma unroll
  for (int i = 0; i < 4; ++i)
    tile[tr + i * 8][tc] = in[(size_t)(r0 + tr + i * 8) * C + c0 + tc];
  __syncthreads();
#pragma unroll
  for (int i = 0; i < 4; ++i) {
    float val = tile[tc][tr + i * 8];
    __hip_bfloat16 h = __float2bfloat16(val);
    size_t oi = (size_t)(c0 + tr + i * 8) * R + r0 + tc;
    outT[oi] = h;
    if (outLo) outLo[oi] = __float2bfloat16(val - __bfloat162float(h));
  }
}

// ---------------- elementwise cast with optional lo residual ----------------
__global__ __launch_bounds__(256) void cast_split_kernel(
    const float* __restrict__ in, __hip_bfloat16* __restrict__ hi,
    __hip_bfloat16* __restrict__ lo, int n4)
{
  int idx = blockIdx.x * 256 + threadIdx.x;
  if (idx >= n4) return;
  f32x4 v = *(const f32x4*)(in + (size_t)idx * 4);
  union { __hip_bfloat16 b[4]; unsigned long long u; } ph, pl;
#pragma unroll
  for (int j = 0; j < 4; ++j) {
    float f = v[j];
    __hip_bfloat16 hh = __float2bfloat16(f);
    ph.b[j] = hh;
    pl.b[j] = __float2bfloat16(f - __bfloat162float(hh));
  }
  *(unsigned long long*)((char*)hi + (size_t)idx * 8) = ph.u;
  if (lo) *(unsigned long long*)((char*)lo + (size_t)idx * 8) = pl.u;
}

// ---------------- split-K reduce (8 partials) -> bf16 hi (+ optional lo) ----------------
__global__ __launch_bounds__(256) void reduce8_kernel(
    const float* __restrict__ part, __hip_bfloat16* __restrict__ hi,
    __hip_bfloat16* __restrict__ lo, int n4)
{
  int idx = blockIdx.x * 256 + threadIdx.x;
  if (idx >= n4) return;
  const size_t chunk = (size_t)SEQL * DVD;   // 2048*128
  f32x4 a = *(const f32x4*)(part + (size_t)idx * 4);
#pragma unroll
  for (int z = 1; z < 8; ++z) {
    f32x4 b = *(const f32x4*)(part + z * chunk + (size_t)idx * 4);
    a.x += b.x; a.y += b.y; a.z += b.z; a.w += b.w;
  }
  union { __hip_bfloat16 b[4]; unsigned long long u; } ph, pl;
#pragma unroll
  for (int j = 0; j < 4; ++j) {
    float f = a[j];
    __hip_bfloat16 hh = __float2bfloat16(f);
    ph.b[j] = hh;
    pl.b[j] = __float2bfloat16(f - __bfloat162float(hh));
  }
  *(unsigned long long*)((char*)hi + (size_t)idx * 8) = ph.u;
  if (lo) *(unsigned long long*)((char*)lo + (size_t)idx * 8) = pl.u;
}

// ---------------- beta = sigmoid(x @ Wb), thread per (s,h); writes [h][s] ----------------
__global__ __launch_bounds__(256) void beta_kernel(
    const float* __restrict__ x, const float* __restrict__ Wb, float* __restrict__ betaT)
{
  int idx = blockIdx.x * 256 + threadIdx.x;      // 0..32767
  int s = idx >> 4, h = idx & 15;
  const float* xr = x + (size_t)s * DIMSZ;
  float acc = 0.f;
  for (int d = 0; d < DIMSZ; d += 4) {
    f32x4 xv = *(const f32x4*)(xr + d);
    acc = fmaf(xv.x, Wb[(size_t)(d + 0) * HN + h], acc);
    acc = fmaf(xv.y, Wb[(size_t)(d + 1) * HN + h], acc);
    acc = fmaf(xv.z, Wb[(size_t)(d + 2) * HN + h], acc);
    acc = fmaf(xv.w, Wb[(size_t)(d + 3) * HN + h], acc);
  }
  betaT[(size_t)h * SEQL + s] = 1.f / (1.f + expf(-acc));
}

// ---------------- fused conv+silu+mix+l2norm -> plain arrays [s][h*128+d] ----------------
__global__ __launch_bounds__(64) void prep_plain(
    const float* __restrict__ xq, const float* __restrict__ xk, const float* __restrict__ xv,
    const float* __restrict__ ve, const float* __restrict__ lam,
    const float* __restrict__ cwq, const float* __restrict__ cwk, const float* __restrict__ cwv,
    float* __restrict__ karr, float* __restrict__ qarr, float* __restrict__ varr)
{
  const int bid = blockIdx.x;          // h*2048 + t
  const int h = bid >> 11, t = bid & 2047;
  const int d2 = threadIdx.x * 2;      // channels d2, d2+1 of this head
  const int c = h * 128 + d2;

  f32x4 wq0 = *(const f32x4*)(cwq + (size_t)c * 4), wq1 = *(const f32x4*)(cwq + (size_t)(c + 1) * 4);
  f32x4 wk0 = *(const f32x4*)(cwk + (size_t)c * 4), wk1 = *(const f32x4*)(cwk + (size_t)(c + 1) * 4);
  f32x4 wv0 = *(const f32x4*)(cwv + (size_t)c * 4), wv1 = *(const f32x4*)(cwv + (size_t)(c + 1) * 4);

  float aq0 = 0, aq1 = 0, ak0 = 0, ak1 = 0, av0 = 0, av1 = 0;
#pragma unroll
  for (int i = 0; i < 4; ++i) {
    int sr = t - 3 + i;
    if (sr >= 0) {
      f32x2 a = *(const f32x2*)(xq + (size_t)sr * 2048 + c);
      f32x2 b = *(const f32x2*)(xk + (size_t)sr * 2048 + c);
      f32x2 d = *(const f32x2*)(xv + (size_t)sr * 2048 + c);
      aq0 = fmaf(a.x, wq0[i], aq0); aq1 = fmaf(a.y, wq1[i], aq1);
      ak0 = fmaf(b.x, wk0[i], ak0); ak1 = fmaf(b.y, wk1[i], ak1);
      av0 = fmaf(d.x, wv0[i], av0); av1 = fmaf(d.y, wv1[i], av1);
    }
  }
  float yq0 = aq0 * sigmoid_f(aq0), yq1 = aq1 * sigmoid_f(aq1);
  float yk0 = ak0 * sigmoid_f(ak0), yk1 = ak1 * sigmoid_f(ak1);
  float yv0 = av0 * sigmoid_f(av0), yv1 = av1 * sigmoid_f(av1);

  float l0 = lam[0], l1 = lam[1];
  f32x2 vev = *(const f32x2*)(ve + ((size_t)t * HN + h) * 128 + d2);
  float v0 = l0 * yv0 + l1 * vev.x;
  float v1 = l0 * yv1 + l1 * vev.y;

  float ssq = yq0 * yq0 + yq1 * yq1;
  float ssk = yk0 * yk0 + yk1 * yk1;
#pragma unroll
  for (int off = 32; off > 0; off >>= 1) {
    ssq += __shfl_xor(ssq, off);
    ssk += __shfl_xor(ssk, off);
  }
  float rq = rsqrtf(ssq + 1e-6f) * QSCALE;
  float rk = rsqrtf(ssk + 1e-6f);

  size_t o = (size_t)t * 2048 + c;
  f32x2 kk; kk.x = yk0 * rk; kk.y = yk1 * rk;
  f32x2 qq; qq.x = yq0 * rq; qq.y = yq1 * rq;
  f32x2 vv2; vv2.x = v0; vv2.y = v1;
  *(f32x2*)(karr + o) = kk;
  *(f32x2*)(qarr + o) = qq;
  *(f32x2*)(varr + o) = vv2;
}

// ---------------- chunk-local precompute (C=32), fp32 ----------------
// Per (h,chunk): G=cumsum(glog); A/B lower-tri with exp(G_t-G_i)<=1;
// forward-substitution solve (I+diag(b)A_s)[uv|W]=diag(b)[V|Khat];
// Qt = Qhat - B_low W; oloc = B_low uv; Kbar; P_C.
#define GP 129

__global__ __launch_bounds__(128) void kda_pre(
    const float* __restrict__ karr, const float* __restrict__ qarr,
    const float* __restrict__ varr, const float* __restrict__ gbuf,
    const float* __restrict__ dtb, const float* __restrict__ A_log,
    const float* __restrict__ betaT,
    __hip_bfloat16* __restrict__ Xgh, __hip_bfloat16* __restrict__ Xgl,
    __hip_bfloat16* __restrict__ KTh, __hip_bfloat16* __restrict__ KTl,
    float* __restrict__ uvS, float* __restrict__ olocS, float* __restrict__ Pg)
{
  __shared__ float kL[32 * GP], qL[32 * GP], GL[32 * GP];
  __shared__ float AL[32][33], BL[32][33], betaL[32];
  const int bid = blockIdx.x;
  const int h = bid >> 6, cc = bid & 63;
  const int tid = threadIdx.x;                 // column owner 0..127
  const size_t rowbase = (size_t)(cc * 32) * 2048 + h * 128 + tid;
  const size_t hc = (size_t)h * 64 + cc;

  const float Aexp = __expf(A_log[h]);
  const float dtv = dtb[h * 128 + tid];

  float vreg[32];
#pragma unroll
  for (int i = 0; i < 32; ++i) {
    size_t o = rowbase + (size_t)i * 2048;
    kL[i * GP + tid] = karr[o];
    qL[i * GP + tid] = qarr[o];
    vreg[i] = varr[o];
    float gv = gbuf[o] + dtv;
    float sp = (gv > 20.f) ? gv : log1pf(__expf(fminf(gv, 20.f)));
    GL[i * GP + tid] = -Aexp * sp;
  }
  if (tid < 32) betaL[tid] = betaT[(size_t)h * SEQL + cc * 32 + tid];
  // cumsum own column (no cross-thread dependency yet)
  float expg[32];
  {
    float gs = 0.f;
#pragma unroll
    for (int i = 0; i < 32; ++i) { gs += GL[i * GP + tid]; GL[i * GP + tid] = gs; expg[i] = __expf(gs); }
  }
  __syncthreads();

  // A,B lower-tri (incl diagonal) pairs
  for (int pp = tid; pp < 528; pp += 128) {
    int t = (int)((sqrtf(8.f * pp + 1.f) - 1.f) * 0.5f);
    while ((t + 1) * (t + 2) / 2 <= pp) ++t;
    while (t * (t + 1) / 2 > pp) --t;
    int i = pp - t * (t + 1) / 2;
    float sA = 0.f, sB = 0.f;
    for (int d = 0; d < 128; ++d) {
      float e = __expf(GL[t * GP + d] - GL[i * GP + d]);
      float kid = kL[i * GP + d] * e;
      sA = fmaf(kL[t * GP + d], kid, sA);
      sB = fmaf(qL[t * GP + d], kid, sB);
    }
    AL[t][i] = sA; BL[t][i] = sB;
  }
  __syncthreads();

  // forward substitution: X[r] = beta_r * (RHS[r] - sum_{j<r} A[r,j] X[j])
  float uv[32], w[32];
#pragma unroll
  for (int r = 0; r < 32; ++r) {
    float suv = 0.f, sw = 0.f;
#pragma unroll
    for (int j = 0; j < 32; ++j) {
      if (j < r) { float a = AL[r][j]; suv = fmaf(a, uv[j], suv); sw = fmaf(a, w[j], sw); }
    }
    float br = betaL[r];
    float khr = kL[r * GP + tid] * expg[r];
    uv[r] = br * (vreg[r] - suv);
    w[r] = br * (khr - sw);
    uvS[rowbase + (size_t)r * 2048] = uv[r];
    size_t xo = hc * 8192 + (size_t)(32 + r) * 128 + tid;
    __hip_bfloat16 hh = __float2bfloat16(w[r]);
    Xgh[xo] = hh;
    Xgl[xo] = __float2bfloat16(w[r] - __bfloat162float(hh));
  }

  // Qt rows + oloc rows
#pragma unroll
  for (int r = 0; r < 32; ++r) {
    float qt = qL[r * GP + tid] * expg[r];
    float ol = 0.f;
#pragma unroll
    for (int j = 0; j < 32; ++j) {
      if (j <= r) { float b = BL[r][j]; qt = fmaf(-b, w[j], qt); ol = fmaf(b, uv[j], ol); }
    }
    size_t xo = hc * 8192 + (size_t)r * 128 + tid;
    __hip_bfloat16 hh = __float2bfloat16(qt);
    Xgh[xo] = hh;
    Xgl[xo] = __float2bfloat16(qt - __bfloat162float(hh));
    olocS[rowbase + (size_t)r * 2048] = ol;
  }

  // KbarT + P
  const float g31 = GL[31 * GP + tid];
  size_t kb = hc * 4096 + (size_t)tid * 32;
#pragma unroll
  for (int i = 0; i < 32; ++i) {
    float kv = kL[i * GP + tid] * __expf(g31 - GL[i * GP + tid]);
    __hip_bfloat16 hh = __float2bfloat16(kv);
    KTh[kb + i] = hh;
    KTl[kb + i] = __float2bfloat16(kv - __bfloat162float(hh));
  }
  Pg[hc * 128 + tid] = expg[31];
}

// ---------------- sequential chunk scan: S kept in MFMA accumulators ----------------
// grid 64 = (h, dv-quarter). Per chunk: Y=[Qt;W]@S (3-pass split bf16);
// o = Y[0:32]+oloc; U = uv - Y[32:64]; S = P (.) S + KbarT @ U.
#define STP 136
#define UTP 40

__global__ __launch_bounds__(256) void kda_seq(
    const __hip_bfloat16* __restrict__ Xgh, const __hip_bfloat16* __restrict__ Xgl,
    const __hip_bfloat16* __restrict__ KTh, const __hip_bfloat16* __restrict__ KTl,
    const float* __restrict__ uvS, const float* __restrict__ olocS,
    const float* __restrict__ Pg, float* __restrict__ obuf)
{
  __shared__ __hip_bfloat16 STh[32 * STP], STl[32 * STP];
  __shared__ __hip_bfloat16 UTh[32 * UTP], UTl[32 * UTP];
  const int tid = threadIdx.x;
  const int w = tid >> 6, lane = tid & 63, l15 = lane & 15, l4 = lane >> 4;
  const int h = blockIdx.x >> 2, vq = blockIdx.x & 3;
  const int v0 = vq * 32;
  const int r0 = (w & 1) * 16 + l4 * 4;
  const int isO = (w < 2);

  for (int i = tid; i < 32 * STP; i += 256) {
    STh[i] = __float2bfloat16(0.f);
    STl[i] = __float2bfloat16(0.f);
  }
  __syncthreads();

  f32x4 S[2][2] = {};

  for (int c = 0; c < 64; ++c) {
    const size_t hc = (size_t)h * 64 + c;
    // ---- issue all global loads for this chunk early ----
    const __hip_bfloat16* xh = Xgh + hc * 8192 + (size_t)(w * 16 + l15) * 128 + l4 * 8;
    const __hip_bfloat16* xl = Xgl + hc * 8192 + (size_t)(w * 16 + l15) * 128 + l4 * 8;
    bf16x8 ah[4], al[4];
#pragma unroll
    for (int kk = 0; kk < 4; ++kk) {
      ah[kk] = *(const bf16x8*)(xh + kk * 32);
      al[kk] = *(const bf16x8*)(xl + kk * 32);
    }
    const float* pb = (isO ? olocS : uvS) + (size_t)(c * 32 + r0) * 2048 + h * 128 + v0 + l15;
    float pB[2][4];
#pragma unroll
    for (int n = 0; n < 2; ++n)
#pragma unroll
      for (int r = 0; r < 4; ++r)
        pB[n][r] = pb[(size_t)r * 2048 + n * 16];
    bf16x8 kah[2], kal[2];
    f32x4 pvv[2];
#pragma unroll
    for (int mi = 0; mi < 2; ++mi) {
      const int kd = (w * 2 + mi) * 16;
      kah[mi] = *(const bf16x8*)(KTh + hc * 4096 + (size_t)(kd + l15) * 32 + l4 * 8);
      kal[mi] = *(const bf16x8*)(KTl + hc * 4096 + (size_t)(kd + l15) * 32 + l4 * 8);
      pvv[mi] = *(const f32x4*)(Pg + hc * 128 + kd + l4 * 4);
    }

    // ---- phase A: Y = X @ S (split 3-pass) ----
    f32x4 Y[2] = {};
#pragma unroll
    for (int kk = 0; kk < 4; ++kk) {
#pragma unroll
      for (int n = 0; n < 2; ++n) {
        const int so = (n * 16 + l15) * STP + kk * 32 + l4 * 8;
        bf16x8 bh = *(const bf16x8*)(STh + so);
        bf16x8 bl = *(const bf16x8*)(STl + so);
        Y[n] = __builtin_amdgcn_mfma_f32_16x16x32_bf16(ah[kk], bh, Y[n], 0, 0, 0);
        Y[n] = __builtin_amdgcn_mfma_f32_16x16x32_bf16(ah[kk], bl, Y[n], 0, 0, 0);
        Y[n] = __builtin_amdgcn_mfma_f32_16x16x32_bf16(al[kk], bh, Y[n], 0, 0, 0);
      }
    }

    // ---- phase B: o-out (waves 0,1) / U -> LDS (waves 2,3) ----
    if (isO) {
#pragma unroll
      for (int n = 0; n < 2; ++n) {
        size_t ob = (size_t)(c * 32 + r0) * 2048 + h * 128 + v0 + n * 16 + l15;
#pragma unroll
        for (int r = 0; r < 4; ++r)
          obuf[ob + (size_t)r * 2048] = Y[n][r] + pB[n][r];
      }
    } else {
#pragma unroll
      for (int n = 0; n < 2; ++n) {
        union { __hip_bfloat16 b[4]; unsigned long long u; } uh, ul;
#pragma unroll
        for (int r = 0; r < 4; ++r) {
          float uu = pB[n][r] - Y[n][r];
          __hip_bfloat16 hh = __float2bfloat16(uu);
          uh.b[r] = hh;
          ul.b[r] = __float2bfloat16(uu - __bfloat162float(hh));
        }
        *(unsigned long long*)(UTh + (n * 16 + l15) * UTP + r0) = uh.u;
        *(unsigned long long*)(UTl + (n * 16 + l15) * UTP + r0) = ul.u;
      }
    }
    __syncthreads();

    // ---- phase C: S = P (.) S + KbarT @ U ----
#pragma unroll
    for (int mi = 0; mi < 2; ++mi)
#pragma unroll
      for (int n = 0; n < 2; ++n)
        S[mi][n] *= pvv[mi];
#pragma unroll
    for (int n = 0; n < 2; ++n) {
      const int uo = (n * 16 + l15) * UTP + l4 * 8;
      bf16x8 ubh = *(const bf16x8*)(UTh + uo);
      bf16x8 ubl = *(const bf16x8*)(UTl + uo);
#pragma unroll
      for (int mi = 0; mi < 2; ++mi) {
        S[mi][n] = __builtin_amdgcn_mfma_f32_16x16x32_bf16(kah[mi], ubh, S[mi][n], 0, 0, 0);
        S[mi][n] = __builtin_amdgcn_mfma_f32_16x16x32_bf16(kah[mi], ubl, S[mi][n], 0, 0, 0);
        S[mi][n] = __builtin_amdgcn_mfma_f32_16x16x32_bf16(kal[mi], ubh, S[mi][n], 0, 0, 0);
      }
    }

    // ---- phase D: refresh operand view of S in LDS ----
#pragma unroll
    for (int mi = 0; mi < 2; ++mi) {
      const int kd0 = (w * 2 + mi) * 16 + l4 * 4;
#pragma unroll
      for (int n = 0; n < 2; ++n) {
        union { __hip_bfloat16 b[4]; unsigned long long u; } sh, sl;
#pragma unroll
        for (int r = 0; r < 4; ++r) {
          __hip_bfloat16 hh = __float2bfloat16(S[mi][n][r]);
          sh.b[r] = hh;
          sl.b[r] = __float2bfloat16(S[mi][n][r] - __bfloat162float(hh));
        }
        *(unsigned long long*)(STh + (n * 16 + l15) * STP + kd0) = sh.u;
        *(unsigned long long*)(STl + (n * 16 + l15) * STP + kd0) = sl.u;
      }
    }
    __syncthreads();
  }
}

// ---------------- sigmoid-gated RMSNorm -> bf16 ----------------
__global__ __launch_bounds__(256) void rmsgate_kernel(
    const float* __restrict__ o, const float* __restrict__ gate,
    const float* __restrict__ bg2, const float* __restrict__ norm_w,
    __hip_bfloat16* __restrict__ og)
{
  int row = blockIdx.x * 4 + (threadIdx.x >> 6);   // s*16 + h
  int lane = threadIdx.x & 63;
  int s = row >> 4, h = row & 15;
  int j = lane * 2;
  const float* p = o + (size_t)row * 128 + j;
  f32x2 v = *(const f32x2*)p;
  float ss = v.x * v.x + v.y * v.y;
#pragma unroll
  for (int off = 32; off > 0; off >>= 1) ss += __shfl_xor(ss, off);
  float rs = rsqrtf(ss * (1.f / 128.f) + 1e-6f);
  int c = h * 128 + j;
  float g0 = gate[(size_t)s * 2048 + c] + bg2[c];
  float g1 = gate[(size_t)s * 2048 + c + 1] + bg2[c + 1];
  float o0 = v.x * rs * norm_w[j] * (1.f / (1.f + expf(-g0)));
  float o1 = v.y * rs * norm_w[j + 1] * (1.f / (1.f + expf(-g1)));
  union { __hip_bfloat16 b[2]; unsigned int u; } pk2;
  pk2.b[0] = __float2bfloat16(o0);
  pk2.b[1] = __float2bfloat16(o1);
  *(unsigned int*)((char*)og + ((size_t)s * 2048 + c) * 2) = pk2.u;
}

// =====================================================================
extern "C" void kernel_launch(void* const* d_in, const int* in_sizes, int n_in,
                              void* d_out, int out_size, void* d_ws, size_t ws_size,
                              hipStream_t stream)
{
  const float* x      = (const float*)d_in[0];
  const float* ve     = (const float*)d_in[1];
  const float* lam    = (const float*)d_in[2];
  const float* Wq     = (const float*)d_in[3];
  const float* Wk     = (const float*)d_in[4];
  const float* Wv     = (const float*)d_in[5];
  const float* cwq    = (const float*)d_in[6];
  const float* cwk    = (const float*)d_in[7];
  const float* cwv    = (const float*)d_in[8];
  const float* Wf1    = (const float*)d_in[9];
  const float* Wf2    = (const float*)d_in[10];
  const float* Wb     = (const float*)d_in[11];
  const float* A_log  = (const float*)d_in[12];
  const float* dtb    = (const float*)d_in[13];
  const float* Wg1    = (const float*)d_in[14];
  const float* Wg2    = (const float*)d_in[15];
  const float* bg2    = (const float*)d_in[16];
  const float* norm_w = (const float*)d_in[17];
  const float* Wo     = (const float*)d_in[18];
  float* out = (float*)d_out;

  const size_t S2 = (size_t)2048 * 2048;

  char* p = (char*)d_ws;
  auto alloc = [&](size_t bytes) { char* r = p; p += (bytes + 255) & ~(size_t)255; return r; };

  __hip_bfloat16* xb    = (__hip_bfloat16*)alloc(S2 * 2);
  __hip_bfloat16* WoT   = (__hip_bfloat16*)alloc(S2 * 2);
  __hip_bfloat16* Wf1hT = (__hip_bfloat16*)alloc(2048 * 128 * 2);
  __hip_bfloat16* Wf1lT = (__hip_bfloat16*)alloc(2048 * 128 * 2);
  __hip_bfloat16* Wf2hT = (__hip_bfloat16*)alloc(2048 * 128 * 2);
  __hip_bfloat16* Wf2lT = (__hip_bfloat16*)alloc(2048 * 128 * 2);
  __hip_bfloat16* Wg1T  = (__hip_bfloat16*)alloc(2048 * 128 * 2);
  __hip_bfloat16* Wg2T  = (__hip_bfloat16*)alloc(2048 * 128 * 2);
  __hip_bfloat16* f1h   = (__hip_bfloat16*)alloc(2048 * 128 * 2);
  __hip_bfloat16* f1l   = (__hip_bfloat16*)alloc(2048 * 128 * 2);
  __hip_bfloat16* g1b   = (__hip_bfloat16*)alloc(2048 * 128 * 2);
  float* betaT = (float*)alloc((size_t)2048 * 16 * 4);
  float* xq    = (float*)alloc(S2 * 4);
  float* xk    = (float*)alloc(S2 * 4);
  float* xv    = (float*)alloc(S2 * 4);
  float* gbuf  = (float*)alloc(S2 * 4);
  float* fpart = (float*)alloc((size_t)8 * 2048 * 128 * 4);
  float* karr  = (float*)alloc(S2 * 4);
  float* qarr  = (float*)alloc(S2 * 4);
  float* varr  = (float*)alloc(S2 * 4);
  float* Pg    = (float*)alloc((size_t)1024 * 128 * 4);

  // overlays (timeline-checked):
  __hip_bfloat16* WqT = (__hip_bfloat16*)karr;                       // dead after proj GEMMs
  __hip_bfloat16* WkT = (__hip_bfloat16*)((char*)karr + S2 * 2);
  __hip_bfloat16* WvT = (__hip_bfloat16*)qarr;
  __hip_bfloat16* xlo = (__hip_bfloat16*)((char*)qarr + S2 * 2);     // dead after f-path
  __hip_bfloat16* Xgh = (__hip_bfloat16*)xq;                         // after prep, xq dead
  __hip_bfloat16* Xgl = (__hip_bfloat16*)xk;
  __hip_bfloat16* KTh = (__hip_bfloat16*)xv;
  __hip_bfloat16* KTl = (__hip_bfloat16*)fpart;                      // dead after f-path; revived for gate path after kda_seq
  float* uvS   = karr;    // o-layout overlay, written by kda_pre after it loads karr
  float* olocS = varr;
  float* obuf  = gbuf;    // gbuf dead after kda_pre
  float* gatebuf = xk;    // after kda_seq, Xgl dead
  __hip_bfloat16* og = (__hip_bfloat16*)karr;  // after kda_seq, uvS dead

  // 1. split-cast x
  cast_split_kernel<<<4096, 256, 0, stream>>>(x, xb, xlo, (int)(S2 / 4));

  // 2. weight transposes
  transpose_cast_kernel<<<dim3(64, 64), 256, 0, stream>>>(Wq, WqT, nullptr, 2048, 2048);
  transpose_cast_kernel<<<dim3(64, 64), 256, 0, stream>>>(Wk, WkT, nullptr, 2048, 2048);
  transpose_cast_kernel<<<dim3(64, 64), 256, 0, stream>>>(Wv, WvT, nullptr, 2048, 2048);
  transpose_cast_kernel<<<dim3(64, 64), 256, 0, stream>>>(Wo, WoT, nullptr, 2048, 2048);
  transpose_cast_kernel<<<dim3(4, 64), 256, 0, stream>>>(Wf1, Wf1hT, Wf1lT, 2048, 128);
  transpose_cast_kernel<<<dim3(64, 4), 256, 0, stream>>>(Wf2, Wf2hT, Wf2lT, 128, 2048);
  transpose_cast_kernel<<<dim3(4, 64), 256, 0, stream>>>(Wg1, Wg1T, nullptr, 2048, 128);
  transpose_cast_kernel<<<dim3(64, 4), 256, 0, stream>>>(Wg2, Wg2T, nullptr, 128, 2048);

  // 3. projection GEMMs
  gemm_bt<<<dim3(16, 16), 256, 0, stream>>>(xb, WqT, xq, 2048, 2048, 2048, 2048, 0);
  gemm_bt<<<dim3(16, 16), 256, 0, stream>>>(xb, WkT, xk, 2048, 2048, 2048, 2048, 0);
  gemm_bt<<<dim3(16, 16), 256, 0, stream>>>(xb, WvT, xv, 2048, 2048, 2048, 2048, 0);

  // 4. f-path: f1 = x @ Wf1 (split precision, split-K z=8); g = f1 @ Wf2 (split)
  gemm_bt<<<dim3(1, 16, 8), 256, 0, stream>>>(xb,  Wf1hT, fpart, 2048, 128, 2048, 256, 0);
  gemm_bt<<<dim3(1, 16, 8), 256, 0, stream>>>(xlo, Wf1hT, fpart, 2048, 128, 2048, 256, 1);
  gemm_bt<<<dim3(1, 16, 8), 256, 0, stream>>>(xb,  Wf1lT, fpart, 2048, 128, 2048, 256, 1);
  reduce8_kernel<<<256, 256, 0, stream>>>(fpart, f1h, f1l, 65536);
  gemm_bt<<<dim3(16, 16), 256, 0, stream>>>(f1h, Wf2hT, gbuf, 2048, 2048, 128, 128, 0);
  gemm_bt<<<dim3(16, 16), 256, 0, stream>>>(f1l, Wf2hT, gbuf, 2048, 2048, 128, 128, 1);
  gemm_bt<<<dim3(16, 16), 256, 0, stream>>>(f1h, Wf2lT, gbuf, 2048, 2048, 128, 128, 1);

  // 5. beta
  beta_kernel<<<128, 256, 0, stream>>>(x, Wb, betaT);

  // 6. prep (conv+silu+mix+l2norm) -> plain arrays (overwrites WqT/WkT/WvT/xlo overlays)
  prep_plain<<<HN * SEQL, 64, 0, stream>>>(xq, xk, xv, ve, lam, cwq, cwk, cwv, karr, qarr, varr);

  // 7. chunk-local precompute
  kda_pre<<<1024, 128, 0, stream>>>(karr, qarr, varr, gbuf, dtb, A_log, betaT,
                                    Xgh, Xgl, KTh, KTl, uvS, olocS, Pg);

  // 8. sequential chunk scan
  kda_seq<<<64, 256, 0, stream>>>(Xgh, Xgl, KTh, KTl, uvS, olocS, Pg, obuf);

  // 9. gate path (after kda_seq so xk/fpart overlays are dead)
  gemm_bt<<<dim3(1, 16, 8), 256, 0, stream>>>(xb, Wg1T, fpart, 2048, 128, 2048, 256, 0);
  reduce8_kernel<<<256, 256, 0, stream>>>(fpart, g1b, nullptr, 65536);
  gemm_bt<<<dim3(16, 16), 256, 0, stream>>>(g1b, Wg2T, gatebuf, 2048, 2048, 128, 128, 0);

  // 10. gated rmsnorm -> bf16
  rmsgate_kernel<<<8192, 256, 0, stream>>>(obuf, gatebuf, bg2, norm_w, og);

  // 11. output projection
  gemm_bt<<<dim3(16, 16), 256, 0, stream>>>(og, WoT, out, 2048, 2048, 2048, 2048, 0);
}

// Round 5
// 511.269 us; speedup vs baseline: 1.8861x; 1.3180x over previous
//
#include <hip/hip_runtime.h>
#include <hip/hip_bf16.h>
#include <stdint.h>
#include <stddef.h>

#define SEQL 2048
#define DIMSZ 2048
#define HN 16
#define DKD 128
#define DVD 128
#define QSCALE 0.08838834764831843f   // 128^-0.5

typedef __attribute__((ext_vector_type(4))) float f32x4;
typedef __attribute__((ext_vector_type(2))) float f32x2;
typedef __attribute__((ext_vector_type(8))) short bf16x8;

__device__ __forceinline__ float sigmoid_f(float x) { return 1.f / (1.f + __expf(-x)); }

// ---------------- bf16 GEMM: C[M,N] (f32) = A[M,K]bf16 @ Bt[N,K]bf16 ----------------
#define BM 128
#define BN 128
#define BKK 64

__global__ __launch_bounds__(256) void gemm_bt(
    const __hip_bfloat16* __restrict__ A, const __hip_bfloat16* __restrict__ B,
    float* __restrict__ C, int M, int N, int lda, int klen, int accum)
{
  __shared__ __hip_bfloat16 As[BM * BKK];
  __shared__ __hip_bfloat16 Bs[BN * BKK];
  const int tid = threadIdx.x;
  const int lane = tid & 63;
  const int w = tid >> 6;
  const int wm = w >> 1, wn = w & 1;            // 2x2 wave grid, 64x64 each
  const int m0 = blockIdx.y * BM, n0 = blockIdx.x * BN;
  const int l15 = lane & 15, l4 = lane >> 4;
  const int kbase = blockIdx.z * klen;

  f32x4 acc[4][4] = {};

  for (int k0 = kbase; k0 < kbase + klen; k0 += BKK) {
#pragma unroll
    for (int i = 0; i < 4; ++i) {
      const int c = (w * 4 + i) * 64 + lane;     // chunk id, 16B each; 8 chunks/row
      const int row = c >> 3;
      const int colb = (c & 7) * 8;
      __builtin_amdgcn_global_load_lds(
          (const __attribute__((address_space(1))) void*)(A + (size_t)(m0 + row) * lda + k0 + colb),
          (__attribute__((address_space(3))) void*)(As + (size_t)c * 8), 16, 0, 0);
      __builtin_amdgcn_global_load_lds(
          (const __attribute__((address_space(1))) void*)(B + (size_t)(n0 + row) * lda + k0 + colb),
          (__attribute__((address_space(3))) void*)(Bs + (size_t)c * 8), 16, 0, 0);
    }
    __syncthreads();
#pragma unroll
    for (int kk = 0; kk < BKK; kk += 32) {
      bf16x8 af[4], bfv[4];
#pragma unroll
      for (int mi = 0; mi < 4; ++mi)
        af[mi] = *(const bf16x8*)(As + (wm * 64 + mi * 16 + l15) * BKK + kk + l4 * 8);
#pragma unroll
      for (int ni = 0; ni < 4; ++ni)
        bfv[ni] = *(const bf16x8*)(Bs + (wn * 64 + ni * 16 + l15) * BKK + kk + l4 * 8);
#pragma unroll
      for (int mi = 0; mi < 4; ++mi)
#pragma unroll
        for (int ni = 0; ni < 4; ++ni)
          acc[mi][ni] = __builtin_amdgcn_mfma_f32_16x16x32_bf16(af[mi], bfv[ni], acc[mi][ni], 0, 0, 0);
    }
    __syncthreads();
  }

  float* Cz = C + (size_t)blockIdx.z * M * N;
#pragma unroll
  for (int mi = 0; mi < 4; ++mi) {
#pragma unroll
    for (int ni = 0; ni < 4; ++ni) {
      const int row = m0 + wm * 64 + mi * 16 + l4 * 4;
      const int col = n0 + wn * 64 + ni * 16 + l15;
#pragma unroll
      for (int r = 0; r < 4; ++r) {
        size_t idx = (size_t)(row + r) * N + col;
        if (accum) Cz[idx] += acc[mi][ni][r];
        else Cz[idx] = acc[mi][ni][r];
      }
    }
  }
}

// ---------------- fused split-precision GEMM: C = Ah@Bh + Ah@Bl + Al@Bh ----------------
__global__ __launch_bounds__(256) void gemm_btsplit(
    const __hip_bfloat16* __restrict__ Ah, const __hip_bfloat16* __restrict__ Al,
    const __hip_bfloat16* __restrict__ Bh, const __hip_bfloat16* __restrict__ Bl,
    float* __restrict__ C, int M, int N, int lda, int klen)
{
  __shared__ __hip_bfloat16 Ash[BM * BKK];
  __shared__ __hip_bfloat16 Asl[BM * BKK];
  __shared__ __hip_bfloat16 Bsh[BN * BKK];
  __shared__ __hip_bfloat16 Bsl[BN * BKK];
  const int tid = threadIdx.x;
  const int lane = tid & 63;
  const int w = tid >> 6;
  const int wm = w >> 1, wn = w & 1;
  const int m0 = blockIdx.y * BM, n0 = blockIdx.x * BN;
  const int l15 = lane & 15, l4 = lane >> 4;
  const int kbase = blockIdx.z * klen;

  f32x4 acc[4][4] = {};

  for (int k0 = kbase; k0 < kbase + klen; k0 += BKK) {
#pragma unroll
    for (int i = 0; i < 4; ++i) {
      const int c = (w * 4 + i) * 64 + lane;
      const int row = c >> 3;
      const int colb = (c & 7) * 8;
      const size_t go = (size_t)(m0 + row) * lda + k0 + colb;
      const size_t gn = (size_t)(n0 + row) * lda + k0 + colb;
      __builtin_amdgcn_global_load_lds(
          (const __attribute__((address_space(1))) void*)(Ah + go),
          (__attribute__((address_space(3))) void*)(Ash + (size_t)c * 8), 16, 0, 0);
      __builtin_amdgcn_global_load_lds(
          (const __attribute__((address_space(1))) void*)(Al + go),
          (__attribute__((address_space(3))) void*)(Asl + (size_t)c * 8), 16, 0, 0);
      __builtin_amdgcn_global_load_lds(
          (const __attribute__((address_space(1))) void*)(Bh + gn),
          (__attribute__((address_space(3))) void*)(Bsh + (size_t)c * 8), 16, 0, 0);
      __builtin_amdgcn_global_load_lds(
          (const __attribute__((address_space(1))) void*)(Bl + gn),
          (__attribute__((address_space(3))) void*)(Bsl + (size_t)c * 8), 16, 0, 0);
    }
    __syncthreads();
#pragma unroll
    for (int kk = 0; kk < BKK; kk += 32) {
      bf16x8 afh[4], afl[4], bfh[4], bfl[4];
#pragma unroll
      for (int mi = 0; mi < 4; ++mi) {
        const int ao = (wm * 64 + mi * 16 + l15) * BKK + kk + l4 * 8;
        afh[mi] = *(const bf16x8*)(Ash + ao);
        afl[mi] = *(const bf16x8*)(Asl + ao);
      }
#pragma unroll
      for (int ni = 0; ni < 4; ++ni) {
        const int bo = (wn * 64 + ni * 16 + l15) * BKK + kk + l4 * 8;
        bfh[ni] = *(const bf16x8*)(Bsh + bo);
        bfl[ni] = *(const bf16x8*)(Bsl + bo);
      }
#pragma unroll
      for (int mi = 0; mi < 4; ++mi)
#pragma unroll
        for (int ni = 0; ni < 4; ++ni) {
          acc[mi][ni] = __builtin_amdgcn_mfma_f32_16x16x32_bf16(afh[mi], bfh[ni], acc[mi][ni], 0, 0, 0);
          acc[mi][ni] = __builtin_amdgcn_mfma_f32_16x16x32_bf16(afh[mi], bfl[ni], acc[mi][ni], 0, 0, 0);
          acc[mi][ni] = __builtin_amdgcn_mfma_f32_16x16x32_bf16(afl[mi], bfh[ni], acc[mi][ni], 0, 0, 0);
        }
    }
    __syncthreads();
  }

  float* Cz = C + (size_t)blockIdx.z * M * N;
#pragma unroll
  for (int mi = 0; mi < 4; ++mi) {
#pragma unroll
    for (int ni = 0; ni < 4; ++ni) {
      const int row = m0 + wm * 64 + mi * 16 + l4 * 4;
      const int col = n0 + wn * 64 + ni * 16 + l15;
#pragma unroll
      for (int r = 0; r < 4; ++r)
        Cz[(size_t)(row + r) * N + col] = acc[mi][ni][r];
    }
  }
}

// ---------------- transpose + cast (optional hi/lo split): out[C,R] = bf16(in[R,C]^T) ----------------
__global__ __launch_bounds__(256) void transpose_cast_kernel(
    const float* __restrict__ in, __hip_bfloat16* __restrict__ outT,
    __hip_bfloat16* __restrict__ outLo, int R, int C)
{
  __shared__ float tile[32][33];
  const int c0 = blockIdx.x * 32, r0 = blockIdx.y * 32;
  const int tc = threadIdx.x & 31, tr = threadIdx.x >> 5;   // tr in 0..7
#pragma unroll
  for (int i = 0; i < 4; ++i)
    tile[tr + i * 8][tc] = in[(size_t)(r0 + tr + i * 8) * C + c0 + tc];
  __syncthreads();
#pragma unroll
  for (int i = 0; i < 4; ++i) {
    float val = tile[tc][tr + i * 8];
    __hip_bfloat16 h = __float2bfloat16(val);
    size_t oi = (size_t)(c0 + tr + i * 8) * R + r0 + tc;
    outT[oi] = h;
    if (outLo) outLo[oi] = __float2bfloat16(val - __bfloat162float(h));
  }
}

// ---------------- elementwise cast with optional lo residual ----------------
__global__ __launch_bounds__(256) void cast_split_kernel(
    const float* __restrict__ in, __hip_bfloat16* __restrict__ hi,
    __hip_bfloat16* __restrict__ lo, int n4)
{
  int idx = blockIdx.x * 256 + threadIdx.x;
  if (idx >= n4) return;
  f32x4 v = *(const f32x4*)(in + (size_t)idx * 4);
  union { __hip_bfloat16 b[4]; unsigned long long u; } ph, pl;
#pragma unroll
  for (int j = 0; j < 4; ++j) {
    float f = v[j];
    __hip_bfloat16 hh = __float2bfloat16(f);
    ph.b[j] = hh;
    pl.b[j] = __float2bfloat16(f - __bfloat162float(hh));
  }
  *(unsigned long long*)((char*)hi + (size_t)idx * 8) = ph.u;
  if (lo) *(unsigned long long*)((char*)lo + (size_t)idx * 8) = pl.u;
}

// ---------------- split-K reduce (8 partials) -> bf16 hi (+ optional lo) ----------------
__global__ __launch_bounds__(256) void reduce8_kernel(
    const float* __restrict__ part, __hip_bfloat16* __restrict__ hi,
    __hip_bfloat16* __restrict__ lo, int n4)
{
  int idx = blockIdx.x * 256 + threadIdx.x;
  if (idx >= n4) return;
  const size_t chunk = (size_t)SEQL * DVD;   // 2048*128
  f32x4 a = *(const f32x4*)(part + (size_t)idx * 4);
#pragma unroll
  for (int z = 1; z < 8; ++z) {
    f32x4 b = *(const f32x4*)(part + z * chunk + (size_t)idx * 4);
    a.x += b.x; a.y += b.y; a.z += b.z; a.w += b.w;
  }
  union { __hip_bfloat16 b[4]; unsigned long long u; } ph, pl;
#pragma unroll
  for (int j = 0; j < 4; ++j) {
    float f = a[j];
    __hip_bfloat16 hh = __float2bfloat16(f);
    ph.b[j] = hh;
    pl.b[j] = __float2bfloat16(f - __bfloat162float(hh));
  }
  *(unsigned long long*)((char*)hi + (size_t)idx * 8) = ph.u;
  if (lo) *(unsigned long long*)((char*)lo + (size_t)idx * 8) = pl.u;
}

// ---------------- beta = sigmoid(x @ Wb), thread per (s,h); writes [h][s] ----------------
__global__ __launch_bounds__(256) void beta_kernel(
    const float* __restrict__ x, const float* __restrict__ Wb, float* __restrict__ betaT)
{
  int idx = blockIdx.x * 256 + threadIdx.x;      // 0..32767
  int s = idx >> 4, h = idx & 15;
  const float* xr = x + (size_t)s * DIMSZ;
  float acc = 0.f;
  for (int d = 0; d < DIMSZ; d += 4) {
    f32x4 xv = *(const f32x4*)(xr + d);
    acc = fmaf(xv.x, Wb[(size_t)(d + 0) * HN + h], acc);
    acc = fmaf(xv.y, Wb[(size_t)(d + 1) * HN + h], acc);
    acc = fmaf(xv.z, Wb[(size_t)(d + 2) * HN + h], acc);
    acc = fmaf(xv.w, Wb[(size_t)(d + 3) * HN + h], acc);
  }
  betaT[(size_t)h * SEQL + s] = 1.f / (1.f + expf(-acc));
}

// ---------------- fused conv+silu+mix+l2norm -> plain arrays [s][h*128+d] ----------------
__global__ __launch_bounds__(64) void prep_plain(
    const float* __restrict__ xq, const float* __restrict__ xk, const float* __restrict__ xv,
    int xstr,
    const float* __restrict__ ve, const float* __restrict__ lam,
    const float* __restrict__ cwq, const float* __restrict__ cwk, const float* __restrict__ cwv,
    float* __restrict__ karr, float* __restrict__ qarr, float* __restrict__ varr)
{
  const int bid = blockIdx.x;          // h*2048 + t
  const int h = bid >> 11, t = bid & 2047;
  const int d2 = threadIdx.x * 2;      // channels d2, d2+1 of this head
  const int c = h * 128 + d2;

  f32x4 wq0 = *(const f32x4*)(cwq + (size_t)c * 4), wq1 = *(const f32x4*)(cwq + (size_t)(c + 1) * 4);
  f32x4 wk0 = *(const f32x4*)(cwk + (size_t)c * 4), wk1 = *(const f32x4*)(cwk + (size_t)(c + 1) * 4);
  f32x4 wv0 = *(const f32x4*)(cwv + (size_t)c * 4), wv1 = *(const f32x4*)(cwv + (size_t)(c + 1) * 4);

  float aq0 = 0, aq1 = 0, ak0 = 0, ak1 = 0, av0 = 0, av1 = 0;
#pragma unroll
  for (int i = 0; i < 4; ++i) {
    int sr = t - 3 + i;
    if (sr >= 0) {
      f32x2 a = *(const f32x2*)(xq + (size_t)sr * xstr + c);
      f32x2 b = *(const f32x2*)(xk + (size_t)sr * xstr + c);
      f32x2 d = *(const f32x2*)(xv + (size_t)sr * xstr + c);
      aq0 = fmaf(a.x, wq0[i], aq0); aq1 = fmaf(a.y, wq1[i], aq1);
      ak0 = fmaf(b.x, wk0[i], ak0); ak1 = fmaf(b.y, wk1[i], ak1);
      av0 = fmaf(d.x, wv0[i], av0); av1 = fmaf(d.y, wv1[i], av1);
    }
  }
  float yq0 = aq0 * sigmoid_f(aq0), yq1 = aq1 * sigmoid_f(aq1);
  float yk0 = ak0 * sigmoid_f(ak0), yk1 = ak1 * sigmoid_f(ak1);
  float yv0 = av0 * sigmoid_f(av0), yv1 = av1 * sigmoid_f(av1);

  float l0 = lam[0], l1 = lam[1];
  f32x2 vev = *(const f32x2*)(ve + ((size_t)t * HN + h) * 128 + d2);
  float v0 = l0 * yv0 + l1 * vev.x;
  float v1 = l0 * yv1 + l1 * vev.y;

  float ssq = yq0 * yq0 + yq1 * yq1;
  float ssk = yk0 * yk0 + yk1 * yk1;
#pragma unroll
  for (int off = 32; off > 0; off >>= 1) {
    ssq += __shfl_xor(ssq, off);
    ssk += __shfl_xor(ssk, off);
  }
  float rq = rsqrtf(ssq + 1e-6f) * QSCALE;
  float rk = rsqrtf(ssk + 1e-6f);

  size_t o = (size_t)t * 2048 + c;
  f32x2 kk; kk.x = yk0 * rk; kk.y = yk1 * rk;
  f32x2 qq; qq.x = yq0 * rq; qq.y = yq1 * rq;
  f32x2 vv2; vv2.x = v0; vv2.y = v1;
  *(f32x2*)(karr + o) = kk;
  *(f32x2*)(qarr + o) = qq;
  *(f32x2*)(varr + o) = vv2;
}

// ---------------- chunk-local precompute (C=32), fp32 ----------------
#define GP 129

__global__ __launch_bounds__(128) void kda_pre(
    const float* __restrict__ karr, const float* __restrict__ qarr,
    const float* __restrict__ varr, const float* __restrict__ gbuf,
    const float* __restrict__ dtb, const float* __restrict__ A_log,
    const float* __restrict__ betaT,
    __hip_bfloat16* __restrict__ Xgh, __hip_bfloat16* __restrict__ KTh,
    float* __restrict__ uvS, float* __restrict__ olocS, float* __restrict__ Pg)
{
  __shared__ float kL[32 * GP], qL[32 * GP], GL[32 * GP];
  __shared__ float AL[32][33], BL[32][33], betaL[32];
  const int bid = blockIdx.x;
  const int h = bid >> 6, cc = bid & 63;
  const int tid = threadIdx.x;                 // column owner 0..127
  const size_t rowbase = (size_t)(cc * 32) * 2048 + h * 128 + tid;
  const size_t hc = (size_t)h * 64 + cc;

  const float Aexp = __expf(A_log[h]);
  const float dtv = dtb[h * 128 + tid];

  float vreg[32];
#pragma unroll
  for (int i = 0; i < 32; ++i) {
    size_t o = rowbase + (size_t)i * 2048;
    kL[i * GP + tid] = karr[o];
    qL[i * GP + tid] = qarr[o];
    vreg[i] = varr[o];
    float gv = gbuf[o] + dtv;
    float sp = (gv > 20.f) ? gv : log1pf(__expf(fminf(gv, 20.f)));
    GL[i * GP + tid] = -Aexp * sp;
  }
  if (tid < 32) betaL[tid] = betaT[(size_t)h * SEQL + cc * 32 + tid];
  float expg[32];
  {
    float gs = 0.f;
#pragma unroll
    for (int i = 0; i < 32; ++i) { gs += GL[i * GP + tid]; GL[i * GP + tid] = gs; expg[i] = __expf(gs); }
  }
  __syncthreads();

  // A,B lower-tri (incl diagonal) pairs
  for (int pp = tid; pp < 528; pp += 128) {
    int t = (int)((sqrtf(8.f * pp + 1.f) - 1.f) * 0.5f);
    while ((t + 1) * (t + 2) / 2 <= pp) ++t;
    while (t * (t + 1) / 2 > pp) --t;
    int i = pp - t * (t + 1) / 2;
    float sA = 0.f, sB = 0.f;
    for (int d = 0; d < 128; ++d) {
      float e = __expf(GL[t * GP + d] - GL[i * GP + d]);
      float kid = kL[i * GP + d] * e;
      sA = fmaf(kL[t * GP + d], kid, sA);
      sB = fmaf(qL[t * GP + d], kid, sB);
    }
    AL[t][i] = sA; BL[t][i] = sB;
  }
  __syncthreads();

  // forward substitution
  float uv[32], w[32];
#pragma unroll
  for (int r = 0; r < 32; ++r) {
    float suv = 0.f, sw = 0.f;
#pragma unroll
    for (int j = 0; j < 32; ++j) {
      if (j < r) { float a = AL[r][j]; suv = fmaf(a, uv[j], suv); sw = fmaf(a, w[j], sw); }
    }
    float br = betaL[r];
    float khr = kL[r * GP + tid] * expg[r];
    uv[r] = br * (vreg[r] - suv);
    w[r] = br * (khr - sw);
    uvS[rowbase + (size_t)r * 2048] = uv[r];
    Xgh[hc * 8192 + (size_t)(32 + r) * 128 + tid] = __float2bfloat16(w[r]);
  }

  // Qt rows + oloc rows
#pragma unroll
  for (int r = 0; r < 32; ++r) {
    float qt = qL[r * GP + tid] * expg[r];
    float ol = 0.f;
#pragma unroll
    for (int j = 0; j < 32; ++j) {
      if (j <= r) { float b = BL[r][j]; qt = fmaf(-b, w[j], qt); ol = fmaf(b, uv[j], ol); }
    }
    Xgh[hc * 8192 + (size_t)r * 128 + tid] = __float2bfloat16(qt);
    olocS[rowbase + (size_t)r * 2048] = ol;
  }

  // KbarT + P
  const float g31 = GL[31 * GP + tid];
  size_t kb = hc * 4096 + (size_t)tid * 32;
#pragma unroll
  for (int i = 0; i < 32; ++i) {
    float kv = kL[i * GP + tid] * __expf(g31 - GL[i * GP + tid]);
    KTh[kb + i] = __float2bfloat16(kv);
  }
  Pg[hc * 128 + tid] = expg[31];
}

// ---------------- sequential chunk scan: S in MFMA accumulators, reg-prefetched ----------------
#define STP 136
#define UTP 40

struct ChunkOps {
  bf16x8 ah[4];
  bf16x8 kah[2];
  f32x4 pvv[2];
  float pB[2][4];
};

__global__ __launch_bounds__(256) void kda_seq(
    const __hip_bfloat16* __restrict__ Xgh, const __hip_bfloat16* __restrict__ KTh,
    const float* __restrict__ uvS, const float* __restrict__ olocS,
    const float* __restrict__ Pg, float* __restrict__ obuf)
{
  __shared__ __hip_bfloat16 STh[32 * STP], STl[32 * STP];
  __shared__ __hip_bfloat16 UTh[32 * UTP];
  const int tid = threadIdx.x;
  const int w = tid >> 6, lane = tid & 63, l15 = lane & 15, l4 = lane >> 4;
  const int h = blockIdx.x >> 2, vq = blockIdx.x & 3;
  const int v0 = vq * 32;
  const int r0 = (w & 1) * 16 + l4 * 4;
  const int isO = (w < 2);

  for (int i = tid; i < 32 * STP; i += 256) {
    STh[i] = __float2bfloat16(0.f);
    STl[i] = __float2bfloat16(0.f);
  }
  __syncthreads();

  f32x4 S[2][2] = {};

  auto loadops = [&](ChunkOps& o, int c) {
    const size_t hc = (size_t)h * 64 + c;
    const __hip_bfloat16* xh = Xgh + hc * 8192 + (size_t)(w * 16 + l15) * 128 + l4 * 8;
#pragma unroll
    for (int kk = 0; kk < 4; ++kk) o.ah[kk] = *(const bf16x8*)(xh + kk * 32);
    const float* pb = (isO ? olocS : uvS) + (size_t)(c * 32 + r0) * 2048 + h * 128 + v0 + l15;
#pragma unroll
    for (int n = 0; n < 2; ++n)
#pragma unroll
      for (int r = 0; r < 4; ++r) o.pB[n][r] = pb[(size_t)r * 2048 + n * 16];
#pragma unroll
    for (int mi = 0; mi < 2; ++mi) {
      const int kd = (w * 2 + mi) * 16;
      o.kah[mi] = *(const bf16x8*)(KTh + hc * 4096 + (size_t)(kd + l15) * 32 + l4 * 8);
      o.pvv[mi] = *(const f32x4*)(Pg + hc * 128 + kd + l4 * 4);
    }
  };

  auto body = [&](ChunkOps& o, int c) {
    // ---- phase A: Y = X @ (Sh + Sl) ----
    f32x4 Y[2] = {};
#pragma unroll
    for (int kk = 0; kk < 4; ++kk)
#pragma unroll
      for (int n = 0; n < 2; ++n) {
        const int so = (n * 16 + l15) * STP + kk * 32 + l4 * 8;
        bf16x8 bh = *(const bf16x8*)(STh + so);
        bf16x8 bl = *(const bf16x8*)(STl + so);
        Y[n] = __builtin_amdgcn_mfma_f32_16x16x32_bf16(o.ah[kk], bh, Y[n], 0, 0, 0);
        Y[n] = __builtin_amdgcn_mfma_f32_16x16x32_bf16(o.ah[kk], bl, Y[n], 0, 0, 0);
      }

    // ---- phase B: o-out (waves 0,1) / U -> LDS hi (waves 2,3) ----
    if (isO) {
#pragma unroll
      for (int n = 0; n < 2; ++n) {
        size_t ob = (size_t)(c * 32 + r0) * 2048 + h * 128 + v0 + n * 16 + l15;
#pragma unroll
        for (int r = 0; r < 4; ++r)
          obuf[ob + (size_t)r * 2048] = Y[n][r] + o.pB[n][r];
      }
    } else {
#pragma unroll
      for (int n = 0; n < 2; ++n) {
        union { __hip_bfloat16 b[4]; unsigned long long u; } uh;
#pragma unroll
        for (int r = 0; r < 4; ++r)
          uh.b[r] = __float2bfloat16(o.pB[n][r] - Y[n][r]);
        *(unsigned long long*)(UTh + (n * 16 + l15) * UTP + r0) = uh.u;
      }
    }
    __syncthreads();

    // ---- phase C: S = P (.) S + KbarT @ U ----
#pragma unroll
    for (int mi = 0; mi < 2; ++mi)
#pragma unroll
      for (int n = 0; n < 2; ++n)
        S[mi][n] *= o.pvv[mi];
#pragma unroll
    for (int n = 0; n < 2; ++n) {
      bf16x8 ubh = *(const bf16x8*)(UTh + (n * 16 + l15) * UTP + l4 * 8);
#pragma unroll
      for (int mi = 0; mi < 2; ++mi)
        S[mi][n] = __builtin_amdgcn_mfma_f32_16x16x32_bf16(o.kah[mi], ubh, S[mi][n], 0, 0, 0);
    }

    // ---- phase D: refresh split operand view of S ----
#pragma unroll
    for (int mi = 0; mi < 2; ++mi) {
      const int kd0 = (w * 2 + mi) * 16 + l4 * 4;
#pragma unroll
      for (int n = 0; n < 2; ++n) {
        union { __hip_bfloat16 b[4]; unsigned long long u; } sh, sl;
#pragma unroll
        for (int r = 0; r < 4; ++r) {
          __hip_bfloat16 hh = __float2bfloat16(S[mi][n][r]);
          sh.b[r] = hh;
          sl.b[r] = __float2bfloat16(S[mi][n][r] - __bfloat162float(hh));
        }
        *(unsigned long long*)(STh + (n * 16 + l15) * STP + kd0) = sh.u;
        *(unsigned long long*)(STl + (n * 16 + l15) * STP + kd0) = sl.u;
      }
    }
    __syncthreads();
  };

  ChunkOps A_, B_;
  loadops(A_, 0);
  for (int c = 0; c < 64; c += 2) {
    loadops(B_, c + 1);            // prefetch next chunk while computing current
    body(A_, c);
    if (c + 2 < 64) loadops(A_, c + 2);
    body(B_, c + 1);
  }
}

// ---------------- sigmoid-gated RMSNorm -> bf16 ----------------
__global__ __launch_bounds__(256) void rmsgate_kernel(
    const float* __restrict__ o, const float* __restrict__ gate,
    const float* __restrict__ bg2, const float* __restrict__ norm_w,
    __hip_bfloat16* __restrict__ og)
{
  int row = blockIdx.x * 4 + (threadIdx.x >> 6);   // s*16 + h
  int lane = threadIdx.x & 63;
  int s = row >> 4, h = row & 15;
  int j = lane * 2;
  const float* p = o + (size_t)row * 128 + j;
  f32x2 v = *(const f32x2*)p;
  float ss = v.x * v.x + v.y * v.y;
#pragma unroll
  for (int off = 32; off > 0; off >>= 1) ss += __shfl_xor(ss, off);
  float rs = rsqrtf(ss * (1.f / 128.f) + 1e-6f);
  int c = h * 128 + j;
  float g0 = gate[(size_t)s * 2048 + c] + bg2[c];
  float g1 = gate[(size_t)s * 2048 + c + 1] + bg2[c + 1];
  float o0 = v.x * rs * norm_w[j] * (1.f / (1.f + expf(-g0)));
  float o1 = v.y * rs * norm_w[j + 1] * (1.f / (1.f + expf(-g1)));
  union { __hip_bfloat16 b[2]; unsigned int u; } pk2;
  pk2.b[0] = __float2bfloat16(o0);
  pk2.b[1] = __float2bfloat16(o1);
  *(unsigned int*)((char*)og + ((size_t)s * 2048 + c) * 2) = pk2.u;
}

// =====================================================================
extern "C" void kernel_launch(void* const* d_in, const int* in_sizes, int n_in,
                              void* d_out, int out_size, void* d_ws, size_t ws_size,
                              hipStream_t stream)
{
  const float* x      = (const float*)d_in[0];
  const float* ve     = (const float*)d_in[1];
  const float* lam    = (const float*)d_in[2];
  const float* Wq     = (const float*)d_in[3];
  const float* Wk     = (const float*)d_in[4];
  const float* Wv     = (const float*)d_in[5];
  const float* cwq    = (const float*)d_in[6];
  const float* cwk    = (const float*)d_in[7];
  const float* cwv    = (const float*)d_in[8];
  const float* Wf1    = (const float*)d_in[9];
  const float* Wf2    = (const float*)d_in[10];
  const float* Wb     = (const float*)d_in[11];
  const float* A_log  = (const float*)d_in[12];
  const float* dtb    = (const float*)d_in[13];
  const float* Wg1    = (const float*)d_in[14];
  const float* Wg2    = (const float*)d_in[15];
  const float* bg2    = (const float*)d_in[16];
  const float* norm_w = (const float*)d_in[17];
  const float* Wo     = (const float*)d_in[18];
  float* out = (float*)d_out;

  const size_t S2 = (size_t)2048 * 2048;

  char* p = (char*)d_ws;
  auto alloc = [&](size_t bytes) { char* r = p; p += (bytes + 255) & ~(size_t)255; return r; };

  __hip_bfloat16* xb    = (__hip_bfloat16*)alloc(S2 * 2);
  __hip_bfloat16* WoT   = (__hip_bfloat16*)alloc(S2 * 2);
  __hip_bfloat16* Wf1hT = (__hip_bfloat16*)alloc(2048 * 128 * 2);
  __hip_bfloat16* Wf1lT = (__hip_bfloat16*)alloc(2048 * 128 * 2);
  __hip_bfloat16* Wf2hT = (__hip_bfloat16*)alloc(2048 * 128 * 2);
  __hip_bfloat16* Wf2lT = (__hip_bfloat16*)alloc(2048 * 128 * 2);
  __hip_bfloat16* Wg1T  = (__hip_bfloat16*)alloc(2048 * 128 * 2);
  __hip_bfloat16* Wg2T  = (__hip_bfloat16*)alloc(2048 * 128 * 2);
  __hip_bfloat16* f1h   = (__hip_bfloat16*)alloc(2048 * 128 * 2);
  __hip_bfloat16* f1l   = (__hip_bfloat16*)alloc(2048 * 128 * 2);
  __hip_bfloat16* g1b   = (__hip_bfloat16*)alloc(2048 * 128 * 2);
  float* betaT = (float*)alloc((size_t)2048 * 16 * 4);
  float* qkv   = (float*)alloc(3 * S2 * 4);          // [2048][6144] f32
  float* gbuf  = (float*)alloc(S2 * 4);
  float* fpart = (float*)alloc((size_t)8 * 2048 * 128 * 4);
  float* gatebuf = (float*)alloc(S2 * 4);
  float* karr  = (float*)alloc(S2 * 4);
  float* qarr  = (float*)alloc(S2 * 4);
  float* varr  = (float*)alloc(S2 * 4);
  float* Pg    = (float*)alloc((size_t)1024 * 128 * 4);

  // overlays (timeline-checked):
  __hip_bfloat16* WqkvT = (__hip_bfloat16*)karr;                   // 24MB in karr+qarr[0:8MB]; dead after QKV gemm
  __hip_bfloat16* xlo   = (__hip_bfloat16*)((char*)qarr + S2 * 2); // qarr[8MB:16MB]; dead after f-path
  __hip_bfloat16* Xgh = (__hip_bfloat16*)qkv;                      // 16MB; qkv dead after prep_plain
  __hip_bfloat16* KTh = (__hip_bfloat16*)(qkv + 2 * S2);           // 8MB in the xv third
  float* uvS   = karr;    // written by kda_pre after it reads karr (same thread/rows)
  float* olocS = varr;
  float* obuf  = gbuf;    // gbuf dead after kda_pre
  __hip_bfloat16* og = (__hip_bfloat16*)qarr;  // after kda_seq; qarr dead after kda_pre

  // 1. split-cast x
  cast_split_kernel<<<4096, 256, 0, stream>>>(x, xb, xlo, (int)(S2 / 4));

  // 2. weight transposes (Wq/Wk/Wv into one merged [6144][2048] B^T)
  transpose_cast_kernel<<<dim3(64, 64), 256, 0, stream>>>(Wq, WqkvT, nullptr, 2048, 2048);
  transpose_cast_kernel<<<dim3(64, 64), 256, 0, stream>>>(Wk, WqkvT + 2048 * 2048, nullptr, 2048, 2048);
  transpose_cast_kernel<<<dim3(64, 64), 256, 0, stream>>>(Wv, WqkvT + 2 * 2048 * 2048, nullptr, 2048, 2048);
  transpose_cast_kernel<<<dim3(64, 64), 256, 0, stream>>>(Wo, WoT, nullptr, 2048, 2048);
  transpose_cast_kernel<<<dim3(4, 64), 256, 0, stream>>>(Wf1, Wf1hT, Wf1lT, 2048, 128);
  transpose_cast_kernel<<<dim3(64, 4), 256, 0, stream>>>(Wf2, Wf2hT, Wf2lT, 128, 2048);
  transpose_cast_kernel<<<dim3(4, 64), 256, 0, stream>>>(Wg1, Wg1T, nullptr, 2048, 128);
  transpose_cast_kernel<<<dim3(64, 4), 256, 0, stream>>>(Wg2, Wg2T, nullptr, 128, 2048);

  // 3. merged QKV projection: qkv[2048][6144]
  gemm_bt<<<dim3(48, 16), 256, 0, stream>>>(xb, WqkvT, qkv, 2048, 6144, 2048, 2048, 0);

  // 4. f-path (fused 3-pass split GEMMs)
  gemm_btsplit<<<dim3(1, 16, 8), 256, 0, stream>>>(xb, xlo, Wf1hT, Wf1lT, fpart, 2048, 128, 2048, 256);
  reduce8_kernel<<<256, 256, 0, stream>>>(fpart, f1h, f1l, 65536);
  gemm_btsplit<<<dim3(16, 16), 256, 0, stream>>>(f1h, f1l, Wf2hT, Wf2lT, gbuf, 2048, 2048, 128, 128);

  // 5. gate path
  gemm_bt<<<dim3(1, 16, 8), 256, 0, stream>>>(xb, Wg1T, fpart, 2048, 128, 2048, 256, 0);
  reduce8_kernel<<<256, 256, 0, stream>>>(fpart, g1b, nullptr, 65536);
  gemm_bt<<<dim3(16, 16), 256, 0, stream>>>(g1b, Wg2T, gatebuf, 2048, 2048, 128, 128, 0);

  // 6. beta
  beta_kernel<<<128, 256, 0, stream>>>(x, Wb, betaT);

  // 7. prep (conv+silu+mix+l2norm) from merged qkv (stride 6144)
  prep_plain<<<HN * SEQL, 64, 0, stream>>>(qkv, qkv + 2048, qkv + 4096, 6144,
                                           ve, lam, cwq, cwk, cwv, karr, qarr, varr);

  // 8. chunk-local precompute (overwrites qkv overlays Xgh/KTh)
  kda_pre<<<1024, 128, 0, stream>>>(karr, qarr, varr, gbuf, dtb, A_log, betaT,
                                    Xgh, KTh, uvS, olocS, Pg);

  // 9. sequential chunk scan
  kda_seq<<<64, 256, 0, stream>>>(Xgh, KTh, uvS, olocS, Pg, obuf);

  // 10. gated rmsnorm -> bf16 (og aliases qarr)
  rmsgate_kernel<<<8192, 256, 0, stream>>>(obuf, gatebuf, bg2, norm_w, og);

  // 11. output projection
  gemm_bt<<<dim3(16, 16), 256, 0, stream>>>(og, WoT, out, 2048, 2048, 2048, 2048, 0);
}

// Round 6
// 458.278 us; speedup vs baseline: 2.1042x; 1.1156x over previous
//
#include <hip/hip_runtime.h>
#include <hip/hip_bf16.h>
#include <stdint.h>
#include <stddef.h>

#define SEQL 2048
#define DIMSZ 2048
#define HN 16
#define DKD 128
#define DVD 128
#define QSCALE 0.08838834764831843f   // 128^-0.5

typedef __attribute__((ext_vector_type(4))) float f32x4;
typedef __attribute__((ext_vector_type(2))) float f32x2;
typedef __attribute__((ext_vector_type(8))) short bf16x8;

__device__ __forceinline__ float sigmoid_f(float x) { return 1.f / (1.f + __expf(-x)); }

// ---------------- bf16 GEMM: C[M,N] (f32) = A[M,K]bf16 @ Bt[N,K]bf16 ----------------
#define BM 128
#define BN 128
#define BKK 64

__global__ __launch_bounds__(256) void gemm_bt(
    const __hip_bfloat16* __restrict__ A, const __hip_bfloat16* __restrict__ B,
    float* __restrict__ C, int M, int N, int lda, int ldb, int klen, int accum)
{
  __shared__ __hip_bfloat16 As[BM * BKK];
  __shared__ __hip_bfloat16 Bs[BN * BKK];
  const int tid = threadIdx.x;
  const int lane = tid & 63;
  const int w = tid >> 6;
  const int wm = w >> 1, wn = w & 1;            // 2x2 wave grid, 64x64 each
  const int m0 = blockIdx.y * BM, n0 = blockIdx.x * BN;
  const int l15 = lane & 15, l4 = lane >> 4;
  const int kbase = blockIdx.z * klen;

  f32x4 acc[4][4] = {};

  for (int k0 = kbase; k0 < kbase + klen; k0 += BKK) {
#pragma unroll
    for (int i = 0; i < 4; ++i) {
      const int c = (w * 4 + i) * 64 + lane;     // chunk id, 16B each; 8 chunks/row
      const int row = c >> 3;
      const int colb = (c & 7) * 8;
      __builtin_amdgcn_global_load_lds(
          (const __attribute__((address_space(1))) void*)(A + (size_t)(m0 + row) * lda + k0 + colb),
          (__attribute__((address_space(3))) void*)(As + (size_t)c * 8), 16, 0, 0);
      __builtin_amdgcn_global_load_lds(
          (const __attribute__((address_space(1))) void*)(B + (size_t)(n0 + row) * ldb + k0 + colb),
          (__attribute__((address_space(3))) void*)(Bs + (size_t)c * 8), 16, 0, 0);
    }
    __syncthreads();
#pragma unroll
    for (int kk = 0; kk < BKK; kk += 32) {
      bf16x8 af[4], bfv[4];
#pragma unroll
      for (int mi = 0; mi < 4; ++mi)
        af[mi] = *(const bf16x8*)(As + (wm * 64 + mi * 16 + l15) * BKK + kk + l4 * 8);
#pragma unroll
      for (int ni = 0; ni < 4; ++ni)
        bfv[ni] = *(const bf16x8*)(Bs + (wn * 64 + ni * 16 + l15) * BKK + kk + l4 * 8);
#pragma unroll
      for (int mi = 0; mi < 4; ++mi)
#pragma unroll
        for (int ni = 0; ni < 4; ++ni)
          acc[mi][ni] = __builtin_amdgcn_mfma_f32_16x16x32_bf16(af[mi], bfv[ni], acc[mi][ni], 0, 0, 0);
    }
    __syncthreads();
  }

  float* Cz = C + (size_t)blockIdx.z * M * N;
#pragma unroll
  for (int mi = 0; mi < 4; ++mi) {
#pragma unroll
    for (int ni = 0; ni < 4; ++ni) {
      const int row = m0 + wm * 64 + mi * 16 + l4 * 4;
      const int col = n0 + wn * 64 + ni * 16 + l15;
#pragma unroll
      for (int r = 0; r < 4; ++r) {
        size_t idx = (size_t)(row + r) * N + col;
        if (accum) Cz[idx] += acc[mi][ni][r];
        else Cz[idx] = acc[mi][ni][r];
      }
    }
  }
}

// ---------------- fused split-precision GEMM: C = Ah@Bh + Ah@Bl + Al@Bh ----------------
__global__ __launch_bounds__(256) void gemm_btsplit(
    const __hip_bfloat16* __restrict__ Ah, const __hip_bfloat16* __restrict__ Al,
    const __hip_bfloat16* __restrict__ Bh, const __hip_bfloat16* __restrict__ Bl,
    float* __restrict__ C, int M, int N, int lda, int ldb, int klen)
{
  __shared__ __hip_bfloat16 Ash[BM * BKK];
  __shared__ __hip_bfloat16 Asl[BM * BKK];
  __shared__ __hip_bfloat16 Bsh[BN * BKK];
  __shared__ __hip_bfloat16 Bsl[BN * BKK];
  const int tid = threadIdx.x;
  const int lane = tid & 63;
  const int w = tid >> 6;
  const int wm = w >> 1, wn = w & 1;
  const int m0 = blockIdx.y * BM, n0 = blockIdx.x * BN;
  const int l15 = lane & 15, l4 = lane >> 4;
  const int kbase = blockIdx.z * klen;

  f32x4 acc[4][4] = {};

  for (int k0 = kbase; k0 < kbase + klen; k0 += BKK) {
#pragma unroll
    for (int i = 0; i < 4; ++i) {
      const int c = (w * 4 + i) * 64 + lane;
      const int row = c >> 3;
      const int colb = (c & 7) * 8;
      const size_t go = (size_t)(m0 + row) * lda + k0 + colb;
      const size_t gn = (size_t)(n0 + row) * ldb + k0 + colb;
      __builtin_amdgcn_global_load_lds(
          (const __attribute__((address_space(1))) void*)(Ah + go),
          (__attribute__((address_space(3))) void*)(Ash + (size_t)c * 8), 16, 0, 0);
      __builtin_amdgcn_global_load_lds(
          (const __attribute__((address_space(1))) void*)(Al + go),
          (__attribute__((address_space(3))) void*)(Asl + (size_t)c * 8), 16, 0, 0);
      __builtin_amdgcn_global_load_lds(
          (const __attribute__((address_space(1))) void*)(Bh + gn),
          (__attribute__((address_space(3))) void*)(Bsh + (size_t)c * 8), 16, 0, 0);
      __builtin_amdgcn_global_load_lds(
          (const __attribute__((address_space(1))) void*)(Bl + gn),
          (__attribute__((address_space(3))) void*)(Bsl + (size_t)c * 8), 16, 0, 0);
    }
    __syncthreads();
#pragma unroll
    for (int kk = 0; kk < BKK; kk += 32) {
      bf16x8 afh[4], afl[4], bfh[4], bfl[4];
#pragma unroll
      for (int mi = 0; mi < 4; ++mi) {
        const int ao = (wm * 64 + mi * 16 + l15) * BKK + kk + l4 * 8;
        afh[mi] = *(const bf16x8*)(Ash + ao);
        afl[mi] = *(const bf16x8*)(Asl + ao);
      }
#pragma unroll
      for (int ni = 0; ni < 4; ++ni) {
        const int bo = (wn * 64 + ni * 16 + l15) * BKK + kk + l4 * 8;
        bfh[ni] = *(const bf16x8*)(Bsh + bo);
        bfl[ni] = *(const bf16x8*)(Bsl + bo);
      }
#pragma unroll
      for (int mi = 0; mi < 4; ++mi)
#pragma unroll
        for (int ni = 0; ni < 4; ++ni) {
          acc[mi][ni] = __builtin_amdgcn_mfma_f32_16x16x32_bf16(afh[mi], bfh[ni], acc[mi][ni], 0, 0, 0);
          acc[mi][ni] = __builtin_amdgcn_mfma_f32_16x16x32_bf16(afh[mi], bfl[ni], acc[mi][ni], 0, 0, 0);
          acc[mi][ni] = __builtin_amdgcn_mfma_f32_16x16x32_bf16(afl[mi], bfh[ni], acc[mi][ni], 0, 0, 0);
        }
    }
    __syncthreads();
  }

  float* Cz = C + (size_t)blockIdx.z * M * N;
#pragma unroll
  for (int mi = 0; mi < 4; ++mi) {
#pragma unroll
    for (int ni = 0; ni < 4; ++ni) {
      const int row = m0 + wm * 64 + mi * 16 + l4 * 4;
      const int col = n0 + wn * 64 + ni * 16 + l15;
#pragma unroll
      for (int r = 0; r < 4; ++r)
        Cz[(size_t)(row + r) * N + col] = acc[mi][ni][r];
    }
  }
}

// ---------------- transpose + cast (optional hi/lo split): out[C,R] = bf16(in[R,C]^T) ----------------
__global__ __launch_bounds__(256) void transpose_cast_kernel(
    const float* __restrict__ in, __hip_bfloat16* __restrict__ outT,
    __hip_bfloat16* __restrict__ outLo, int R, int C)
{
  __shared__ float tile[32][33];
  const int c0 = blockIdx.x * 32, r0 = blockIdx.y * 32;
  const int tc = threadIdx.x & 31, tr = threadIdx.x >> 5;   // tr in 0..7
#pragma unroll
  for (int i = 0; i < 4; ++i)
    tile[tr + i * 8][tc] = in[(size_t)(r0 + tr + i * 8) * C + c0 + tc];
  __syncthreads();
#pragma unroll
  for (int i = 0; i < 4; ++i) {
    float val = tile[tc][tr + i * 8];
    __hip_bfloat16 h = __float2bfloat16(val);
    size_t oi = (size_t)(c0 + tr + i * 8) * R + r0 + tc;
    outT[oi] = h;
    if (outLo) outLo[oi] = __float2bfloat16(val - __bfloat162float(h));
  }
}

// ---------------- elementwise cast with optional lo residual ----------------
__global__ __launch_bounds__(256) void cast_split_kernel(
    const float* __restrict__ in, __hip_bfloat16* __restrict__ hi,
    __hip_bfloat16* __restrict__ lo, int n4)
{
  int idx = blockIdx.x * 256 + threadIdx.x;
  if (idx >= n4) return;
  f32x4 v = *(const f32x4*)(in + (size_t)idx * 4);
  union { __hip_bfloat16 b[4]; unsigned long long u; } ph, pl;
#pragma unroll
  for (int j = 0; j < 4; ++j) {
    float f = v[j];
    __hip_bfloat16 hh = __float2bfloat16(f);
    ph.b[j] = hh;
    pl.b[j] = __float2bfloat16(f - __bfloat162float(hh));
  }
  *(unsigned long long*)((char*)hi + (size_t)idx * 8) = ph.u;
  if (lo) *(unsigned long long*)((char*)lo + (size_t)idx * 8) = pl.u;
}

// ---------------- split-K reduce (8 partials) -> bf16 hi (+ optional lo) ----------------
__global__ __launch_bounds__(256) void reduce8_kernel(
    const float* __restrict__ part, __hip_bfloat16* __restrict__ hi,
    __hip_bfloat16* __restrict__ lo, int n4, size_t chunk)
{
  int idx = blockIdx.x * 256 + threadIdx.x;
  if (idx >= n4) return;
  f32x4 a = *(const f32x4*)(part + (size_t)idx * 4);
#pragma unroll
  for (int z = 1; z < 8; ++z) {
    f32x4 b = *(const f32x4*)(part + z * chunk + (size_t)idx * 4);
    a.x += b.x; a.y += b.y; a.z += b.z; a.w += b.w;
  }
  union { __hip_bfloat16 b[4]; unsigned long long u; } ph, pl;
#pragma unroll
  for (int j = 0; j < 4; ++j) {
    float f = a[j];
    __hip_bfloat16 hh = __float2bfloat16(f);
    ph.b[j] = hh;
    pl.b[j] = __float2bfloat16(f - __bfloat162float(hh));
  }
  *(unsigned long long*)((char*)hi + (size_t)idx * 8) = ph.u;
  if (lo) *(unsigned long long*)((char*)lo + (size_t)idx * 8) = pl.u;
}

// ---------------- beta = sigmoid(x @ Wb), thread per (s,h); writes [h][s] ----------------
__global__ __launch_bounds__(256) void beta_kernel(
    const float* __restrict__ x, const float* __restrict__ Wb, float* __restrict__ betaT)
{
  int idx = blockIdx.x * 256 + threadIdx.x;      // 0..32767
  int s = idx >> 4, h = idx & 15;
  const float* xr = x + (size_t)s * DIMSZ;
  float acc = 0.f;
  for (int d = 0; d < DIMSZ; d += 4) {
    f32x4 xv = *(const f32x4*)(xr + d);
    acc = fmaf(xv.x, Wb[(size_t)(d + 0) * HN + h], acc);
    acc = fmaf(xv.y, Wb[(size_t)(d + 1) * HN + h], acc);
    acc = fmaf(xv.z, Wb[(size_t)(d + 2) * HN + h], acc);
    acc = fmaf(xv.w, Wb[(size_t)(d + 3) * HN + h], acc);
  }
  betaT[(size_t)h * SEQL + s] = 1.f / (1.f + expf(-acc));
}

// ---------------- fused conv+silu+mix+l2norm -> plain arrays [s][h*128+d] ----------------
__global__ __launch_bounds__(64) void prep_plain(
    const float* __restrict__ xq, const float* __restrict__ xk, const float* __restrict__ xv,
    int xstr,
    const float* __restrict__ ve, const float* __restrict__ lam,
    const float* __restrict__ cwq, const float* __restrict__ cwk, const float* __restrict__ cwv,
    float* __restrict__ karr, float* __restrict__ qarr, float* __restrict__ varr)
{
  const int bid = blockIdx.x;          // h*2048 + t
  const int h = bid >> 11, t = bid & 2047;
  const int d2 = threadIdx.x * 2;      // channels d2, d2+1 of this head
  const int c = h * 128 + d2;

  f32x4 wq0 = *(const f32x4*)(cwq + (size_t)c * 4), wq1 = *(const f32x4*)(cwq + (size_t)(c + 1) * 4);
  f32x4 wk0 = *(const f32x4*)(cwk + (size_t)c * 4), wk1 = *(const f32x4*)(cwk + (size_t)(c + 1) * 4);
  f32x4 wv0 = *(const f32x4*)(cwv + (size_t)c * 4), wv1 = *(const f32x4*)(cwv + (size_t)(c + 1) * 4);

  float aq0 = 0, aq1 = 0, ak0 = 0, ak1 = 0, av0 = 0, av1 = 0;
#pragma unroll
  for (int i = 0; i < 4; ++i) {
    int sr = t - 3 + i;
    if (sr >= 0) {
      f32x2 a = *(const f32x2*)(xq + (size_t)sr * xstr + c);
      f32x2 b = *(const f32x2*)(xk + (size_t)sr * xstr + c);
      f32x2 d = *(const f32x2*)(xv + (size_t)sr * xstr + c);
      aq0 = fmaf(a.x, wq0[i], aq0); aq1 = fmaf(a.y, wq1[i], aq1);
      ak0 = fmaf(b.x, wk0[i], ak0); ak1 = fmaf(b.y, wk1[i], ak1);
      av0 = fmaf(d.x, wv0[i], av0); av1 = fmaf(d.y, wv1[i], av1);
    }
  }
  float yq0 = aq0 * sigmoid_f(aq0), yq1 = aq1 * sigmoid_f(aq1);
  float yk0 = ak0 * sigmoid_f(ak0), yk1 = ak1 * sigmoid_f(ak1);
  float yv0 = av0 * sigmoid_f(av0), yv1 = av1 * sigmoid_f(av1);

  float l0 = lam[0], l1 = lam[1];
  f32x2 vev = *(const f32x2*)(ve + ((size_t)t * HN + h) * 128 + d2);
  float v0 = l0 * yv0 + l1 * vev.x;
  float v1 = l0 * yv1 + l1 * vev.y;

  float ssq = yq0 * yq0 + yq1 * yq1;
  float ssk = yk0 * yk0 + yk1 * yk1;
#pragma unroll
  for (int off = 32; off > 0; off >>= 1) {
    ssq += __shfl_xor(ssq, off);
    ssk += __shfl_xor(ssk, off);
  }
  float rq = rsqrtf(ssq + 1e-6f) * QSCALE;
  float rk = rsqrtf(ssk + 1e-6f);

  size_t o = (size_t)t * 2048 + c;
  f32x2 kk; kk.x = yk0 * rk; kk.y = yk1 * rk;
  f32x2 qq; qq.x = yq0 * rq; qq.y = yq1 * rq;
  f32x2 vv2; vv2.x = v0; vv2.y = v1;
  *(f32x2*)(karr + o) = kk;
  *(f32x2*)(qarr + o) = qq;
  *(f32x2*)(varr + o) = vv2;
}

// ---------------- chunk-local precompute (C=32), fp32, register-tiled pairs ----------------
// 256 threads: col = tid&127 (d channel), half = tid>>7 (row-halves for fill).
// Pairs phase: 8-lane group per row t (t = wave + 4*group), t-side slice (16 d) in regs,
// i-side via aligned ds_read_b128. GP=132 keeps 16B alignment.
#define GP 132

__global__ __launch_bounds__(256) void kda_pre(
    const float* __restrict__ karr, const float* __restrict__ qarr,
    const float* __restrict__ varr, const float* __restrict__ gbuf,
    const float* __restrict__ dtb, const float* __restrict__ A_log,
    const float* __restrict__ betaT,
    __hip_bfloat16* __restrict__ Xgh, __hip_bfloat16* __restrict__ KTh,
    float* __restrict__ uvS, float* __restrict__ olocS, float* __restrict__ Pg)
{
  __shared__ float kL[32 * GP], qL[32 * GP], GL[32 * GP];
  __shared__ float AL[32][33], BL[32][33], betaL[32], csum[128];
  const int bid = blockIdx.x;
  const int h = bid >> 6, cc = bid & 63;
  const int tid = threadIdx.x;
  const int col = tid & 127, half = tid >> 7;
  const size_t rowbase = (size_t)(cc * 32) * 2048 + h * 128 + col;
  const size_t hc = (size_t)h * 64 + cc;

  const float Aexp = __expf(A_log[h]);
  const float dtv = dtb[h * 128 + col];
  const int rbase = half * 16;

  // fill k,q + local glog cumsum (16 rows per half)
  float gloc[16];
#pragma unroll
  for (int i = 0; i < 16; ++i) {
    int r = rbase + i;
    size_t o = rowbase + (size_t)r * 2048;
    kL[r * GP + col] = karr[o];
    qL[r * GP + col] = qarr[o];
    float gv = gbuf[o] + dtv;
    float sp = (gv > 20.f) ? gv : log1pf(__expf(fminf(gv, 20.f)));
    gloc[i] = -Aexp * sp;
  }
  {
    float run = 0.f;
#pragma unroll
    for (int i = 0; i < 16; ++i) { run += gloc[i]; gloc[i] = run; }
    if (half == 0) csum[col] = run;
  }
  if (tid < 32) betaL[tid] = betaT[(size_t)h * SEQL + cc * 32 + tid];
  float vreg[32];
  if (half == 0) {
#pragma unroll
    for (int r = 0; r < 32; ++r) vreg[r] = varr[rowbase + (size_t)r * 2048];
  }
  __syncthreads();
  {
    float base = (half == 0) ? 0.f : csum[col];
#pragma unroll
    for (int i = 0; i < 16; ++i) GL[(rbase + i) * GP + col] = gloc[i] + base;
  }
  __syncthreads();

  // ---- pairs phase: A[t][i], B[t][i] ----
  const int w = tid >> 6, l = tid & 63;
  const int tg = l >> 3, s8 = l & 7;
  const int tt = w + tg * 4;               // row t for this 8-lane group
  const int ds = s8 * 16;                  // 16-d slice

  float Gt[16], kt[16], qt[16];
#pragma unroll
  for (int j = 0; j < 16; j += 4) {
    *(f32x4*)&Gt[j] = *(const f32x4*)&GL[tt * GP + ds + j];
    *(f32x4*)&kt[j] = *(const f32x4*)&kL[tt * GP + ds + j];
    *(f32x4*)&qt[j] = *(const f32x4*)&qL[tt * GP + ds + j];
  }
  {
    // diagonal (e = 1)
    float sA = 0.f, sB = 0.f;
#pragma unroll
    for (int j = 0; j < 16; ++j) { sA = fmaf(kt[j], kt[j], sA); sB = fmaf(qt[j], kt[j], sB); }
    sA += __shfl_xor(sA, 1); sA += __shfl_xor(sA, 2); sA += __shfl_xor(sA, 4);
    sB += __shfl_xor(sB, 1); sB += __shfl_xor(sB, 2); sB += __shfl_xor(sB, 4);
    if (s8 == 0) { AL[tt][tt] = sA; BL[tt][tt] = sB; }
  }
  for (int i = 0; i < 28 + w; ++i) {
    if (i < tt) {
      float sA = 0.f, sB = 0.f;
#pragma unroll
      for (int jj = 0; jj < 4; ++jj) {
        f32x4 Gi = *(const f32x4*)&GL[i * GP + ds + jj * 4];
        f32x4 ki = *(const f32x4*)&kL[i * GP + ds + jj * 4];
#pragma unroll
        for (int u = 0; u < 4; ++u) {
          float e = __expf(Gt[jj * 4 + u] - Gi[u]);
          float kid = ki[u] * e;
          sA = fmaf(kt[jj * 4 + u], kid, sA);
          sB = fmaf(qt[jj * 4 + u], kid, sB);
        }
      }
      sA += __shfl_xor(sA, 1); sA += __shfl_xor(sA, 2); sA += __shfl_xor(sA, 4);
      sB += __shfl_xor(sB, 1); sB += __shfl_xor(sB, 2); sB += __shfl_xor(sB, 4);
      if (s8 == 0) { AL[tt][i] = sA; BL[tt][i] = sB; }
    }
  }
  __syncthreads();

  // KbarT (both halves, 16 rows each)
  {
    const float g31 = GL[31 * GP + col];
    size_t kb = hc * 4096 + (size_t)col * 32;
#pragma unroll
    for (int i = 0; i < 16; ++i) {
      int r = rbase + i;
      float kv = kL[r * GP + col] * __expf(g31 - GL[r * GP + col]);
      KTh[kb + r] = __float2bfloat16(kv);
    }
  }

  if (half == 0) {
    float expg[32];
#pragma unroll
    for (int r = 0; r < 32; ++r) expg[r] = __expf(GL[r * GP + col]);

    // forward substitution
    float uvr[32], wr[32];
#pragma unroll
    for (int r = 0; r < 32; ++r) {
      float suv = 0.f, sw = 0.f;
#pragma unroll
      for (int j = 0; j < 32; ++j) {
        if (j < r) { float a = AL[r][j]; suv = fmaf(a, uvr[j], suv); sw = fmaf(a, wr[j], sw); }
      }
      float br = betaL[r];
      float khr = kL[r * GP + col] * expg[r];
      uvr[r] = br * (vreg[r] - suv);
      wr[r] = br * (khr - sw);
      uvS[rowbase + (size_t)r * 2048] = uvr[r];
      Xgh[hc * 8192 + (size_t)(32 + r) * 128 + col] = __float2bfloat16(wr[r]);
    }

    // Qt rows + oloc rows
#pragma unroll
    for (int r = 0; r < 32; ++r) {
      float qtv = qL[r * GP + col] * expg[r];
      float ol = 0.f;
#pragma unroll
      for (int j = 0; j < 32; ++j) {
        if (j <= r) { float b = BL[r][j]; qtv = fmaf(-b, wr[j], qtv); ol = fmaf(b, uvr[j], ol); }
      }
      Xgh[hc * 8192 + (size_t)r * 128 + col] = __float2bfloat16(qtv);
      olocS[rowbase + (size_t)r * 2048] = ol;
    }
    Pg[hc * 128 + col] = expg[31];
  }
}

// ---------------- sequential chunk scan: S in MFMA accumulators, reg-prefetched ----------------
// grid 128 = (h, dv-eighth of 16). Per chunk: Y=[Qt;W]@S; o = Y[0:32]+oloc;
// U = uv - Y[32:64]; S = P (.) S + KbarT @ U.
#define STP 136
#define UTP 40

struct ChunkOps {
  bf16x8 ah[4];
  bf16x8 kah[2];
  f32x4 pvv[2];
  float pB[4];
};

__global__ __launch_bounds__(256) void kda_seq(
    const __hip_bfloat16* __restrict__ Xgh, const __hip_bfloat16* __restrict__ KTh,
    const float* __restrict__ uvS, const float* __restrict__ olocS,
    const float* __restrict__ Pg, float* __restrict__ obuf)
{
  __shared__ __hip_bfloat16 STh[16 * STP], STl[16 * STP];
  __shared__ __hip_bfloat16 UTh[16 * UTP];
  const int tid = threadIdx.x;
  const int w = tid >> 6, lane = tid & 63, l15 = lane & 15, l4 = lane >> 4;
  const int h = blockIdx.x >> 3, vq = blockIdx.x & 7;
  const int v0 = vq * 16;
  const int r0 = (w & 1) * 16 + l4 * 4;
  const int isO = (w < 2);

  for (int i = tid; i < 16 * STP; i += 256) {
    STh[i] = __float2bfloat16(0.f);
    STl[i] = __float2bfloat16(0.f);
  }
  __syncthreads();

  f32x4 S[2] = {};

  auto loadops = [&](ChunkOps& o, int c) {
    const size_t hc = (size_t)h * 64 + c;
    const __hip_bfloat16* xh = Xgh + hc * 8192 + (size_t)(w * 16 + l15) * 128 + l4 * 8;
#pragma unroll
    for (int kk = 0; kk < 4; ++kk) o.ah[kk] = *(const bf16x8*)(xh + kk * 32);
    const float* pb = (isO ? olocS : uvS) + (size_t)(c * 32 + r0) * 2048 + h * 128 + v0 + l15;
#pragma unroll
    for (int r = 0; r < 4; ++r) o.pB[r] = pb[(size_t)r * 2048];
#pragma unroll
    for (int mi = 0; mi < 2; ++mi) {
      const int kd = (w * 2 + mi) * 16;
      o.kah[mi] = *(const bf16x8*)(KTh + hc * 4096 + (size_t)(kd + l15) * 32 + l4 * 8);
      o.pvv[mi] = *(const f32x4*)(Pg + hc * 128 + kd + l4 * 4);
    }
  };

  auto body = [&](ChunkOps& o, int c) {
    // ---- phase A: Y = X @ (Sh + Sl) ----
    f32x4 Y = {};
#pragma unroll
    for (int kk = 0; kk < 4; ++kk) {
      const int so = l15 * STP + kk * 32 + l4 * 8;
      bf16x8 bh = *(const bf16x8*)(STh + so);
      bf16x8 bl = *(const bf16x8*)(STl + so);
      Y = __builtin_amdgcn_mfma_f32_16x16x32_bf16(o.ah[kk], bh, Y, 0, 0, 0);
      Y = __builtin_amdgcn_mfma_f32_16x16x32_bf16(o.ah[kk], bl, Y, 0, 0, 0);
    }

    // ---- phase B: o-out (waves 0,1) / U -> LDS hi (waves 2,3) ----
    if (isO) {
      size_t ob = (size_t)(c * 32 + r0) * 2048 + h * 128 + v0 + l15;
#pragma unroll
      for (int r = 0; r < 4; ++r)
        obuf[ob + (size_t)r * 2048] = Y[r] + o.pB[r];
    } else {
      union { __hip_bfloat16 b[4]; unsigned long long u; } uh;
#pragma unroll
      for (int r = 0; r < 4; ++r)
        uh.b[r] = __float2bfloat16(o.pB[r] - Y[r]);
      *(unsigned long long*)(UTh + l15 * UTP + r0) = uh.u;
    }
    __syncthreads();

    // ---- phase C: S = P (.) S + KbarT @ U ----
#pragma unroll
    for (int mi = 0; mi < 2; ++mi) S[mi] *= o.pvv[mi];
    {
      bf16x8 ubh = *(const bf16x8*)(UTh + l15 * UTP + l4 * 8);
#pragma unroll
      for (int mi = 0; mi < 2; ++mi)
        S[mi] = __builtin_amdgcn_mfma_f32_16x16x32_bf16(o.kah[mi], ubh, S[mi], 0, 0, 0);
    }

    // ---- phase D: refresh split operand view of S ----
#pragma unroll
    for (int mi = 0; mi < 2; ++mi) {
      const int kd0 = (w * 2 + mi) * 16 + l4 * 4;
      union { __hip_bfloat16 b[4]; unsigned long long u; } sh, sl;
#pragma unroll
      for (int r = 0; r < 4; ++r) {
        __hip_bfloat16 hh = __float2bfloat16(S[mi][r]);
        sh.b[r] = hh;
        sl.b[r] = __float2bfloat16(S[mi][r] - __bfloat162float(hh));
      }
      *(unsigned long long*)(STh + l15 * STP + kd0) = sh.u;
      *(unsigned long long*)(STl + l15 * STP + kd0) = sl.u;
    }
    __syncthreads();
  };

  ChunkOps A_, B_;
  loadops(A_, 0);
  for (int c = 0; c < 64; c += 2) {
    loadops(B_, c + 1);            // prefetch next chunk while computing current
    body(A_, c);
    if (c + 2 < 64) loadops(A_, c + 2);
    body(B_, c + 1);
  }
}

// ---------------- sigmoid-gated RMSNorm -> bf16 ----------------
__global__ __launch_bounds__(256) void rmsgate_kernel(
    const float* __restrict__ o, const float* __restrict__ gate,
    const float* __restrict__ bg2, const float* __restrict__ norm_w,
    __hip_bfloat16* __restrict__ og)
{
  int row = blockIdx.x * 4 + (threadIdx.x >> 6);   // s*16 + h
  int lane = threadIdx.x & 63;
  int s = row >> 4, h = row & 15;
  int j = lane * 2;
  const float* p = o + (size_t)row * 128 + j;
  f32x2 v = *(const f32x2*)p;
  float ss = v.x * v.x + v.y * v.y;
#pragma unroll
  for (int off = 32; off > 0; off >>= 1) ss += __shfl_xor(ss, off);
  float rs = rsqrtf(ss * (1.f / 128.f) + 1e-6f);
  int c = h * 128 + j;
  float g0 = gate[(size_t)s * 2048 + c] + bg2[c];
  float g1 = gate[(size_t)s * 2048 + c + 1] + bg2[c + 1];
  float o0 = v.x * rs * norm_w[j] * (1.f / (1.f + expf(-g0)));
  float o1 = v.y * rs * norm_w[j + 1] * (1.f / (1.f + expf(-g1)));
  union { __hip_bfloat16 b[2]; unsigned int u; } pk2;
  pk2.b[0] = __float2bfloat16(o0);
  pk2.b[1] = __float2bfloat16(o1);
  *(unsigned int*)((char*)og + ((size_t)s * 2048 + c) * 2) = pk2.u;
}

// =====================================================================
extern "C" void kernel_launch(void* const* d_in, const int* in_sizes, int n_in,
                              void* d_out, int out_size, void* d_ws, size_t ws_size,
                              hipStream_t stream)
{
  const float* x      = (const float*)d_in[0];
  const float* ve     = (const float*)d_in[1];
  const float* lam    = (const float*)d_in[2];
  const float* Wq     = (const float*)d_in[3];
  const float* Wk     = (const float*)d_in[4];
  const float* Wv     = (const float*)d_in[5];
  const float* cwq    = (const float*)d_in[6];
  const float* cwk    = (const float*)d_in[7];
  const float* cwv    = (const float*)d_in[8];
  const float* Wf1    = (const float*)d_in[9];
  const float* Wf2    = (const float*)d_in[10];
  const float* Wb     = (const float*)d_in[11];
  const float* A_log  = (const float*)d_in[12];
  const float* dtb    = (const float*)d_in[13];
  const float* Wg1    = (const float*)d_in[14];
  const float* Wg2    = (const float*)d_in[15];
  const float* bg2    = (const float*)d_in[16];
  const float* norm_w = (const float*)d_in[17];
  const float* Wo     = (const float*)d_in[18];
  float* out = (float*)d_out;

  const size_t S2 = (size_t)2048 * 2048;

  char* p = (char*)d_ws;
  auto alloc = [&](size_t bytes) { char* r = p; p += (bytes + 255) & ~(size_t)255; return r; };

  __hip_bfloat16* xb     = (__hip_bfloat16*)alloc(S2 * 2);
  __hip_bfloat16* WoT    = (__hip_bfloat16*)alloc(S2 * 2);
  __hip_bfloat16* Wf2hT  = (__hip_bfloat16*)alloc(2048 * 128 * 2);
  __hip_bfloat16* Wf2lT  = (__hip_bfloat16*)alloc(2048 * 128 * 2);
  __hip_bfloat16* Wg2T   = (__hip_bfloat16*)alloc(2048 * 128 * 2);
  __hip_bfloat16* Wfg1hT = (__hip_bfloat16*)alloc((size_t)256 * 2048 * 2);
  __hip_bfloat16* Wfg1lT = (__hip_bfloat16*)alloc((size_t)256 * 2048 * 2);
  __hip_bfloat16* f1g1h  = (__hip_bfloat16*)alloc((size_t)2048 * 256 * 2);
  __hip_bfloat16* f1g1l  = (__hip_bfloat16*)alloc((size_t)2048 * 256 * 2);
  float* betaT = (float*)alloc((size_t)2048 * 16 * 4);
  float* qkv   = (float*)alloc(3 * S2 * 4);          // [2048][6144] f32
  float* gbuf  = (float*)alloc(S2 * 4);
  float* gatebuf = (float*)alloc(S2 * 4);
  float* karr  = (float*)alloc(S2 * 4);
  float* qarr  = (float*)alloc(S2 * 4);
  float* varr  = (float*)alloc(S2 * 4);
  float* Pg    = (float*)alloc((size_t)1024 * 128 * 4);

  // overlays (timeline-checked):
  __hip_bfloat16* WqkvT = (__hip_bfloat16*)karr;                   // 24MB in karr+qarr[0:8MB]; dead after QKV gemm
  __hip_bfloat16* xlo   = (__hip_bfloat16*)((char*)qarr + S2 * 2); // qarr[8MB:16MB]; dead after stage1
  float* fpart = karr;                                             // 16MB; alive stage1->reduce8 only
  __hip_bfloat16* Xgh = (__hip_bfloat16*)qkv;                      // 16MB; qkv dead after prep_plain
  __hip_bfloat16* KTh = (__hip_bfloat16*)(qkv + 2 * S2);           // 8MB in the 3rd third
  float* uvS   = karr;    // written by kda_pre after it reads karr (same thread/rows)
  float* olocS = varr;
  float* obuf  = gbuf;    // gbuf dead after kda_pre
  __hip_bfloat16* og = (__hip_bfloat16*)qarr;  // after kda_seq; qarr dead after kda_pre

  // 1. split-cast x
  cast_split_kernel<<<4096, 256, 0, stream>>>(x, xb, xlo, (int)(S2 / 4));

  // 2. weight transposes (Wq/Wk/Wv merged; Wf1|Wg1 merged into [256][2048])
  transpose_cast_kernel<<<dim3(64, 64), 256, 0, stream>>>(Wq, WqkvT, nullptr, 2048, 2048);
  transpose_cast_kernel<<<dim3(64, 64), 256, 0, stream>>>(Wk, WqkvT + 2048 * 2048, nullptr, 2048, 2048);
  transpose_cast_kernel<<<dim3(64, 64), 256, 0, stream>>>(Wv, WqkvT + 2 * 2048 * 2048, nullptr, 2048, 2048);
  transpose_cast_kernel<<<dim3(64, 64), 256, 0, stream>>>(Wo, WoT, nullptr, 2048, 2048);
  transpose_cast_kernel<<<dim3(4, 64), 256, 0, stream>>>(Wf1, Wfg1hT, Wfg1lT, 2048, 128);
  transpose_cast_kernel<<<dim3(4, 64), 256, 0, stream>>>(Wg1, Wfg1hT + 128 * 2048, nullptr, 2048, 128);
  hipMemsetAsync(Wfg1lT + 128 * 2048, 0, (size_t)128 * 2048 * 2, stream);
  transpose_cast_kernel<<<dim3(64, 4), 256, 0, stream>>>(Wf2, Wf2hT, Wf2lT, 128, 2048);
  transpose_cast_kernel<<<dim3(64, 4), 256, 0, stream>>>(Wg2, Wg2T, nullptr, 128, 2048);

  // 3. merged QKV projection: qkv[2048][6144]
  gemm_bt<<<dim3(48, 16), 256, 0, stream>>>(xb, WqkvT, qkv, 2048, 6144, 2048, 2048, 2048, 0);

  // 4. merged f1|g1 stage (split-K z=8, 3-pass split precision)
  gemm_btsplit<<<dim3(2, 16, 8), 256, 0, stream>>>(xb, xlo, Wfg1hT, Wfg1lT, fpart,
                                                   2048, 256, 2048, 2048, 256);
  reduce8_kernel<<<512, 256, 0, stream>>>(fpart, f1g1h, f1g1l, 131072, (size_t)2048 * 256);

  // 5. second stages: g = f1 @ Wf2 (split); gate = g1 @ Wg2
  gemm_btsplit<<<dim3(16, 16), 256, 0, stream>>>(f1g1h, f1g1l, Wf2hT, Wf2lT, gbuf,
                                                 2048, 2048, 256, 128, 128);
  gemm_bt<<<dim3(16, 16), 256, 0, stream>>>(f1g1h + 128, Wg2T, gatebuf,
                                            2048, 2048, 256, 128, 128, 0);

  // 6. beta
  beta_kernel<<<128, 256, 0, stream>>>(x, Wb, betaT);

  // 7. prep (conv+silu+mix+l2norm) from merged qkv (stride 6144)
  prep_plain<<<HN * SEQL, 64, 0, stream>>>(qkv, qkv + 2048, qkv + 4096, 6144,
                                           ve, lam, cwq, cwk, cwv, karr, qarr, varr);

  // 8. chunk-local precompute (overwrites qkv overlays Xgh/KTh)
  kda_pre<<<1024, 256, 0, stream>>>(karr, qarr, varr, gbuf, dtb, A_log, betaT,
                                    Xgh, KTh, uvS, olocS, Pg);

  // 9. sequential chunk scan (128 blocks: h x v-eighth)
  kda_seq<<<128, 256, 0, stream>>>(Xgh, KTh, uvS, olocS, Pg, obuf);

  // 10. gated rmsnorm -> bf16 (og aliases qarr)
  rmsgate_kernel<<<8192, 256, 0, stream>>>(obuf, gatebuf, bg2, norm_w, og);

  // 11. output projection
  gemm_bt<<<dim3(16, 16), 256, 0, stream>>>(og, WoT, out, 2048, 2048, 2048, 2048, 2048, 0);
}

// Round 7
// 426.002 us; speedup vs baseline: 2.2636x; 1.0758x over previous
//
#include <hip/hip_runtime.h>
#include <hip/hip_bf16.h>
#include <stdint.h>
#include <stddef.h>

#define SEQL 2048
#define DIMSZ 2048
#define HN 16
#define DKD 128
#define DVD 128
#define QSCALE 0.08838834764831843f   // 128^-0.5

typedef __attribute__((ext_vector_type(4))) float f32x4;
typedef __attribute__((ext_vector_type(2))) float f32x2;
typedef __attribute__((ext_vector_type(8))) short bf16x8;

__device__ __forceinline__ float sigmoid_f(float x) { return 1.f / (1.f + __expf(-x)); }

// ---------------- bf16 GEMM: C[M,N] (f32) = A[M,K]bf16 @ Bt[N,K]bf16 ----------------
#define BM 128
#define BN 128
#define BKK 64

__global__ __launch_bounds__(256) void gemm_bt(
    const __hip_bfloat16* __restrict__ A, const __hip_bfloat16* __restrict__ B,
    float* __restrict__ C, int M, int N, int lda, int ldb, int klen, int accum)
{
  __shared__ __hip_bfloat16 As[BM * BKK];
  __shared__ __hip_bfloat16 Bs[BN * BKK];
  const int tid = threadIdx.x;
  const int lane = tid & 63;
  const int w = tid >> 6;
  const int wm = w >> 1, wn = w & 1;            // 2x2 wave grid, 64x64 each
  const int m0 = blockIdx.y * BM, n0 = blockIdx.x * BN;
  const int l15 = lane & 15, l4 = lane >> 4;
  const int kbase = blockIdx.z * klen;

  f32x4 acc[4][4] = {};

  for (int k0 = kbase; k0 < kbase + klen; k0 += BKK) {
#pragma unroll
    for (int i = 0; i < 4; ++i) {
      const int c = (w * 4 + i) * 64 + lane;     // chunk id, 16B each; 8 chunks/row
      const int row = c >> 3;
      const int colb = (c & 7) * 8;
      __builtin_amdgcn_global_load_lds(
          (const __attribute__((address_space(1))) void*)(A + (size_t)(m0 + row) * lda + k0 + colb),
          (__attribute__((address_space(3))) void*)(As + (size_t)c * 8), 16, 0, 0);
      __builtin_amdgcn_global_load_lds(
          (const __attribute__((address_space(1))) void*)(B + (size_t)(n0 + row) * ldb + k0 + colb),
          (__attribute__((address_space(3))) void*)(Bs + (size_t)c * 8), 16, 0, 0);
    }
    __syncthreads();
#pragma unroll
    for (int kk = 0; kk < BKK; kk += 32) {
      bf16x8 af[4], bfv[4];
#pragma unroll
      for (int mi = 0; mi < 4; ++mi)
        af[mi] = *(const bf16x8*)(As + (wm * 64 + mi * 16 + l15) * BKK + kk + l4 * 8);
#pragma unroll
      for (int ni = 0; ni < 4; ++ni)
        bfv[ni] = *(const bf16x8*)(Bs + (wn * 64 + ni * 16 + l15) * BKK + kk + l4 * 8);
#pragma unroll
      for (int mi = 0; mi < 4; ++mi)
#pragma unroll
        for (int ni = 0; ni < 4; ++ni)
          acc[mi][ni] = __builtin_amdgcn_mfma_f32_16x16x32_bf16(af[mi], bfv[ni], acc[mi][ni], 0, 0, 0);
    }
    __syncthreads();
  }

  float* Cz = C + (size_t)blockIdx.z * M * N;
#pragma unroll
  for (int mi = 0; mi < 4; ++mi) {
#pragma unroll
    for (int ni = 0; ni < 4; ++ni) {
      const int row = m0 + wm * 64 + mi * 16 + l4 * 4;
      const int col = n0 + wn * 64 + ni * 16 + l15;
#pragma unroll
      for (int r = 0; r < 4; ++r) {
        size_t idx = (size_t)(row + r) * N + col;
        if (accum) Cz[idx] += acc[mi][ni][r];
        else Cz[idx] = acc[mi][ni][r];
      }
    }
  }
}

// ---------------- 256x256 8-phase GEMM (T2+T3+T4+T5), for large-N projections ----------------
// 512 thr = 8 waves (2m x 4n), 128x64 out/wave. LDS 128KB: 2 buf x {A,B} x 256row x 64k bf16.
// LDS rows quadrant-grouped; kc ^= (row&7) swizzle on BOTH gload-source and ds_read (G21).
// Counted vmcnt(6)/vmcnt(4) at phases 0/1 only; raw s_barrier (no __syncthreads drain).
#define PHASE256(MQ, NQ, NEEDA, NEEDB)                                          \
  {                                                                             \
    if (NEEDA) {                                                                \
      _Pragma("unroll") for (int m2 = 0; m2 < 4; ++m2)                          \
      _Pragma("unroll") for (int ks = 0; ks < 2; ++ks) {                        \
        const int la = (MQ) * 128 + wm * 64 + m2 * 16 + l15;                    \
        const int kc = ks * 4 + l4;                                             \
        a[m2][ks] = *(const bf16x8*)(lds + cb + la * 64 + (kc ^ (la & 7)) * 8); \
      }                                                                         \
    }                                                                           \
    if (NEEDB) {                                                                \
      _Pragma("unroll") for (int n2 = 0; n2 < 2; ++n2)                          \
      _Pragma("unroll") for (int ks = 0; ks < 2; ++ks) {                        \
        const int lb = (NQ) * 128 + wn * 32 + n2 * 16 + l15;                    \
        const int kc = ks * 4 + l4;                                             \
        b[n2][ks] = *(const bf16x8*)(lds + cb + 16384 + lb * 64 + (kc ^ (lb & 7)) * 8); \
      }                                                                         \
    }                                                                           \
    __builtin_amdgcn_s_setprio(1);                                              \
    _Pragma("unroll") for (int m2 = 0; m2 < 4; ++m2)                            \
    _Pragma("unroll") for (int n2 = 0; n2 < 2; ++n2)                            \
    _Pragma("unroll") for (int ks = 0; ks < 2; ++ks)                            \
      acc[(MQ) * 4 + m2][(NQ) * 2 + n2] = __builtin_amdgcn_mfma_f32_16x16x32_bf16( \
          a[m2][ks], b[n2][ks], acc[(MQ) * 4 + m2][(NQ) * 2 + n2], 0, 0, 0);    \
    __builtin_amdgcn_s_setprio(0);                                              \
  }

__global__ __launch_bounds__(512, 2) void gemm_bt256(
    const __hip_bfloat16* __restrict__ A, const __hip_bfloat16* __restrict__ B,
    float* __restrict__ C, int M, int N, int lda, int ldb, int NT)
{
  __shared__ __hip_bfloat16 lds[65536];   // 128 KiB
  const int tid = threadIdx.x;
  const int w = tid >> 6, lane = tid & 63;
  const int wm = w >> 2, wn = w & 3;
  const int l15 = lane & 15, l4 = lane >> 4;
  const int m0 = blockIdx.y * 256, n0 = blockIdx.x * 256;

  f32x4 acc[8][4] = {};
  bf16x8 a[4][2], b[2][2];

  auto stage_half = [&](int which, int t1) {
    const int buf = t1 & 1;
    const int k0n = ((t1 < NT) ? t1 : 0) * 64;
    const int mat = which & 1;          // 0=A, 1=B
    const int half = which >> 1;
#pragma unroll
    for (int i = 0; i < 2; ++i) {
      const int c = i * 512 + tid;           // chunk 0..1023 within half (16B each)
      const int l = half * 128 + (c >> 3);   // lds row 0..255 (quadrant-grouped)
      const int kcs = (c & 7) ^ (l & 7);     // pre-swizzled source chunk
      const __hip_bfloat16* src;
      if (mat == 0) {
        const int grow = ((l >> 6) & 1) * 128 + (l >> 7) * 64 + (l & 63);
        src = A + (size_t)(m0 + grow) * lda + k0n + kcs * 8;
      } else {
        const int gcol = ((l >> 5) & 3) * 64 + (l >> 7) * 32 + (l & 31);
        src = B + (size_t)(n0 + gcol) * ldb + k0n + kcs * 8;
      }
      __builtin_amdgcn_global_load_lds(
          (const __attribute__((address_space(1))) void*)src,
          (__attribute__((address_space(3))) void*)(lds + (size_t)buf * 32768 + mat * 16384 + half * 8192 + (size_t)c * 8),
          16, 0, 0);
    }
  };

  // prologue: fully stage tile 0 (A-lo, B-lo, A-hi, B-hi)
  stage_half(0, 0); stage_half(1, 0); stage_half(2, 0); stage_half(3, 0);

  for (int t = 0; t < NT; ++t) {
    const size_t cb = (size_t)(t & 1) * 32768;
    // phase 0: quad (0,0) — needs prev A-lo,B-lo
    stage_half(0, t + 1);
    asm volatile("s_waitcnt vmcnt(6)" ::: "memory");
    __builtin_amdgcn_s_barrier();
    __builtin_amdgcn_sched_barrier(0);
    PHASE256(0, 0, 1, 1)
    __builtin_amdgcn_s_barrier();
    // phase 1: quad (0,1) — needs prev B-hi (all of prev tile)
    stage_half(1, t + 1);
    asm volatile("s_waitcnt vmcnt(4)" ::: "memory");
    __builtin_amdgcn_s_barrier();
    __builtin_amdgcn_sched_barrier(0);
    PHASE256(0, 1, 0, 1)
    __builtin_amdgcn_s_barrier();
    // phase 2: quad (1,1) — A-hi already covered
    stage_half(2, t + 1);
    __builtin_amdgcn_s_barrier();
    __builtin_amdgcn_sched_barrier(0);
    PHASE256(1, 1, 1, 0)
    __builtin_amdgcn_s_barrier();
    // phase 3: quad (1,0) — B-lo re-read
    stage_half(3, t + 1);
    __builtin_amdgcn_s_barrier();
    __builtin_amdgcn_sched_barrier(0);
    PHASE256(1, 0, 0, 1)
    __builtin_amdgcn_s_barrier();
  }
  asm volatile("s_waitcnt vmcnt(0)" ::: "memory");

#pragma unroll
  for (int mi = 0; mi < 8; ++mi) {
#pragma unroll
    for (int ni = 0; ni < 4; ++ni) {
      const int row = m0 + wm * 128 + mi * 16 + l4 * 4;
      const int col = n0 + wn * 64 + ni * 16 + l15;
#pragma unroll
      for (int r = 0; r < 4; ++r)
        C[(size_t)(row + r) * N + col] = acc[mi][ni][r];
    }
  }
}

// ---------------- fused split-precision GEMM: C = Ah@Bh + Ah@Bl + Al@Bh ----------------
__global__ __launch_bounds__(256) void gemm_btsplit(
    const __hip_bfloat16* __restrict__ Ah, const __hip_bfloat16* __restrict__ Al,
    const __hip_bfloat16* __restrict__ Bh, const __hip_bfloat16* __restrict__ Bl,
    float* __restrict__ C, int M, int N, int lda, int ldb, int klen)
{
  __shared__ __hip_bfloat16 Ash[BM * BKK];
  __shared__ __hip_bfloat16 Asl[BM * BKK];
  __shared__ __hip_bfloat16 Bsh[BN * BKK];
  __shared__ __hip_bfloat16 Bsl[BN * BKK];
  const int tid = threadIdx.x;
  const int lane = tid & 63;
  const int w = tid >> 6;
  const int wm = w >> 1, wn = w & 1;
  const int m0 = blockIdx.y * BM, n0 = blockIdx.x * BN;
  const int l15 = lane & 15, l4 = lane >> 4;
  const int kbase = blockIdx.z * klen;

  f32x4 acc[4][4] = {};

  for (int k0 = kbase; k0 < kbase + klen; k0 += BKK) {
#pragma unroll
    for (int i = 0; i < 4; ++i) {
      const int c = (w * 4 + i) * 64 + lane;
      const int row = c >> 3;
      const int colb = (c & 7) * 8;
      const size_t go = (size_t)(m0 + row) * lda + k0 + colb;
      const size_t gn = (size_t)(n0 + row) * ldb + k0 + colb;
      __builtin_amdgcn_global_load_lds(
          (const __attribute__((address_space(1))) void*)(Ah + go),
          (__attribute__((address_space(3))) void*)(Ash + (size_t)c * 8), 16, 0, 0);
      __builtin_amdgcn_global_load_lds(
          (const __attribute__((address_space(1))) void*)(Al + go),
          (__attribute__((address_space(3))) void*)(Asl + (size_t)c * 8), 16, 0, 0);
      __builtin_amdgcn_global_load_lds(
          (const __attribute__((address_space(1))) void*)(Bh + gn),
          (__attribute__((address_space(3))) void*)(Bsh + (size_t)c * 8), 16, 0, 0);
      __builtin_amdgcn_global_load_lds(
          (const __attribute__((address_space(1))) void*)(Bl + gn),
          (__attribute__((address_space(3))) void*)(Bsl + (size_t)c * 8), 16, 0, 0);
    }
    __syncthreads();
#pragma unroll
    for (int kk = 0; kk < BKK; kk += 32) {
      bf16x8 afh[4], afl[4], bfh[4], bfl[4];
#pragma unroll
      for (int mi = 0; mi < 4; ++mi) {
        const int ao = (wm * 64 + mi * 16 + l15) * BKK + kk + l4 * 8;
        afh[mi] = *(const bf16x8*)(Ash + ao);
        afl[mi] = *(const bf16x8*)(Asl + ao);
      }
#pragma unroll
      for (int ni = 0; ni < 4; ++ni) {
        const int bo = (wn * 64 + ni * 16 + l15) * BKK + kk + l4 * 8;
        bfh[ni] = *(const bf16x8*)(Bsh + bo);
        bfl[ni] = *(const bf16x8*)(Bsl + bo);
      }
#pragma unroll
      for (int mi = 0; mi < 4; ++mi)
#pragma unroll
        for (int ni = 0; ni < 4; ++ni) {
          acc[mi][ni] = __builtin_amdgcn_mfma_f32_16x16x32_bf16(afh[mi], bfh[ni], acc[mi][ni], 0, 0, 0);
          acc[mi][ni] = __builtin_amdgcn_mfma_f32_16x16x32_bf16(afh[mi], bfl[ni], acc[mi][ni], 0, 0, 0);
          acc[mi][ni] = __builtin_amdgcn_mfma_f32_16x16x32_bf16(afl[mi], bfh[ni], acc[mi][ni], 0, 0, 0);
        }
    }
    __syncthreads();
  }

  float* Cz = C + (size_t)blockIdx.z * M * N;
#pragma unroll
  for (int mi = 0; mi < 4; ++mi) {
#pragma unroll
    for (int ni = 0; ni < 4; ++ni) {
      const int row = m0 + wm * 64 + mi * 16 + l4 * 4;
      const int col = n0 + wn * 64 + ni * 16 + l15;
#pragma unroll
      for (int r = 0; r < 4; ++r)
        Cz[(size_t)(row + r) * N + col] = acc[mi][ni][r];
    }
  }
}

// ---------------- transpose + cast (optional hi/lo split): out[C,R] = bf16(in[R,C]^T) ----------------
__global__ __launch_bounds__(256) void transpose_cast_kernel(
    const float* __restrict__ in, __hip_bfloat16* __restrict__ outT,
    __hip_bfloat16* __restrict__ outLo, int R, int C)
{
  __shared__ float tile[32][33];
  const int c0 = blockIdx.x * 32, r0 = blockIdx.y * 32;
  const int tc = threadIdx.x & 31, tr = threadIdx.x >> 5;   // tr in 0..7
#pragma unroll
  for (int i = 0; i < 4; ++i)
    tile[tr + i * 8][tc] = in[(size_t)(r0 + tr + i * 8) * C + c0 + tc];
  __syncthreads();
#pragma unroll
  for (int i = 0; i < 4; ++i) {
    float val = tile[tc][tr + i * 8];
    __hip_bfloat16 h = __float2bfloat16(val);
    size_t oi = (size_t)(c0 + tr + i * 8) * R + r0 + tc;
    outT[oi] = h;
    if (outLo) outLo[oi] = __float2bfloat16(val - __bfloat162float(h));
  }
}

// ---------------- elementwise cast with optional lo residual ----------------
__global__ __launch_bounds__(256) void cast_split_kernel(
    const float* __restrict__ in, __hip_bfloat16* __restrict__ hi,
    __hip_bfloat16* __restrict__ lo, int n4)
{
  int idx = blockIdx.x * 256 + threadIdx.x;
  if (idx >= n4) return;
  f32x4 v = *(const f32x4*)(in + (size_t)idx * 4);
  union { __hip_bfloat16 b[4]; unsigned long long u; } ph, pl;
#pragma unroll
  for (int j = 0; j < 4; ++j) {
    float f = v[j];
    __hip_bfloat16 hh = __float2bfloat16(f);
    ph.b[j] = hh;
    pl.b[j] = __float2bfloat16(f - __bfloat162float(hh));
  }
  *(unsigned long long*)((char*)hi + (size_t)idx * 8) = ph.u;
  if (lo) *(unsigned long long*)((char*)lo + (size_t)idx * 8) = pl.u;
}

// ---------------- split-K reduce (8 partials) -> bf16 hi (+ optional lo) ----------------
__global__ __launch_bounds__(256) void reduce8_kernel(
    const float* __restrict__ part, __hip_bfloat16* __restrict__ hi,
    __hip_bfloat16* __restrict__ lo, int n4, size_t chunk)
{
  int idx = blockIdx.x * 256 + threadIdx.x;
  if (idx >= n4) return;
  f32x4 a = *(const f32x4*)(part + (size_t)idx * 4);
#pragma unroll
  for (int z = 1; z < 8; ++z) {
    f32x4 b = *(const f32x4*)(part + z * chunk + (size_t)idx * 4);
    a.x += b.x; a.y += b.y; a.z += b.z; a.w += b.w;
  }
  union { __hip_bfloat16 b[4]; unsigned long long u; } ph, pl;
#pragma unroll
  for (int j = 0; j < 4; ++j) {
    float f = a[j];
    __hip_bfloat16 hh = __float2bfloat16(f);
    ph.b[j] = hh;
    pl.b[j] = __float2bfloat16(f - __bfloat162float(hh));
  }
  *(unsigned long long*)((char*)hi + (size_t)idx * 8) = ph.u;
  if (lo) *(unsigned long long*)((char*)lo + (size_t)idx * 8) = pl.u;
}

// ---------------- beta = sigmoid(x @ Wb), thread per (s,h); writes [h][s] ----------------
__global__ __launch_bounds__(256) void beta_kernel(
    const float* __restrict__ x, const float* __restrict__ Wb, float* __restrict__ betaT)
{
  int idx = blockIdx.x * 256 + threadIdx.x;      // 0..32767
  int s = idx >> 4, h = idx & 15;
  const float* xr = x + (size_t)s * DIMSZ;
  float acc = 0.f;
  for (int d = 0; d < DIMSZ; d += 4) {
    f32x4 xv = *(const f32x4*)(xr + d);
    acc = fmaf(xv.x, Wb[(size_t)(d + 0) * HN + h], acc);
    acc = fmaf(xv.y, Wb[(size_t)(d + 1) * HN + h], acc);
    acc = fmaf(xv.z, Wb[(size_t)(d + 2) * HN + h], acc);
    acc = fmaf(xv.w, Wb[(size_t)(d + 3) * HN + h], acc);
  }
  betaT[(size_t)h * SEQL + s] = 1.f / (1.f + expf(-acc));
}

// ---------------- fused conv+silu+mix+l2norm -> plain arrays [s][h*128+d] ----------------
__global__ __launch_bounds__(64) void prep_plain(
    const float* __restrict__ xq, const float* __restrict__ xk, const float* __restrict__ xv,
    int xstr,
    const float* __restrict__ ve, const float* __restrict__ lam,
    const float* __restrict__ cwq, const float* __restrict__ cwk, const float* __restrict__ cwv,
    float* __restrict__ karr, float* __restrict__ qarr, float* __restrict__ varr)
{
  const int bid = blockIdx.x;          // h*2048 + t
  const int h = bid >> 11, t = bid & 2047;
  const int d2 = threadIdx.x * 2;      // channels d2, d2+1 of this head
  const int c = h * 128 + d2;

  f32x4 wq0 = *(const f32x4*)(cwq + (size_t)c * 4), wq1 = *(const f32x4*)(cwq + (size_t)(c + 1) * 4);
  f32x4 wk0 = *(const f32x4*)(cwk + (size_t)c * 4), wk1 = *(const f32x4*)(cwk + (size_t)(c + 1) * 4);
  f32x4 wv0 = *(const f32x4*)(cwv + (size_t)c * 4), wv1 = *(const f32x4*)(cwv + (size_t)(c + 1) * 4);

  float aq0 = 0, aq1 = 0, ak0 = 0, ak1 = 0, av0 = 0, av1 = 0;
#pragma unroll
  for (int i = 0; i < 4; ++i) {
    int sr = t - 3 + i;
    if (sr >= 0) {
      f32x2 a = *(const f32x2*)(xq + (size_t)sr * xstr + c);
      f32x2 b = *(const f32x2*)(xk + (size_t)sr * xstr + c);
      f32x2 d = *(const f32x2*)(xv + (size_t)sr * xstr + c);
      aq0 = fmaf(a.x, wq0[i], aq0); aq1 = fmaf(a.y, wq1[i], aq1);
      ak0 = fmaf(b.x, wk0[i], ak0); ak1 = fmaf(b.y, wk1[i], ak1);
      av0 = fmaf(d.x, wv0[i], av0); av1 = fmaf(d.y, wv1[i], av1);
    }
  }
  float yq0 = aq0 * sigmoid_f(aq0), yq1 = aq1 * sigmoid_f(aq1);
  float yk0 = ak0 * sigmoid_f(ak0), yk1 = ak1 * sigmoid_f(ak1);
  float yv0 = av0 * sigmoid_f(av0), yv1 = av1 * sigmoid_f(av1);

  float l0 = lam[0], l1 = lam[1];
  f32x2 vev = *(const f32x2*)(ve + ((size_t)t * HN + h) * 128 + d2);
  float v0 = l0 * yv0 + l1 * vev.x;
  float v1 = l0 * yv1 + l1 * vev.y;

  float ssq = yq0 * yq0 + yq1 * yq1;
  float ssk = yk0 * yk0 + yk1 * yk1;
#pragma unroll
  for (int off = 32; off > 0; off >>= 1) {
    ssq += __shfl_xor(ssq, off);
    ssk += __shfl_xor(ssk, off);
  }
  float rq = rsqrtf(ssq + 1e-6f) * QSCALE;
  float rk = rsqrtf(ssk + 1e-6f);

  size_t o = (size_t)t * 2048 + c;
  f32x2 kk; kk.x = yk0 * rk; kk.y = yk1 * rk;
  f32x2 qq; qq.x = yq0 * rq; qq.y = yq1 * rq;
  f32x2 vv2; vv2.x = v0; vv2.y = v1;
  *(f32x2*)(karr + o) = kk;
  *(f32x2*)(qarr + o) = qq;
  *(f32x2*)(varr + o) = vv2;
}

// ---------------- chunk-local precompute (C=32), fp32, register-tiled pairs ----------------
#define GP 132

__global__ __launch_bounds__(256) void kda_pre(
    const float* __restrict__ karr, const float* __restrict__ qarr,
    const float* __restrict__ varr, const float* __restrict__ gbuf,
    const float* __restrict__ dtb, const float* __restrict__ A_log,
    const float* __restrict__ betaT,
    __hip_bfloat16* __restrict__ Xgh, __hip_bfloat16* __restrict__ KTh,
    float* __restrict__ uvS, float* __restrict__ olocS, float* __restrict__ Pg)
{
  __shared__ float kL[32 * GP], qL[32 * GP], GL[32 * GP];
  __shared__ float AL[32][33], BL[32][33], betaL[32], csum[128];
  const int bid = blockIdx.x;
  const int h = bid >> 6, cc = bid & 63;
  const int tid = threadIdx.x;
  const int col = tid & 127, half = tid >> 7;
  const size_t rowbase = (size_t)(cc * 32) * 2048 + h * 128 + col;
  const size_t hc = (size_t)h * 64 + cc;

  const float Aexp = __expf(A_log[h]);
  const float dtv = dtb[h * 128 + col];
  const int rbase = half * 16;

  float gloc[16];
#pragma unroll
  for (int i = 0; i < 16; ++i) {
    int r = rbase + i;
    size_t o = rowbase + (size_t)r * 2048;
    kL[r * GP + col] = karr[o];
    qL[r * GP + col] = qarr[o];
    float gv = gbuf[o] + dtv;
    float sp = (gv > 20.f) ? gv : log1pf(__expf(fminf(gv, 20.f)));
    gloc[i] = -Aexp * sp;
  }
  {
    float run = 0.f;
#pragma unroll
    for (int i = 0; i < 16; ++i) { run += gloc[i]; gloc[i] = run; }
    if (half == 0) csum[col] = run;
  }
  if (tid < 32) betaL[tid] = betaT[(size_t)h * SEQL + cc * 32 + tid];
  float vreg[32];
  if (half == 0) {
#pragma unroll
    for (int r = 0; r < 32; ++r) vreg[r] = varr[rowbase + (size_t)r * 2048];
  }
  __syncthreads();
  {
    float base = (half == 0) ? 0.f : csum[col];
#pragma unroll
    for (int i = 0; i < 16; ++i) GL[(rbase + i) * GP + col] = gloc[i] + base;
  }
  __syncthreads();

  // ---- pairs phase: A[t][i], B[t][i] ----
  const int w = tid >> 6, l = tid & 63;
  const int tg = l >> 3, s8 = l & 7;
  const int tt = w + tg * 4;
  const int ds = s8 * 16;

  float Gt[16], kt[16], qt[16];
#pragma unroll
  for (int j = 0; j < 16; j += 4) {
    *(f32x4*)&Gt[j] = *(const f32x4*)&GL[tt * GP + ds + j];
    *(f32x4*)&kt[j] = *(const f32x4*)&kL[tt * GP + ds + j];
    *(f32x4*)&qt[j] = *(const f32x4*)&qL[tt * GP + ds + j];
  }
  {
    float sA = 0.f, sB = 0.f;
#pragma unroll
    for (int j = 0; j < 16; ++j) { sA = fmaf(kt[j], kt[j], sA); sB = fmaf(qt[j], kt[j], sB); }
    sA += __shfl_xor(sA, 1); sA += __shfl_xor(sA, 2); sA += __shfl_xor(sA, 4);
    sB += __shfl_xor(sB, 1); sB += __shfl_xor(sB, 2); sB += __shfl_xor(sB, 4);
    if (s8 == 0) { AL[tt][tt] = sA; BL[tt][tt] = sB; }
  }
  for (int i = 0; i < 28 + w; ++i) {
    if (i < tt) {
      float sA = 0.f, sB = 0.f;
#pragma unroll
      for (int jj = 0; jj < 4; ++jj) {
        f32x4 Gi = *(const f32x4*)&GL[i * GP + ds + jj * 4];
        f32x4 ki = *(const f32x4*)&kL[i * GP + ds + jj * 4];
#pragma unroll
        for (int u = 0; u < 4; ++u) {
          float e = __expf(Gt[jj * 4 + u] - Gi[u]);
          float kid = ki[u] * e;
          sA = fmaf(kt[jj * 4 + u], kid, sA);
          sB = fmaf(qt[jj * 4 + u], kid, sB);
        }
      }
      sA += __shfl_xor(sA, 1); sA += __shfl_xor(sA, 2); sA += __shfl_xor(sA, 4);
      sB += __shfl_xor(sB, 1); sB += __shfl_xor(sB, 2); sB += __shfl_xor(sB, 4);
      if (s8 == 0) { AL[tt][i] = sA; BL[tt][i] = sB; }
    }
  }
  __syncthreads();

  {
    const float g31 = GL[31 * GP + col];
    size_t kb = hc * 4096 + (size_t)col * 32;
#pragma unroll
    for (int i = 0; i < 16; ++i) {
      int r = rbase + i;
      float kv = kL[r * GP + col] * __expf(g31 - GL[r * GP + col]);
      KTh[kb + r] = __float2bfloat16(kv);
    }
  }

  if (half == 0) {
    float expg[32];
#pragma unroll
    for (int r = 0; r < 32; ++r) expg[r] = __expf(GL[r * GP + col]);

    float uvr[32], wr[32];
#pragma unroll
    for (int r = 0; r < 32; ++r) {
      float suv = 0.f, sw = 0.f;
#pragma unroll
      for (int j = 0; j < 32; ++j) {
        if (j < r) { float a = AL[r][j]; suv = fmaf(a, uvr[j], suv); sw = fmaf(a, wr[j], sw); }
      }
      float br = betaL[r];
      float khr = kL[r * GP + col] * expg[r];
      uvr[r] = br * (vreg[r] - suv);
      wr[r] = br * (khr - sw);
      uvS[rowbase + (size_t)r * 2048] = uvr[r];
      Xgh[hc * 8192 + (size_t)(32 + r) * 128 + col] = __float2bfloat16(wr[r]);
    }

#pragma unroll
    for (int r = 0; r < 32; ++r) {
      float qtv = qL[r * GP + col] * expg[r];
      float ol = 0.f;
#pragma unroll
      for (int j = 0; j < 32; ++j) {
        if (j <= r) { float b = BL[r][j]; qtv = fmaf(-b, wr[j], qtv); ol = fmaf(b, uvr[j], ol); }
      }
      Xgh[hc * 8192 + (size_t)r * 128 + col] = __float2bfloat16(qtv);
      olocS[rowbase + (size_t)r * 2048] = ol;
    }
    Pg[hc * 128 + col] = expg[31];
  }
}

// ---------------- sequential chunk scan: S in MFMA accumulators, reg-prefetched ----------------
#define STP 136
#define UTP 40

struct ChunkOps {
  bf16x8 ah[4];
  bf16x8 kah[2];
  f32x4 pvv[2];
  float pB[4];
};

__global__ __launch_bounds__(256) void kda_seq(
    const __hip_bfloat16* __restrict__ Xgh, const __hip_bfloat16* __restrict__ KTh,
    const float* __restrict__ uvS, const float* __restrict__ olocS,
    const float* __restrict__ Pg, float* __restrict__ obuf)
{
  __shared__ __hip_bfloat16 STh[16 * STP], STl[16 * STP];
  __shared__ __hip_bfloat16 UTh[16 * UTP];
  const int tid = threadIdx.x;
  const int w = tid >> 6, lane = tid & 63, l15 = lane & 15, l4 = lane >> 4;
  const int h = blockIdx.x >> 3, vq = blockIdx.x & 7;
  const int v0 = vq * 16;
  const int r0 = (w & 1) * 16 + l4 * 4;
  const int isO = (w < 2);

  for (int i = tid; i < 16 * STP; i += 256) {
    STh[i] = __float2bfloat16(0.f);
    STl[i] = __float2bfloat16(0.f);
  }
  __syncthreads();

  f32x4 S[2] = {};

  auto loadops = [&](ChunkOps& o, int c) {
    const size_t hc = (size_t)h * 64 + c;
    const __hip_bfloat16* xh = Xgh + hc * 8192 + (size_t)(w * 16 + l15) * 128 + l4 * 8;
#pragma unroll
    for (int kk = 0; kk < 4; ++kk) o.ah[kk] = *(const bf16x8*)(xh + kk * 32);
    const float* pb = (isO ? olocS : uvS) + (size_t)(c * 32 + r0) * 2048 + h * 128 + v0 + l15;
#pragma unroll
    for (int r = 0; r < 4; ++r) o.pB[r] = pb[(size_t)r * 2048];
#pragma unroll
    for (int mi = 0; mi < 2; ++mi) {
      const int kd = (w * 2 + mi) * 16;
      o.kah[mi] = *(const bf16x8*)(KTh + hc * 4096 + (size_t)(kd + l15) * 32 + l4 * 8);
      o.pvv[mi] = *(const f32x4*)(Pg + hc * 128 + kd + l4 * 4);
    }
  };

  auto body = [&](ChunkOps& o, int c) {
    f32x4 Y = {};
#pragma unroll
    for (int kk = 0; kk < 4; ++kk) {
      const int so = l15 * STP + kk * 32 + l4 * 8;
      bf16x8 bh = *(const bf16x8*)(STh + so);
      bf16x8 bl = *(const bf16x8*)(STl + so);
      Y = __builtin_amdgcn_mfma_f32_16x16x32_bf16(o.ah[kk], bh, Y, 0, 0, 0);
      Y = __builtin_amdgcn_mfma_f32_16x16x32_bf16(o.ah[kk], bl, Y, 0, 0, 0);
    }

    if (isO) {
      size_t ob = (size_t)(c * 32 + r0) * 2048 + h * 128 + v0 + l15;
#pragma unroll
      for (int r = 0; r < 4; ++r)
        obuf[ob + (size_t)r * 2048] = Y[r] + o.pB[r];
    } else {
      union { __hip_bfloat16 b[4]; unsigned long long u; } uh;
#pragma unroll
      for (int r = 0; r < 4; ++r)
        uh.b[r] = __float2bfloat16(o.pB[r] - Y[r]);
      *(unsigned long long*)(UTh + l15 * UTP + r0) = uh.u;
    }
    __syncthreads();

#pragma unroll
    for (int mi = 0; mi < 2; ++mi) S[mi] *= o.pvv[mi];
    {
      bf16x8 ubh = *(const bf16x8*)(UTh + l15 * UTP + l4 * 8);
#pragma unroll
      for (int mi = 0; mi < 2; ++mi)
        S[mi] = __builtin_amdgcn_mfma_f32_16x16x32_bf16(o.kah[mi], ubh, S[mi], 0, 0, 0);
    }

#pragma unroll
    for (int mi = 0; mi < 2; ++mi) {
      const int kd0 = (w * 2 + mi) * 16 + l4 * 4;
      union { __hip_bfloat16 b[4]; unsigned long long u; } sh, sl;
#pragma unroll
      for (int r = 0; r < 4; ++r) {
        __hip_bfloat16 hh = __float2bfloat16(S[mi][r]);
        sh.b[r] = hh;
        sl.b[r] = __float2bfloat16(S[mi][r] - __bfloat162float(hh));
      }
      *(unsigned long long*)(STh + l15 * STP + kd0) = sh.u;
      *(unsigned long long*)(STl + l15 * STP + kd0) = sl.u;
    }
    __syncthreads();
  };

  ChunkOps A_, B_;
  loadops(A_, 0);
  for (int c = 0; c < 64; c += 2) {
    loadops(B_, c + 1);
    body(A_, c);
    if (c + 2 < 64) loadops(A_, c + 2);
    body(B_, c + 1);
  }
}

// ---------------- sigmoid-gated RMSNorm -> bf16 ----------------
__global__ __launch_bounds__(256) void rmsgate_kernel(
    const float* __restrict__ o, const float* __restrict__ gate,
    const float* __restrict__ bg2, const float* __restrict__ norm_w,
    __hip_bfloat16* __restrict__ og)
{
  int row = blockIdx.x * 4 + (threadIdx.x >> 6);   // s*16 + h
  int lane = threadIdx.x & 63;
  int s = row >> 4, h = row & 15;
  int j = lane * 2;
  const float* p = o + (size_t)row * 128 + j;
  f32x2 v = *(const f32x2*)p;
  float ss = v.x * v.x + v.y * v.y;
#pragma unroll
  for (int off = 32; off > 0; off >>= 1) ss += __shfl_xor(ss, off);
  float rs = rsqrtf(ss * (1.f / 128.f) + 1e-6f);
  int c = h * 128 + j;
  float g0 = gate[(size_t)s * 2048 + c] + bg2[c];
  float g1 = gate[(size_t)s * 2048 + c + 1] + bg2[c + 1];
  float o0 = v.x * rs * norm_w[j] * (1.f / (1.f + expf(-g0)));
  float o1 = v.y * rs * norm_w[j + 1] * (1.f / (1.f + expf(-g1)));
  union { __hip_bfloat16 b[2]; unsigned int u; } pk2;
  pk2.b[0] = __float2bfloat16(o0);
  pk2.b[1] = __float2bfloat16(o1);
  *(unsigned int*)((char*)og + ((size_t)s * 2048 + c) * 2) = pk2.u;
}

// =====================================================================
extern "C" void kernel_launch(void* const* d_in, const int* in_sizes, int n_in,
                              void* d_out, int out_size, void* d_ws, size_t ws_size,
                              hipStream_t stream)
{
  const float* x      = (const float*)d_in[0];
  const float* ve     = (const float*)d_in[1];
  const float* lam    = (const float*)d_in[2];
  const float* Wq     = (const float*)d_in[3];
  const float* Wk     = (const float*)d_in[4];
  const float* Wv     = (const float*)d_in[5];
  const float* cwq    = (const float*)d_in[6];
  const float* cwk    = (const float*)d_in[7];
  const float* cwv    = (const float*)d_in[8];
  const float* Wf1    = (const float*)d_in[9];
  const float* Wf2    = (const float*)d_in[10];
  const float* Wb     = (const float*)d_in[11];
  const float* A_log  = (const float*)d_in[12];
  const float* dtb    = (const float*)d_in[13];
  const float* Wg1    = (const float*)d_in[14];
  const float* Wg2    = (const float*)d_in[15];
  const float* bg2    = (const float*)d_in[16];
  const float* norm_w = (const float*)d_in[17];
  const float* Wo     = (const float*)d_in[18];
  float* out = (float*)d_out;

  const size_t S2 = (size_t)2048 * 2048;

  char* p = (char*)d_ws;
  auto alloc = [&](size_t bytes) { char* r = p; p += (bytes + 255) & ~(size_t)255; return r; };

  __hip_bfloat16* xb     = (__hip_bfloat16*)alloc(S2 * 2);
  __hip_bfloat16* WoT    = (__hip_bfloat16*)alloc(S2 * 2);
  __hip_bfloat16* Wf2hT  = (__hip_bfloat16*)alloc(2048 * 128 * 2);
  __hip_bfloat16* Wf2lT  = (__hip_bfloat16*)alloc(2048 * 128 * 2);
  __hip_bfloat16* Wg2T   = (__hip_bfloat16*)alloc(2048 * 128 * 2);
  __hip_bfloat16* Wfg1hT = (__hip_bfloat16*)alloc((size_t)256 * 2048 * 2);
  __hip_bfloat16* Wfg1lT = (__hip_bfloat16*)alloc((size_t)256 * 2048 * 2);
  __hip_bfloat16* f1g1h  = (__hip_bfloat16*)alloc((size_t)2048 * 256 * 2);
  __hip_bfloat16* f1g1l  = (__hip_bfloat16*)alloc((size_t)2048 * 256 * 2);
  float* betaT = (float*)alloc((size_t)2048 * 16 * 4);
  float* qkv   = (float*)alloc(3 * S2 * 4);          // [2048][6144] f32
  float* gbuf  = (float*)alloc(S2 * 4);
  float* gatebuf = (float*)alloc(S2 * 4);
  float* karr  = (float*)alloc(S2 * 4);
  float* qarr  = (float*)alloc(S2 * 4);
  float* varr  = (float*)alloc(S2 * 4);
  float* Pg    = (float*)alloc((size_t)1024 * 128 * 4);

  // overlays (timeline-checked):
  __hip_bfloat16* WqkvT = (__hip_bfloat16*)karr;                   // 24MB in karr+qarr[0:8MB]; dead after QKV gemm
  __hip_bfloat16* xlo   = (__hip_bfloat16*)((char*)qarr + S2 * 2); // qarr[8MB:16MB]; dead after stage1
  float* fpart = karr;                                             // 16MB; alive stage1->reduce8 only
  __hip_bfloat16* Xgh = (__hip_bfloat16*)qkv;                      // 16MB; qkv dead after prep_plain
  __hip_bfloat16* KTh = (__hip_bfloat16*)(qkv + 2 * S2);           // 8MB in the 3rd third
  float* uvS   = karr;    // written by kda_pre after it reads karr (same thread/rows)
  float* olocS = varr;
  float* obuf  = gbuf;    // gbuf dead after kda_pre
  __hip_bfloat16* og = (__hip_bfloat16*)qarr;  // after kda_seq; qarr dead after kda_pre

  // 1. split-cast x
  cast_split_kernel<<<4096, 256, 0, stream>>>(x, xb, xlo, (int)(S2 / 4));

  // 2. weight transposes (Wq/Wk/Wv merged; Wf1|Wg1 merged into [256][2048])
  transpose_cast_kernel<<<dim3(64, 64), 256, 0, stream>>>(Wq, WqkvT, nullptr, 2048, 2048);
  transpose_cast_kernel<<<dim3(64, 64), 256, 0, stream>>>(Wk, WqkvT + 2048 * 2048, nullptr, 2048, 2048);
  transpose_cast_kernel<<<dim3(64, 64), 256, 0, stream>>>(Wv, WqkvT + 2 * 2048 * 2048, nullptr, 2048, 2048);
  transpose_cast_kernel<<<dim3(64, 64), 256, 0, stream>>>(Wo, WoT, nullptr, 2048, 2048);
  transpose_cast_kernel<<<dim3(4, 64), 256, 0, stream>>>(Wf1, Wfg1hT, Wfg1lT, 2048, 128);
  transpose_cast_kernel<<<dim3(4, 64), 256, 0, stream>>>(Wg1, Wfg1hT + 128 * 2048, nullptr, 2048, 128);
  hipMemsetAsync(Wfg1lT + 128 * 2048, 0, (size_t)128 * 2048 * 2, stream);
  transpose_cast_kernel<<<dim3(64, 4), 256, 0, stream>>>(Wf2, Wf2hT, Wf2lT, 128, 2048);
  transpose_cast_kernel<<<dim3(64, 4), 256, 0, stream>>>(Wg2, Wg2T, nullptr, 128, 2048);

  // 3. merged QKV projection via 8-phase 256^2 GEMM: qkv[2048][6144]
  gemm_bt256<<<dim3(24, 8), 512, 0, stream>>>(xb, WqkvT, qkv, 2048, 6144, 2048, 2048, 32);

  // 4. merged f1|g1 stage (split-K z=8, 3-pass split precision)
  gemm_btsplit<<<dim3(2, 16, 8), 256, 0, stream>>>(xb, xlo, Wfg1hT, Wfg1lT, fpart,
                                                   2048, 256, 2048, 2048, 256);
  reduce8_kernel<<<512, 256, 0, stream>>>(fpart, f1g1h, f1g1l, 131072, (size_t)2048 * 256);

  // 5. second stages: g = f1 @ Wf2 (split); gate = g1 @ Wg2
  gemm_btsplit<<<dim3(16, 16), 256, 0, stream>>>(f1g1h, f1g1l, Wf2hT, Wf2lT, gbuf,
                                                 2048, 2048, 256, 128, 128);
  gemm_bt<<<dim3(16, 16), 256, 0, stream>>>(f1g1h + 128, Wg2T, gatebuf,
                                            2048, 2048, 256, 128, 128, 0);

  // 6. beta
  beta_kernel<<<128, 256, 0, stream>>>(x, Wb, betaT);

  // 7. prep (conv+silu+mix+l2norm) from merged qkv (stride 6144)
  prep_plain<<<HN * SEQL, 64, 0, stream>>>(qkv, qkv + 2048, qkv + 4096, 6144,
                                           ve, lam, cwq, cwk, cwv, karr, qarr, varr);

  // 8. chunk-local precompute (overwrites qkv overlays Xgh/KTh)
  kda_pre<<<1024, 256, 0, stream>>>(karr, qarr, varr, gbuf, dtb, A_log, betaT,
                                    Xgh, KTh, uvS, olocS, Pg);

  // 9. sequential chunk scan (128 blocks: h x v-eighth)
  kda_seq<<<128, 256, 0, stream>>>(Xgh, KTh, uvS, olocS, Pg, obuf);

  // 10. gated rmsnorm -> bf16 (og aliases qarr)
  rmsgate_kernel<<<8192, 256, 0, stream>>>(obuf, gatebuf, bg2, norm_w, og);

  // 11. output projection
  gemm_bt<<<dim3(16, 16), 256, 0, stream>>>(og, WoT, out, 2048, 2048, 2048, 2048, 2048, 0);
}

// Round 10
// 401.327 us; speedup vs baseline: 2.4028x; 1.0615x over previous
//
#include <hip/hip_runtime.h>
#include <hip/hip_bf16.h>
#include <stdint.h>
#include <stddef.h>

#define SEQL 2048
#define DIMSZ 2048
#define HN 16
#define DKD 128
#define DVD 128
#define QSCALE 0.08838834764831843f   // 128^-0.5

typedef __attribute__((ext_vector_type(4))) float f32x4;
typedef __attribute__((ext_vector_type(2))) float f32x2;
typedef __attribute__((ext_vector_type(8))) short bf16x8;

__device__ __forceinline__ float sigmoid_f(float x) { return 1.f / (1.f + __expf(-x)); }

// ---------------- bf16 GEMM: C[M,N] (f32) = A[M,K]bf16 @ Bt[N,K]bf16 ----------------
#define BM 128
#define BN 128
#define BKK 64

__global__ __launch_bounds__(256) void gemm_bt(
    const __hip_bfloat16* __restrict__ A, const __hip_bfloat16* __restrict__ B,
    float* __restrict__ C, int M, int N, int lda, int ldb, int klen, int accum)
{
  __shared__ __hip_bfloat16 As[BM * BKK];
  __shared__ __hip_bfloat16 Bs[BN * BKK];
  const int tid = threadIdx.x;
  const int lane = tid & 63;
  const int w = tid >> 6;
  const int wm = w >> 1, wn = w & 1;            // 2x2 wave grid, 64x64 each
  const int m0 = blockIdx.y * BM, n0 = blockIdx.x * BN;
  const int l15 = lane & 15, l4 = lane >> 4;
  const int kbase = blockIdx.z * klen;

  f32x4 acc[4][4] = {};

  for (int k0 = kbase; k0 < kbase + klen; k0 += BKK) {
#pragma unroll
    for (int i = 0; i < 4; ++i) {
      const int c = (w * 4 + i) * 64 + lane;     // chunk id, 16B each; 8 chunks/row
      const int row = c >> 3;
      const int colb = (c & 7) * 8;
      __builtin_amdgcn_global_load_lds(
          (const __attribute__((address_space(1))) void*)(A + (size_t)(m0 + row) * lda + k0 + colb),
          (__attribute__((address_space(3))) void*)(As + (size_t)c * 8), 16, 0, 0);
      __builtin_amdgcn_global_load_lds(
          (const __attribute__((address_space(1))) void*)(B + (size_t)(n0 + row) * ldb + k0 + colb),
          (__attribute__((address_space(3))) void*)(Bs + (size_t)c * 8), 16, 0, 0);
    }
    __syncthreads();
#pragma unroll
    for (int kk = 0; kk < BKK; kk += 32) {
      bf16x8 af[4], bfv[4];
#pragma unroll
      for (int mi = 0; mi < 4; ++mi)
        af[mi] = *(const bf16x8*)(As + (wm * 64 + mi * 16 + l15) * BKK + kk + l4 * 8);
#pragma unroll
      for (int ni = 0; ni < 4; ++ni)
        bfv[ni] = *(const bf16x8*)(Bs + (wn * 64 + ni * 16 + l15) * BKK + kk + l4 * 8);
#pragma unroll
      for (int mi = 0; mi < 4; ++mi)
#pragma unroll
        for (int ni = 0; ni < 4; ++ni)
          acc[mi][ni] = __builtin_amdgcn_mfma_f32_16x16x32_bf16(af[mi], bfv[ni], acc[mi][ni], 0, 0, 0);
    }
    __syncthreads();
  }

  float* Cz = C + (size_t)blockIdx.z * M * N;
#pragma unroll
  for (int mi = 0; mi < 4; ++mi) {
#pragma unroll
    for (int ni = 0; ni < 4; ++ni) {
      const int row = m0 + wm * 64 + mi * 16 + l4 * 4;
      const int col = n0 + wn * 64 + ni * 16 + l15;
#pragma unroll
      for (int r = 0; r < 4; ++r) {
        size_t idx = (size_t)(row + r) * N + col;
        if (accum) Cz[idx] += acc[mi][ni][r];
        else Cz[idx] = acc[mi][ni][r];
      }
    }
  }
}

// ---------------- 256x256 8-phase GEMM (T2+T3+T4+T5), for large-N projections ----------------
#define PHASE256(MQ, NQ, NEEDA, NEEDB)                                          \
  {                                                                             \
    if (NEEDA) {                                                                \
      _Pragma("unroll") for (int m2 = 0; m2 < 4; ++m2)                          \
      _Pragma("unroll") for (int ks = 0; ks < 2; ++ks) {                        \
        const int la = (MQ) * 128 + wm * 64 + m2 * 16 + l15;                    \
        const int kc = ks * 4 + l4;                                             \
        a[m2][ks] = *(const bf16x8*)(lds + cb + la * 64 + (kc ^ (la & 7)) * 8); \
      }                                                                         \
    }                                                                           \
    if (NEEDB) {                                                                \
      _Pragma("unroll") for (int n2 = 0; n2 < 2; ++n2)                          \
      _Pragma("unroll") for (int ks = 0; ks < 2; ++ks) {                        \
        const int lb = (NQ) * 128 + wn * 32 + n2 * 16 + l15;                    \
        const int kc = ks * 4 + l4;                                             \
        b[n2][ks] = *(const bf16x8*)(lds + cb + 16384 + lb * 64 + (kc ^ (lb & 7)) * 8); \
      }                                                                         \
    }                                                                           \
    __builtin_amdgcn_s_setprio(1);                                              \
    _Pragma("unroll") for (int m2 = 0; m2 < 4; ++m2)                            \
    _Pragma("unroll") for (int n2 = 0; n2 < 2; ++n2)                            \
    _Pragma("unroll") for (int ks = 0; ks < 2; ++ks)                            \
      acc[(MQ) * 4 + m2][(NQ) * 2 + n2] = __builtin_amdgcn_mfma_f32_16x16x32_bf16( \
          a[m2][ks], b[n2][ks], acc[(MQ) * 4 + m2][(NQ) * 2 + n2], 0, 0, 0);    \
    __builtin_amdgcn_s_setprio(0);                                              \
  }

__global__ __launch_bounds__(512, 2) void gemm_bt256(
    const __hip_bfloat16* __restrict__ A, const __hip_bfloat16* __restrict__ B,
    float* __restrict__ C, int M, int N, int lda, int ldb, int NT)
{
  __shared__ __hip_bfloat16 lds[65536];   // 128 KiB
  const int tid = threadIdx.x;
  const int w = tid >> 6, lane = tid & 63;
  const int wm = w >> 2, wn = w & 3;
  const int l15 = lane & 15, l4 = lane >> 4;
  const int m0 = blockIdx.y * 256, n0 = blockIdx.x * 256;

  f32x4 acc[8][4] = {};
  bf16x8 a[4][2], b[2][2];

  auto stage_half = [&](int which, int t1) {
    const int buf = t1 & 1;
    const int k0n = ((t1 < NT) ? t1 : 0) * 64;
    const int mat = which & 1;          // 0=A, 1=B
    const int half = which >> 1;
#pragma unroll
    for (int i = 0; i < 2; ++i) {
      const int c = i * 512 + tid;           // chunk 0..1023 within half (16B each)
      const int l = half * 128 + (c >> 3);   // lds row 0..255 (quadrant-grouped)
      const int kcs = (c & 7) ^ (l & 7);     // pre-swizzled source chunk
      const __hip_bfloat16* src;
      if (mat == 0) {
        const int grow = ((l >> 6) & 1) * 128 + (l >> 7) * 64 + (l & 63);
        src = A + (size_t)(m0 + grow) * lda + k0n + kcs * 8;
      } else {
        const int gcol = ((l >> 5) & 3) * 64 + (l >> 7) * 32 + (l & 31);
        src = B + (size_t)(n0 + gcol) * ldb + k0n + kcs * 8;
      }
      __builtin_amdgcn_global_load_lds(
          (const __attribute__((address_space(1))) void*)src,
          (__attribute__((address_space(3))) void*)(lds + (size_t)buf * 32768 + mat * 16384 + half * 8192 + (size_t)c * 8),
          16, 0, 0);
    }
  };

  stage_half(0, 0); stage_half(1, 0); stage_half(2, 0); stage_half(3, 0);

  for (int t = 0; t < NT; ++t) {
    const size_t cb = (size_t)(t & 1) * 32768;
    stage_half(0, t + 1);
    asm volatile("s_waitcnt vmcnt(6)" ::: "memory");
    __builtin_amdgcn_s_barrier();
    __builtin_amdgcn_sched_barrier(0);
    PHASE256(0, 0, 1, 1)
    __builtin_amdgcn_s_barrier();
    stage_half(1, t + 1);
    asm volatile("s_waitcnt vmcnt(4)" ::: "memory");
    __builtin_amdgcn_s_barrier();
    __builtin_amdgcn_sched_barrier(0);
    PHASE256(0, 1, 0, 1)
    __builtin_amdgcn_s_barrier();
    stage_half(2, t + 1);
    __builtin_amdgcn_s_barrier();
    __builtin_amdgcn_sched_barrier(0);
    PHASE256(1, 1, 1, 0)
    __builtin_amdgcn_s_barrier();
    stage_half(3, t + 1);
    __builtin_amdgcn_s_barrier();
    __builtin_amdgcn_sched_barrier(0);
    PHASE256(1, 0, 0, 1)
    __builtin_amdgcn_s_barrier();
  }
  asm volatile("s_waitcnt vmcnt(0)" ::: "memory");

#pragma unroll
  for (int mi = 0; mi < 8; ++mi) {
#pragma unroll
    for (int ni = 0; ni < 4; ++ni) {
      const int row = m0 + wm * 128 + mi * 16 + l4 * 4;
      const int col = n0 + wn * 64 + ni * 16 + l15;
#pragma unroll
      for (int r = 0; r < 4; ++r)
        C[(size_t)(row + r) * N + col] = acc[mi][ni][r];
    }
  }
}

// ---------------- fused split-precision GEMM: C = Ah@Bh + Ah@Bl + Al@Bh ----------------
__global__ __launch_bounds__(256) void gemm_btsplit(
    const __hip_bfloat16* __restrict__ Ah, const __hip_bfloat16* __restrict__ Al,
    const __hip_bfloat16* __restrict__ Bh, const __hip_bfloat16* __restrict__ Bl,
    float* __restrict__ C, int M, int N, int lda, int ldb, int klen)
{
  __shared__ __hip_bfloat16 Ash[BM * BKK];
  __shared__ __hip_bfloat16 Asl[BM * BKK];
  __shared__ __hip_bfloat16 Bsh[BN * BKK];
  __shared__ __hip_bfloat16 Bsl[BN * BKK];
  const int tid = threadIdx.x;
  const int lane = tid & 63;
  const int w = tid >> 6;
  const int wm = w >> 1, wn = w & 1;
  const int m0 = blockIdx.y * BM, n0 = blockIdx.x * BN;
  const int l15 = lane & 15, l4 = lane >> 4;
  const int kbase = blockIdx.z * klen;

  f32x4 acc[4][4] = {};

  for (int k0 = kbase; k0 < kbase + klen; k0 += BKK) {
#pragma unroll
    for (int i = 0; i < 4; ++i) {
      const int c = (w * 4 + i) * 64 + lane;
      const int row = c >> 3;
      const int colb = (c & 7) * 8;
      const size_t go = (size_t)(m0 + row) * lda + k0 + colb;
      const size_t gn = (size_t)(n0 + row) * ldb + k0 + colb;
      __builtin_amdgcn_global_load_lds(
          (const __attribute__((address_space(1))) void*)(Ah + go),
          (__attribute__((address_space(3))) void*)(Ash + (size_t)c * 8), 16, 0, 0);
      __builtin_amdgcn_global_load_lds(
          (const __attribute__((address_space(1))) void*)(Al + go),
          (__attribute__((address_space(3))) void*)(Asl + (size_t)c * 8), 16, 0, 0);
      __builtin_amdgcn_global_load_lds(
          (const __attribute__((address_space(1))) void*)(Bh + gn),
          (__attribute__((address_space(3))) void*)(Bsh + (size_t)c * 8), 16, 0, 0);
      __builtin_amdgcn_global_load_lds(
          (const __attribute__((address_space(1))) void*)(Bl + gn),
          (__attribute__((address_space(3))) void*)(Bsl + (size_t)c * 8), 16, 0, 0);
    }
    __syncthreads();
#pragma unroll
    for (int kk = 0; kk < BKK; kk += 32) {
      bf16x8 afh[4], afl[4], bfh[4], bfl[4];
#pragma unroll
      for (int mi = 0; mi < 4; ++mi) {
        const int ao = (wm * 64 + mi * 16 + l15) * BKK + kk + l4 * 8;
        afh[mi] = *(const bf16x8*)(Ash + ao);
        afl[mi] = *(const bf16x8*)(Asl + ao);
      }
#pragma unroll
      for (int ni = 0; ni < 4; ++ni) {
        const int bo = (wn * 64 + ni * 16 + l15) * BKK + kk + l4 * 8;
        bfh[ni] = *(const bf16x8*)(Bsh + bo);
        bfl[ni] = *(const bf16x8*)(Bsl + bo);
      }
#pragma unroll
      for (int mi = 0; mi < 4; ++mi)
#pragma unroll
        for (int ni = 0; ni < 4; ++ni) {
          acc[mi][ni] = __builtin_amdgcn_mfma_f32_16x16x32_bf16(afh[mi], bfh[ni], acc[mi][ni], 0, 0, 0);
          acc[mi][ni] = __builtin_amdgcn_mfma_f32_16x16x32_bf16(afh[mi], bfl[ni], acc[mi][ni], 0, 0, 0);
          acc[mi][ni] = __builtin_amdgcn_mfma_f32_16x16x32_bf16(afl[mi], bfh[ni], acc[mi][ni], 0, 0, 0);
        }
    }
    __syncthreads();
  }

  float* Cz = C + (size_t)blockIdx.z * M * N;
#pragma unroll
  for (int mi = 0; mi < 4; ++mi) {
#pragma unroll
    for (int ni = 0; ni < 4; ++ni) {
      const int row = m0 + wm * 64 + mi * 16 + l4 * 4;
      const int col = n0 + wn * 64 + ni * 16 + l15;
#pragma unroll
      for (int r = 0; r < 4; ++r)
        Cz[(size_t)(row + r) * N + col] = acc[mi][ni][r];
    }
  }
}

// ---------------- transpose + cast (optional hi/lo split): out[C,R] = bf16(in[R,C]^T) ----------------
__global__ __launch_bounds__(256) void transpose_cast_kernel(
    const float* __restrict__ in, __hip_bfloat16* __restrict__ outT,
    __hip_bfloat16* __restrict__ outLo, int R, int C)
{
  __shared__ float tile[32][33];
  const int c0 = blockIdx.x * 32, r0 = blockIdx.y * 32;
  const int tc = threadIdx.x & 31, tr = threadIdx.x >> 5;   // tr in 0..7
#pragma unroll
  for (int i = 0; i < 4; ++i)
    tile[tr + i * 8][tc] = in[(size_t)(r0 + tr + i * 8) * C + c0 + tc];
  __syncthreads();
#pragma unroll
  for (int i = 0; i < 4; ++i) {
    float val = tile[tc][tr + i * 8];
    __hip_bfloat16 h = __float2bfloat16(val);
    size_t oi = (size_t)(c0 + tr + i * 8) * R + r0 + tc;
    outT[oi] = h;
    if (outLo) outLo[oi] = __float2bfloat16(val - __bfloat162float(h));
  }
}

// ---------------- elementwise cast with optional lo residual ----------------
__global__ __launch_bounds__(256) void cast_split_kernel(
    const float* __restrict__ in, __hip_bfloat16* __restrict__ hi,
    __hip_bfloat16* __restrict__ lo, int n4)
{
  int idx = blockIdx.x * 256 + threadIdx.x;
  if (idx >= n4) return;
  f32x4 v = *(const f32x4*)(in + (size_t)idx * 4);
  union { __hip_bfloat16 b[4]; unsigned long long u; } ph, pl;
#pragma unroll
  for (int j = 0; j < 4; ++j) {
    float f = v[j];
    __hip_bfloat16 hh = __float2bfloat16(f);
    ph.b[j] = hh;
    pl.b[j] = __float2bfloat16(f - __bfloat162float(hh));
  }
  *(unsigned long long*)((char*)hi + (size_t)idx * 8) = ph.u;
  if (lo) *(unsigned long long*)((char*)lo + (size_t)idx * 8) = pl.u;
}

// ---------------- split-K reduce (8 partials) -> bf16 hi (+ optional lo) ----------------
__global__ __launch_bounds__(256) void reduce8_kernel(
    const float* __restrict__ part, __hip_bfloat16* __restrict__ hi,
    __hip_bfloat16* __restrict__ lo, int n4, size_t chunk)
{
  int idx = blockIdx.x * 256 + threadIdx.x;
  if (idx >= n4) return;
  f32x4 a = *(const f32x4*)(part + (size_t)idx * 4);
#pragma unroll
  for (int z = 1; z < 8; ++z) {
    f32x4 b = *(const f32x4*)(part + z * chunk + (size_t)idx * 4);
    a.x += b.x; a.y += b.y; a.z += b.z; a.w += b.w;
  }
  union { __hip_bfloat16 b[4]; unsigned long long u; } ph, pl;
#pragma unroll
  for (int j = 0; j < 4; ++j) {
    float f = a[j];
    __hip_bfloat16 hh = __float2bfloat16(f);
    ph.b[j] = hh;
    pl.b[j] = __float2bfloat16(f - __bfloat162float(hh));
  }
  *(unsigned long long*)((char*)hi + (size_t)idx * 8) = ph.u;
  if (lo) *(unsigned long long*)((char*)lo + (size_t)idx * 8) = pl.u;
}

// ---------------- beta = sigmoid(x @ Wb), thread per (s,h); writes [h][s] ----------------
__global__ __launch_bounds__(256) void beta_kernel(
    const float* __restrict__ x, const float* __restrict__ Wb, float* __restrict__ betaT)
{
  int idx = blockIdx.x * 256 + threadIdx.x;      // 0..32767
  int s = idx >> 4, h = idx & 15;
  const float* xr = x + (size_t)s * DIMSZ;
  float acc = 0.f;
  for (int d = 0; d < DIMSZ; d += 4) {
    f32x4 xv = *(const f32x4*)(xr + d);
    acc = fmaf(xv.x, Wb[(size_t)(d + 0) * HN + h], acc);
    acc = fmaf(xv.y, Wb[(size_t)(d + 1) * HN + h], acc);
    acc = fmaf(xv.z, Wb[(size_t)(d + 2) * HN + h], acc);
    acc = fmaf(xv.w, Wb[(size_t)(d + 3) * HN + h], acc);
  }
  betaT[(size_t)h * SEQL + s] = 1.f / (1.f + expf(-acc));
}

// ---------------- fused prep + chunk-local precompute (C=32) ----------------
// One block per (h, chunk). Phase 1: conv+silu+ve-mix+l2norm+glog computed in-register
// from qkv (3-row halo is chunk-local); G via per-wave cumsum + cross-wave prefix.
// Phase 2 (pairs): slice-20 LDS layout (conflict-free i-broadcast reads) + wave-skewed
// rows (tt = 8w+tg). Phase 3: KbarT + forward substitution + Qt/oloc.
// LDS 80768 B -> 2 blocks/CU.
#define SL20(r, d) ((r) * 160 + ((d) >> 4) * 20 + ((d) & 15))

__global__ __launch_bounds__(256) void kda_pref(
    const float* __restrict__ qkv, const float* __restrict__ ve,
    const float* __restrict__ lam,
    const float* __restrict__ cwq, const float* __restrict__ cwk, const float* __restrict__ cwv,
    const float* __restrict__ gbuf,
    const float* __restrict__ dtb, const float* __restrict__ A_log,
    const float* __restrict__ betaT,
    __hip_bfloat16* __restrict__ Xgh, __hip_bfloat16* __restrict__ KTh,
    float* __restrict__ uvS, float* __restrict__ olocS, float* __restrict__ Pg)
{
  __shared__ float GL2[32 * 160];
  __shared__ float kL2[32 * 160];
  __shared__ float qL2[32 * 132];
  __shared__ float vL2[32 * 128];
  __shared__ float ALB[32][33];      // lower: A; upper [i][t]: B[t][i] (i<t)
  __shared__ float Bdiag[32], betaL[32];
  __shared__ float csumW[4 * 128];

  const int bid = blockIdx.x;
  const int h = bid >> 6, cc = bid & 63;
  const int tid = threadIdx.x;
  const int w = tid >> 6, lane = tid & 63;
  const size_t hc = (size_t)h * 64 + cc;
  const float Aexp = __expf(A_log[h]);

  // ======== phase 1: conv + silu + mix + l2norm + glog ========
  {
    const int c = lane * 2;                 // col pair
    const int r0g = cc * 32 + w * 8;        // global row base for this wave
    const int cg = h * 128 + c;

    f32x4 wq0 = *(const f32x4*)(cwq + (size_t)cg * 4), wq1 = *(const f32x4*)(cwq + (size_t)(cg + 1) * 4);
    f32x4 wk0 = *(const f32x4*)(cwk + (size_t)cg * 4), wk1 = *(const f32x4*)(cwk + (size_t)(cg + 1) * 4);
    f32x4 wv0 = *(const f32x4*)(cwv + (size_t)cg * 4), wv1 = *(const f32x4*)(cwv + (size_t)(cg + 1) * 4);
    f32x2 dt2 = *(const f32x2*)(dtb + cg);
    const float l0 = lam[0], l1 = lam[1];

    f32x2 xqr[11], xkr[11], xvr[11];
#pragma unroll
    for (int i = 0; i < 11; ++i) {
      const int sr = r0g - 3 + i;
      if (sr >= 0) {
        const size_t ro = (size_t)sr * 6144 + cg;
        xqr[i] = *(const f32x2*)(qkv + ro);
        xkr[i] = *(const f32x2*)(qkv + 2048 + ro);
        xvr[i] = *(const f32x2*)(qkv + 4096 + ro);
      } else {
        xqr[i].x = xqr[i].y = xkr[i].x = xkr[i].y = xvr[i].x = xvr[i].y = 0.f;
      }
    }

    float gl0[8], gl1[8];
#pragma unroll
    for (int i = 0; i < 8; ++i) {
      const int rr = r0g + i;
      const int lr = w * 8 + i;
      float aq0 = 0, aq1 = 0, ak0 = 0, ak1 = 0, av0 = 0, av1 = 0;
#pragma unroll
      for (int j = 0; j < 4; ++j) {
        aq0 = fmaf(xqr[i + j].x, wq0[j], aq0); aq1 = fmaf(xqr[i + j].y, wq1[j], aq1);
        ak0 = fmaf(xkr[i + j].x, wk0[j], ak0); ak1 = fmaf(xkr[i + j].y, wk1[j], ak1);
        av0 = fmaf(xvr[i + j].x, wv0[j], av0); av1 = fmaf(xvr[i + j].y, wv1[j], av1);
      }
      float yq0 = aq0 * sigmoid_f(aq0), yq1 = aq1 * sigmoid_f(aq1);
      float yk0 = ak0 * sigmoid_f(ak0), yk1 = ak1 * sigmoid_f(ak1);
      float yv0 = av0 * sigmoid_f(av0), yv1 = av1 * sigmoid_f(av1);

      f32x2 vev = *(const f32x2*)(ve + ((size_t)rr * HN + h) * 128 + c);
      float v0 = l0 * yv0 + l1 * vev.x;
      float v1 = l0 * yv1 + l1 * vev.y;

      float ssq = yq0 * yq0 + yq1 * yq1;
      float ssk = yk0 * yk0 + yk1 * yk1;
#pragma unroll
      for (int off = 32; off > 0; off >>= 1) {
        ssq += __shfl_xor(ssq, off);
        ssk += __shfl_xor(ssk, off);
      }
      float rq = rsqrtf(ssq + 1e-6f) * QSCALE;
      float rk = rsqrtf(ssk + 1e-6f);

      f32x2 kk; kk.x = yk0 * rk; kk.y = yk1 * rk;
      f32x2 qq; qq.x = yq0 * rq; qq.y = yq1 * rq;
      f32x2 vv; vv.x = v0; vv.y = v1;
      *(f32x2*)&kL2[SL20(lr, c)] = kk;
      *(f32x2*)&qL2[lr * 132 + c] = qq;
      *(f32x2*)&vL2[lr * 128 + c] = vv;

      f32x2 gv = *(const f32x2*)(gbuf + (size_t)rr * 2048 + cg);
      float g0 = gv.x + dt2.x, g1 = gv.y + dt2.y;
      float sp0 = (g0 > 20.f) ? g0 : log1pf(__expf(fminf(g0, 20.f)));
      float sp1 = (g1 > 20.f) ? g1 : log1pf(__expf(fminf(g1, 20.f)));
      gl0[i] = -Aexp * sp0;
      gl1[i] = -Aexp * sp1;
    }
    // per-wave cumsum
    {
      float r0 = 0.f, r1 = 0.f;
#pragma unroll
      for (int i = 0; i < 8; ++i) { r0 += gl0[i]; gl0[i] = r0; r1 += gl1[i]; gl1[i] = r1; }
      csumW[w * 128 + c] = r0;
      csumW[w * 128 + c + 1] = r1;
    }
    if (tid < 32) betaL[tid] = betaT[(size_t)h * SEQL + cc * 32 + tid];
    __syncthreads();
    // cross-wave prefix, write GL
    {
      float p0 = 0.f, p1 = 0.f;
      for (int wp = 0; wp < w; ++wp) { p0 += csumW[wp * 128 + c]; p1 += csumW[wp * 128 + c + 1]; }
#pragma unroll
      for (int i = 0; i < 8; ++i) {
        f32x2 gg; gg.x = gl0[i] + p0; gg.y = gl1[i] + p1;
        *(f32x2*)&GL2[SL20(w * 8 + i, c)] = gg;
      }
    }
  }
  __syncthreads();

  // ======== phase 2: pairs A[t][i], B[t][i] (wave-skewed, conflict-free) ========
  {
    const int tg = lane >> 3, s8 = lane & 7;
    const int tt = w * 8 + tg;              // wave w owns rows 8w..8w+7
    const int ds = s8 * 20;                 // slice base (dwords) within row

    float Gt[16], kt[16], qt[16];
#pragma unroll
    for (int j = 0; j < 16; j += 4) {
      *(f32x4*)&Gt[j] = *(const f32x4*)&GL2[tt * 160 + ds + j];
      *(f32x4*)&kt[j] = *(const f32x4*)&kL2[tt * 160 + ds + j];
      *(f32x4*)&qt[j] = *(const f32x4*)&qL2[tt * 132 + s8 * 16 + j];
    }
    {
      float sA = 0.f, sB = 0.f;
#pragma unroll
      for (int j = 0; j < 16; ++j) { sA = fmaf(kt[j], kt[j], sA); sB = fmaf(qt[j], kt[j], sB); }
      sA += __shfl_xor(sA, 1); sA += __shfl_xor(sA, 2); sA += __shfl_xor(sA, 4);
      sB += __shfl_xor(sB, 1); sB += __shfl_xor(sB, 2); sB += __shfl_xor(sB, 4);
      if (s8 == 0) { ALB[tt][tt] = sA; Bdiag[tt] = sB; }
    }
    const int ibound = w * 8 + 7;
    for (int i = 0; i < ibound; ++i) {
      if (i < tt) {
        float sA = 0.f, sB = 0.f;
#pragma unroll
        for (int jj = 0; jj < 4; ++jj) {
          f32x4 Gi = *(const f32x4*)&GL2[i * 160 + ds + jj * 4];
          f32x4 ki = *(const f32x4*)&kL2[i * 160 + ds + jj * 4];
#pragma unroll
          for (int u = 0; u < 4; ++u) {
            float e = __expf(Gt[jj * 4 + u] - Gi[u]);
            float kid = ki[u] * e;
            sA = fmaf(kt[jj * 4 + u], kid, sA);
            sB = fmaf(qt[jj * 4 + u], kid, sB);
          }
        }
        sA += __shfl_xor(sA, 1); sA += __shfl_xor(sA, 2); sA += __shfl_xor(sA, 4);
        sB += __shfl_xor(sB, 1); sB += __shfl_xor(sB, 2); sB += __shfl_xor(sB, 4);
        if (s8 == 0) { ALB[tt][i] = sA; ALB[i][tt] = sB; }
      }
    }
  }
  __syncthreads();

  // ======== phase 3: KbarT + substitution + Qt/oloc ========
  const int col = tid & 127, half = tid >> 7;
  const size_t rowbase = (size_t)(cc * 32) * 2048 + h * 128 + col;
  const int rbase = half * 16;
  {
    const float g31 = GL2[SL20(31, col)];
    size_t kb = hc * 4096 + (size_t)col * 32;
#pragma unroll
    for (int i = 0; i < 16; ++i) {
      int r = rbase + i;
      float kv = kL2[SL20(r, col)] * __expf(g31 - GL2[SL20(r, col)]);
      KTh[kb + r] = __float2bfloat16(kv);
    }
  }

  if (half == 0) {
    float expg[32];
#pragma unroll
    for (int r = 0; r < 32; ++r) expg[r] = __expf(GL2[SL20(r, col)]);

    float uvr[32], wr[32];
#pragma unroll
    for (int r = 0; r < 32; ++r) {
      float suv = 0.f, sw = 0.f;
#pragma unroll
      for (int j = 0; j < 32; ++j) {
        if (j < r) { float a = ALB[r][j]; suv = fmaf(a, uvr[j], suv); sw = fmaf(a, wr[j], sw); }
      }
      float br = betaL[r];
      float khr = kL2[SL20(r, col)] * expg[r];
      uvr[r] = br * (vL2[r * 128 + col] - suv);
      wr[r] = br * (khr - sw);
      uvS[rowbase + (size_t)r * 2048] = uvr[r];
      Xgh[hc * 8192 + (size_t)(32 + r) * 128 + col] = __float2bfloat16(wr[r]);
    }

#pragma unroll
    for (int r = 0; r < 32; ++r) {
      float qtv = qL2[r * 132 + col] * expg[r];
      float ol = 0.f;
#pragma unroll
      for (int j = 0; j < 32; ++j) {
        if (j < r) { float b = ALB[j][r]; qtv = fmaf(-b, wr[j], qtv); ol = fmaf(b, uvr[j], ol); }
      }
      { float b = Bdiag[r]; qtv = fmaf(-b, wr[r], qtv); ol = fmaf(b, uvr[r], ol); }
      Xgh[hc * 8192 + (size_t)r * 128 + col] = __float2bfloat16(qtv);
      olocS[rowbase + (size_t)r * 2048] = ol;
    }
    Pg[hc * 128 + col] = expg[31];
  }
}

// ---------------- sequential chunk scan: S in MFMA accumulators, reg-prefetched ----------------
#define STP 136
#define UTP 40

struct ChunkOps {
  bf16x8 ah[4];
  bf16x8 kah[2];
  f32x4 pvv[2];
  float pB[4];
};

__global__ __launch_bounds__(256) void kda_seq(
    const __hip_bfloat16* __restrict__ Xgh, const __hip_bfloat16* __restrict__ KTh,
    const float* __restrict__ uvS, const float* __restrict__ olocS,
    const float* __restrict__ Pg, float* __restrict__ obuf)
{
  __shared__ __hip_bfloat16 STh[16 * STP], STl[16 * STP];
  __shared__ __hip_bfloat16 UTh[16 * UTP];
  const int tid = threadIdx.x;
  const int w = tid >> 6, lane = tid & 63, l15 = lane & 15, l4 = lane >> 4;
  const int h = blockIdx.x >> 3, vq = blockIdx.x & 7;
  const int v0 = vq * 16;
  const int r0 = (w & 1) * 16 + l4 * 4;
  const int isO = (w < 2);

  for (int i = tid; i < 16 * STP; i += 256) {
    STh[i] = __float2bfloat16(0.f);
    STl[i] = __float2bfloat16(0.f);
  }
  __syncthreads();

  f32x4 S[2] = {};

  auto loadops = [&](ChunkOps& o, int c) {
    const size_t hc = (size_t)h * 64 + c;
    const __hip_bfloat16* xh = Xgh + hc * 8192 + (size_t)(w * 16 + l15) * 128 + l4 * 8;
#pragma unroll
    for (int kk = 0; kk < 4; ++kk) o.ah[kk] = *(const bf16x8*)(xh + kk * 32);
    const float* pb = (isO ? olocS : uvS) + (size_t)(c * 32 + r0) * 2048 + h * 128 + v0 + l15;
#pragma unroll
    for (int r = 0; r < 4; ++r) o.pB[r] = pb[(size_t)r * 2048];
#pragma unroll
    for (int mi = 0; mi < 2; ++mi) {
      const int kd = (w * 2 + mi) * 16;
      o.kah[mi] = *(const bf16x8*)(KTh + hc * 4096 + (size_t)(kd + l15) * 32 + l4 * 8);
      o.pvv[mi] = *(const f32x4*)(Pg + hc * 128 + kd + l4 * 4);
    }
  };

  auto body = [&](ChunkOps& o, int c) {
    f32x4 Y = {};
#pragma unroll
    for (int kk = 0; kk < 4; ++kk) {
      const int so = l15 * STP + kk * 32 + l4 * 8;
      bf16x8 bh = *(const bf16x8*)(STh + so);
      bf16x8 bl = *(const bf16x8*)(STl + so);
      Y = __builtin_amdgcn_mfma_f32_16x16x32_bf16(o.ah[kk], bh, Y, 0, 0, 0);
      Y = __builtin_amdgcn_mfma_f32_16x16x32_bf16(o.ah[kk], bl, Y, 0, 0, 0);
    }

    if (isO) {
      size_t ob = (size_t)(c * 32 + r0) * 2048 + h * 128 + v0 + l15;
#pragma unroll
      for (int r = 0; r < 4; ++r)
        obuf[ob + (size_t)r * 2048] = Y[r] + o.pB[r];
    } else {
      union { __hip_bfloat16 b[4]; unsigned long long u; } uh;
#pragma unroll
      for (int r = 0; r < 4; ++r)
        uh.b[r] = __float2bfloat16(o.pB[r] - Y[r]);
      *(unsigned long long*)(UTh + l15 * UTP + r0) = uh.u;
    }
    __syncthreads();

#pragma unroll
    for (int mi = 0; mi < 2; ++mi) S[mi] *= o.pvv[mi];
    {
      bf16x8 ubh = *(const bf16x8*)(UTh + l15 * UTP + l4 * 8);
#pragma unroll
      for (int mi = 0; mi < 2; ++mi)
        S[mi] = __builtin_amdgcn_mfma_f32_16x16x32_bf16(o.kah[mi], ubh, S[mi], 0, 0, 0);
    }

#pragma unroll
    for (int mi = 0; mi < 2; ++mi) {
      const int kd0 = (w * 2 + mi) * 16 + l4 * 4;
      union { __hip_bfloat16 b[4]; unsigned long long u; } sh, sl;
#pragma unroll
      for (int r = 0; r < 4; ++r) {
        __hip_bfloat16 hh = __float2bfloat16(S[mi][r]);
        sh.b[r] = hh;
        sl.b[r] = __float2bfloat16(S[mi][r] - __bfloat162float(hh));
      }
      *(unsigned long long*)(STh + l15 * STP + kd0) = sh.u;
      *(unsigned long long*)(STl + l15 * STP + kd0) = sl.u;
    }
    __syncthreads();
  };

  ChunkOps A_, B_;
  loadops(A_, 0);
  for (int c = 0; c < 64; c += 2) {
    loadops(B_, c + 1);
    body(A_, c);
    if (c + 2 < 64) loadops(A_, c + 2);
    body(B_, c + 1);
  }
}

// ---------------- sigmoid-gated RMSNorm -> bf16 ----------------
__global__ __launch_bounds__(256) void rmsgate_kernel(
    const float* __restrict__ o, const float* __restrict__ gate,
    const float* __restrict__ bg2, const float* __restrict__ norm_w,
    __hip_bfloat16* __restrict__ og)
{
  int row = blockIdx.x * 4 + (threadIdx.x >> 6);   // s*16 + h
  int lane = threadIdx.x & 63;
  int s = row >> 4, h = row & 15;
  int j = lane * 2;
  const float* p = o + (size_t)row * 128 + j;
  f32x2 v = *(const f32x2*)p;
  float ss = v.x * v.x + v.y * v.y;
#pragma unroll
  for (int off = 32; off > 0; off >>= 1) ss += __shfl_xor(ss, off);
  float rs = rsqrtf(ss * (1.f / 128.f) + 1e-6f);
  int c = h * 128 + j;
  float g0 = gate[(size_t)s * 2048 + c] + bg2[c];
  float g1 = gate[(size_t)s * 2048 + c + 1] + bg2[c + 1];
  float o0 = v.x * rs * norm_w[j] * (1.f / (1.f + expf(-g0)));
  float o1 = v.y * rs * norm_w[j + 1] * (1.f / (1.f + expf(-g1)));
  union { __hip_bfloat16 b[2]; unsigned int u; } pk2;
  pk2.b[0] = __float2bfloat16(o0);
  pk2.b[1] = __float2bfloat16(o1);
  *(unsigned int*)((char*)og + ((size_t)s * 2048 + c) * 2) = pk2.u;
}

// =====================================================================
extern "C" void kernel_launch(void* const* d_in, const int* in_sizes, int n_in,
                              void* d_out, int out_size, void* d_ws, size_t ws_size,
                              hipStream_t stream)
{
  const float* x      = (const float*)d_in[0];
  const float* ve     = (const float*)d_in[1];
  const float* lam    = (const float*)d_in[2];
  const float* Wq     = (const float*)d_in[3];
  const float* Wk     = (const float*)d_in[4];
  const float* Wv     = (const float*)d_in[5];
  const float* cwq    = (const float*)d_in[6];
  const float* cwk    = (const float*)d_in[7];
  const float* cwv    = (const float*)d_in[8];
  const float* Wf1    = (const float*)d_in[9];
  const float* Wf2    = (const float*)d_in[10];
  const float* Wb     = (const float*)d_in[11];
  const float* A_log  = (const float*)d_in[12];
  const float* dtb    = (const float*)d_in[13];
  const float* Wg1    = (const float*)d_in[14];
  const float* Wg2    = (const float*)d_in[15];
  const float* bg2    = (const float*)d_in[16];
  const float* norm_w = (const float*)d_in[17];
  const float* Wo     = (const float*)d_in[18];
  float* out = (float*)d_out;

  const size_t S2 = (size_t)2048 * 2048;

  char* p = (char*)d_ws;
  auto alloc = [&](size_t bytes) { char* r = p; p += (bytes + 255) & ~(size_t)255; return r; };

  __hip_bfloat16* xb     = (__hip_bfloat16*)alloc(S2 * 2);
  __hip_bfloat16* WoT    = (__hip_bfloat16*)alloc(S2 * 2);
  __hip_bfloat16* Wf2hT  = (__hip_bfloat16*)alloc(2048 * 128 * 2);
  __hip_bfloat16* Wf2lT  = (__hip_bfloat16*)alloc(2048 * 128 * 2);
  __hip_bfloat16* Wg2T   = (__hip_bfloat16*)alloc(2048 * 128 * 2);
  __hip_bfloat16* Wfg1hT = (__hip_bfloat16*)alloc((size_t)256 * 2048 * 2);
  __hip_bfloat16* Wfg1lT = (__hip_bfloat16*)alloc((size_t)256 * 2048 * 2);
  __hip_bfloat16* f1g1h  = (__hip_bfloat16*)alloc((size_t)2048 * 256 * 2);
  __hip_bfloat16* f1g1l  = (__hip_bfloat16*)alloc((size_t)2048 * 256 * 2);
  float* betaT = (float*)alloc((size_t)2048 * 16 * 4);
  float* qkv   = (float*)alloc(3 * S2 * 4);          // [2048][6144] f32
  float* gbuf  = (float*)alloc(S2 * 4);
  float* gatebuf = (float*)alloc(S2 * 4);
  float* uvS   = (float*)alloc(S2 * 4);
  float* olocS = (float*)alloc(S2 * 4);
  __hip_bfloat16* Xgh = (__hip_bfloat16*)alloc(S2 * 4);   // 16MB: 1024 hc x 64 rows x 128 cols bf16 (was S2*2: overflowed onto KTh)
  __hip_bfloat16* KTh = (__hip_bfloat16*)alloc(S2 * 2);   // 8MB: 1024 hc x 128 x 32 bf16
  float* Pg    = (float*)alloc((size_t)1024 * 128 * 4);

  // overlays (timeline-checked):
  // WqkvT (24MB, steps 2-3) -> uvS(16MB) + olocS[0:8MB]; both first written at kda_pref (step 7)
  __hip_bfloat16* WqkvT = (__hip_bfloat16*)uvS;
  // xlo (8MB, steps 1-4) -> olocS[8MB:16MB] (disjoint from WqkvT)
  __hip_bfloat16* xlo = (__hip_bfloat16*)((char*)olocS + S2 * 2);
  // fpart (16MB, step 4 only) -> fits inside Xgh (16MB); Xgh written later at step 7
  float* fpart = (float*)Xgh;
  float* obuf  = gbuf;                          // gbuf dead after kda_pref
  __hip_bfloat16* og = (__hip_bfloat16*)qkv;    // qkv dead after kda_pref

  // 1. split-cast x
  cast_split_kernel<<<4096, 256, 0, stream>>>(x, xb, xlo, (int)(S2 / 4));

  // 2. weight transposes (Wq/Wk/Wv merged; Wf1|Wg1 merged into [256][2048])
  transpose_cast_kernel<<<dim3(64, 64), 256, 0, stream>>>(Wq, WqkvT, nullptr, 2048, 2048);
  transpose_cast_kernel<<<dim3(64, 64), 256, 0, stream>>>(Wk, WqkvT + 2048 * 2048, nullptr, 2048, 2048);
  transpose_cast_kernel<<<dim3(64, 64), 256, 0, stream>>>(Wv, WqkvT + 2 * 2048 * 2048, nullptr, 2048, 2048);
  transpose_cast_kernel<<<dim3(64, 64), 256, 0, stream>>>(Wo, WoT, nullptr, 2048, 2048);
  transpose_cast_kernel<<<dim3(4, 64), 256, 0, stream>>>(Wf1, Wfg1hT, Wfg1lT, 2048, 128);
  transpose_cast_kernel<<<dim3(4, 64), 256, 0, stream>>>(Wg1, Wfg1hT + 128 * 2048, nullptr, 2048, 128);
  hipMemsetAsync(Wfg1lT + 128 * 2048, 0, (size_t)128 * 2048 * 2, stream);
  transpose_cast_kernel<<<dim3(64, 4), 256, 0, stream>>>(Wf2, Wf2hT, Wf2lT, 128, 2048);
  transpose_cast_kernel<<<dim3(64, 4), 256, 0, stream>>>(Wg2, Wg2T, nullptr, 128, 2048);

  // 3. merged QKV projection via 8-phase 256^2 GEMM: qkv[2048][6144]
  gemm_bt256<<<dim3(24, 8), 512, 0, stream>>>(xb, WqkvT, qkv, 2048, 6144, 2048, 2048, 32);

  // 4. merged f1|g1 stage (split-K z=8, 3-pass split precision)
  gemm_btsplit<<<dim3(2, 16, 8), 256, 0, stream>>>(xb, xlo, Wfg1hT, Wfg1lT, fpart,
                                                   2048, 256, 2048, 2048, 256);
  reduce8_kernel<<<512, 256, 0, stream>>>(fpart, f1g1h, f1g1l, 131072, (size_t)2048 * 256);

  // 5. second stages: g = f1 @ Wf2 (split); gate = g1 @ Wg2
  gemm_btsplit<<<dim3(16, 16), 256, 0, stream>>>(f1g1h, f1g1l, Wf2hT, Wf2lT, gbuf,
                                                 2048, 2048, 256, 128, 128);
  gemm_bt<<<dim3(16, 16), 256, 0, stream>>>(f1g1h + 128, Wg2T, gatebuf,
                                            2048, 2048, 256, 128, 128, 0);

  // 6. beta
  beta_kernel<<<128, 256, 0, stream>>>(x, Wb, betaT);

  // 7. fused prep + chunk-local precompute
  kda_pref<<<1024, 256, 0, stream>>>(qkv, ve, lam, cwq, cwk, cwv, gbuf, dtb, A_log, betaT,
                                     Xgh, KTh, uvS, olocS, Pg);

  // 8. sequential chunk scan (128 blocks: h x v-eighth)
  kda_seq<<<128, 256, 0, stream>>>(Xgh, KTh, uvS, olocS, Pg, obuf);

  // 9. gated rmsnorm -> bf16 (og aliases qkv)
  rmsgate_kernel<<<8192, 256, 0, stream>>>(obuf, gatebuf, bg2, norm_w, og);

  // 10. output projection
  gemm_bt<<<dim3(16, 16), 256, 0, stream>>>(og, WoT, out, 2048, 2048, 2048, 2048, 2048, 0);
}